// Round 2
// baseline (2141.351 us; speedup 1.0000x reference)
//
#include <hip/hip_runtime.h>
#include <math.h>

#define PP 40000
#define HDIM 200
#define WDIM 200
#define NEPS 1e-8f

// workspace layout (float offsets)
#define OFF_COM    0            // 15*PP
#define OFF_ENT    (15*PP)      // 15*PP
#define OFF_MASK   (30*PP)      // 12*PP
#define OFF_DEN    (42*PP)      // 12*PP
#define OFF_LOGITS (54*PP)      // 15*PP
#define OFF_U      (69*PP)      // 3*128*PP
#define MISC_FULL  (453*PP)
#define MISC_MIN   (69*PP)
// misc (uint slots): [0..11] min_ord, [12..23] max_ord, [24] count, [25..36] iszero

__device__ __forceinline__ unsigned f2ord(float f){
    unsigned u = __float_as_uint(f);
    return (u & 0x80000000u) ? ~u : (u | 0x80000000u);
}
__device__ __forceinline__ float ord2f(unsigned u){
    unsigned v = (u & 0x80000000u) ? (u & 0x7fffffffu) : ~u;
    return __uint_as_float(v);
}

__device__ __forceinline__ void tap_setup(int p, int* off, bool* val){
    int h = p / WDIM, w = p - h*WDIM;
#pragma unroll
    for (int ky=0;ky<3;ky++)
#pragma unroll
        for (int kx=0;kx<3;kx++){
            int t = ky*3+kx;
            int hh = h+ky-1, ww = w+kx-1;
            val[t] = (hh>=0)&&(hh<HDIM)&&(ww>=0)&&(ww<WDIM);
            off[t] = hh*WDIM+ww;
        }
}

__global__ void k_init(unsigned* misc){
    int t = threadIdx.x;
    if (t < 12) misc[t] = 0xFFFFFFFFu;        // min (sortable) = +inf
    else if (t < 25) misc[t] = 0u;            // max = -inf, count = 0
}

// compress conv3x3 (64->1) + relu, fused per-image min/max of raw nb values
__global__ __launch_bounds__(256) void k_conv(const float* __restrict__ bevs,
        const float* __restrict__ cw, const float* __restrict__ cb,
        float* __restrict__ com, unsigned* __restrict__ misc)
{
    __shared__ float wl[576];
    int img = blockIdx.y;          // 0..14 = bt*5+n
    int n = img % 5;
    for (int i = threadIdx.x; i < 576; i += 256) wl[i] = cw[i];
    __syncthreads();
    int p = blockIdx.x*256 + threadIdx.x;
    float vmin = INFINITY, vmax = -INFINITY;
    if (p < PP){
        int off[9]; bool val[9];
        tap_setup(p, off, val);
        const float* src = bevs + (size_t)img*64*PP;
        float acc = cb[0];
        for (int c=0;c<64;c++){
            const float* sc = src + (size_t)c*PP;
            const float* wc = &wl[c*9];
#pragma unroll
            for (int t=0;t<9;t++){
                if (val[t]){
                    float v = sc[off[t]];
                    acc = fmaf(wc[t], v, acc);
                    vmin = fminf(vmin, v); vmax = fmaxf(vmax, v);
                }
            }
        }
        com[(size_t)img*PP + p] = fmaxf(acc, 0.0f);
    }
    if (n > 0){
#pragma unroll
        for (int s=32;s>0;s>>=1){
            vmin = fminf(vmin, __shfl_xor(vmin, s, 64));
            vmax = fmaxf(vmax, __shfl_xor(vmax, s, 64));
        }
        if ((threadIdx.x & 63) == 0){
            int im12 = (img/5)*4 + (n-1);
            atomicMin(&misc[im12], f2ord(vmin));
            atomicMax(&misc[12+im12], f2ord(vmax));
        }
    }
}

__global__ __launch_bounds__(256) void k_ent(const float* __restrict__ com,
        float* __restrict__ ent)
{
    int img = blockIdx.y;
    int p = blockIdx.x*256 + threadIdx.x;
    if (p >= PP) return;
    int off[9]; bool val[9];
    tap_setup(p, off, val);
    const float* s = com + (size_t)img*PP;
    float x = s[p];
    float acc = 0.0f;
#pragma unroll
    for (int t=0;t<9;t++){
        float xv = val[t] ? s[off[t]] : 0.0f;   // zero pad
        acc += 1.0f/(1.0f + expf(x - xv));      // sigmoid(xv - x)
    }
    ent[(size_t)img*PP + p] = acc / 9.0f;
}

__global__ __launch_bounds__(256) void k_mask(const float* __restrict__ ent,
        float* __restrict__ maskb, unsigned* __restrict__ misc)
{
    int im12 = blockIdx.y; int bt = im12 >> 2; int n = (im12 & 3) + 1;
    int p = blockIdx.x*256 + threadIdx.x;
    int v = 0;
    if (p < PP){
        float en = ent[(size_t)(bt*5+n)*PP + p];
        float et = ent[(size_t)(bt*5)*PP + p];
        v = en > et;
        maskb[(size_t)im12*PP + p] = (float)v;
    }
    unsigned long long bal = __ballot(v);
    if ((threadIdx.x & 63) == 0) atomicAdd(&misc[24], (unsigned)__popcll(bal));
}

__global__ __launch_bounds__(256) void k_den(const float* __restrict__ maskb,
        float* __restrict__ denb)
{
    int im12 = blockIdx.y;
    int p = blockIdx.x*256 + threadIdx.x;
    if (p >= PP) return;
    int off[9]; bool val[9];
    tap_setup(p, off, val);
    const float* mrow = maskb + (size_t)im12*PP;
    float s = 0.0f;
#pragma unroll
    for (int t=0;t<9;t++) if (val[t]) s += mrow[off[t]];
    denb[(size_t)im12*PP + p] = s;
}

__global__ void k_fin(unsigned* misc, float* bwout){
    int t = threadIdx.x;
    if (t < 12){
        float mn = ord2f(misc[t]);
        float mx = ord2f(misc[12+t]);
        ((int*)misc)[25+t] = (mn + mx == 0.0f) ? 1 : 0;
    }
    if (t == 12) bwout[0] = (float)misc[24] / 480000.0f;
}

// accumulate 32 outputs for one channel's input value xcv, weights at cbase (LDS)
#define ACC32(xcv, cbase) do { \
    const float4* _wr = (const float4*)(cbase); \
    _Pragma("unroll") \
    for (int _o4=0;_o4<8;_o4++){ \
        float4 _wv = _wr[_o4]; \
        acc[_o4*4+0] = fmaf(_wv.x, (xcv), acc[_o4*4+0]); \
        acc[_o4*4+1] = fmaf(_wv.y, (xcv), acc[_o4*4+1]); \
        acc[_o4*4+2] = fmaf(_wv.z, (xcv), acc[_o4*4+2]); \
        acc[_o4*4+3] = fmaf(_wv.w, (xcv), acc[_o4*4+3]); \
    } \
} while(0)

#define FOLD_Z_QUARTER(q) do { \
    _Pragma("unroll") \
    for (int _o=0;_o<32;_o++){ \
        float _v = fmaxf(acc[_o], 0.0f); \
        const float4* _w2r = (const float4*)&w2t[((q)*32+_o)*32]; \
        _Pragma("unroll") \
        for (int _j4=0;_j4<8;_j4++){ \
            float4 _wv = _w2r[_j4]; \
            z[_j4*4+0]=fmaf(_wv.x,_v,z[_j4*4+0]); \
            z[_j4*4+1]=fmaf(_wv.y,_v,z[_j4*4+1]); \
            z[_j4*4+2]=fmaf(_wv.z,_v,z[_j4*4+2]); \
            z[_j4*4+3]=fmaf(_wv.w,_v,z[_j4*4+3]); \
        } \
    } \
} while(0)

#define PWF_TAIL(logit_idx) do { \
    float y3[8]; \
    _Pragma("unroll") \
    for (int k=0;k<8;k++) y3[k]=b3l[k]; \
    _Pragma("unroll") \
    for (int j=0;j<32;j++){ \
        float v = fmaxf(z[j],0.0f); \
        _Pragma("unroll") \
        for (int k=0;k<8;k++) y3[k] = fmaf(w3t[j*8+k], v, y3[k]); \
    } \
    float sres = b4l[0]; \
    _Pragma("unroll") \
    for (int k=0;k<8;k++) sres = fmaf(w4l[k], fmaxf(y3[k],0.0f), sres); \
    logits[(size_t)(logit_idx)*PP + p] = fmaxf(sres, 0.0f); \
} while(0)

#define PWF_SMALL_LOADS() do { \
    for (int i=tid;i<128*32;i+=256){ int o=i>>5, j=i&31; w2t[i] = w2[j*128 + o]; } \
    for (int i=tid;i<32*8;i+=256){ int j=i>>3, k=i&7; w3t[i] = w3[k*32 + j]; } \
    if (tid<8)   w4l[tid]=w4[tid]; \
    if (tid<128) b1l[tid]=b1[tid]; \
    if (tid<32)  b2l[tid]=b2[tid]; \
    if (tid<8)   b3l[tid]=b3[tid]; \
    if (tid==0)  b4l[0]=b4[0]; \
} while(0)

// n=0 branch: u = W1a@tg + b1 (stored), logit0 = pwf([tg;tg])
// 8 phases: quarter q of outputs, half h of input channels (W1a then W1b)
__global__ __launch_bounds__(256,3) void k_pwf0(const float* __restrict__ bevs,
        const float* __restrict__ w1, const float* __restrict__ b1,
        const float* __restrict__ w2, const float* __restrict__ b2,
        const float* __restrict__ w3, const float* __restrict__ b3,
        const float* __restrict__ w4, const float* __restrict__ b4,
        float* __restrict__ ubuf, float* __restrict__ logits)
{
    __shared__ __align__(16) float w1buf[64*32];   // quarter: [c][o32]
    __shared__ __align__(16) float w2t[128*32];
    __shared__ __align__(16) float w3t[32*8];
    __shared__ float w4l[8], b1l[128], b2l[32], b3l[8], b4l[1];
    int bt = blockIdx.y;
    int tid = threadIdx.x;
    PWF_SMALL_LOADS();
    int p = blockIdx.x*256 + tid;
    const float* tg = bevs + (size_t)bt*5*64*PP;
    float xc[64];
    if (p < PP){
#pragma unroll
        for (int c=0;c<64;c++) xc[c] = tg[(size_t)c*PP + p];
    } else {
#pragma unroll
        for (int c=0;c<64;c++) xc[c] = 0.0f;
    }
    __syncthreads();
    float z[32];
#pragma unroll
    for (int j=0;j<32;j++) z[j]=b2l[j];
    float acc[32];
    float* ub = (ubuf && p < PP) ? (ubuf + (size_t)bt*128*PP + p) : nullptr;
#pragma unroll 1
    for (int ph=0; ph<8; ph++){
        int q = ph>>1, half = ph&1;
        __syncthreads();
        for (int i=tid;i<2048;i+=256){ int c=i>>5, o=i&31; w1buf[i] = w1[(q*32+o)*128 + half*64 + c]; }
        __syncthreads();
        if (half==0){
#pragma unroll
            for (int o=0;o<32;o++) acc[o] = b1l[q*32+o];
        }
#pragma unroll
        for (int c=0;c<64;c++) ACC32(xc[c], &w1buf[c*32]);
        if (half==0){
            if (ub){
#pragma unroll
                for (int o=0;o<32;o++) ub[(size_t)(q*32+o)*PP] = acc[o];
            }
        } else {
            FOLD_Z_QUARTER(q);
        }
    }
    if (p >= PP) return;
    PWF_TAIL(bt*5);
}

// n>=1 branches: warp recomputed inline into xc[64];
// MODE 0: u quarter read from ubuf; MODE 1: recompute W1a@tg per quarter
template<int MODE>
__global__ __launch_bounds__(256,3) void k_pwfn(const float* __restrict__ bevs,
        const float* __restrict__ w1, const float* __restrict__ b1,
        const float* __restrict__ w2, const float* __restrict__ b2,
        const float* __restrict__ w3, const float* __restrict__ b3,
        const float* __restrict__ w4, const float* __restrict__ b4,
        const float* __restrict__ maskb, const float* __restrict__ denb,
        const float* __restrict__ ubuf, const unsigned* __restrict__ misc,
        float* __restrict__ logits)
{
    __shared__ __align__(16) float w1buf[64*32];
    __shared__ __align__(16) float w2t[128*32];
    __shared__ __align__(16) float w3t[32*8];
    __shared__ float w4l[8], b1l[128], b2l[32], b3l[8], b4l[1];
    int tid = threadIdx.x;
    PWF_SMALL_LOADS();
    int im12 = blockIdx.y; int bt = im12 >> 2; int n = (im12 & 3) + 1;
    int p = blockIdx.x*256 + tid;
    float xc[64];
    if (p < PP){
        int off[9]; bool val[9];
        tap_setup(p, off, val);
        const float* mrow = maskb + (size_t)im12*PP;
        float m9[9];
#pragma unroll
        for (int t=0;t<9;t++) m9[t] = val[t] ? mrow[off[t]] : 0.0f;
        float rden = 1.0f/(denb[(size_t)im12*PP + p] + NEPS);
        int iz = ((const int*)misc)[25+im12];
        const float* nbb = bevs + (size_t)(bt*5+n)*64*PP;
#pragma unroll
        for (int c=0;c<64;c++){
            const float* sc = nbb + (size_t)c*PP;
            float num = 0.0f, center = 0.0f;
#pragma unroll
            for (int t=0;t<9;t++){
                if (val[t]){
                    float v = sc[off[t]];
                    num = fmaf(m9[t], v, num);
                    if (t==4) center = v;
                }
            }
            float mc = m9[4];
            xc[c] = iz ? center : fmaf(mc, center, (1.0f-mc)*(num*rden));
        }
    } else {
#pragma unroll
        for (int c=0;c<64;c++) xc[c] = 0.0f;
    }
    __syncthreads();
    float z[32];
#pragma unroll
    for (int j=0;j<32;j++) z[j]=b2l[j];
    float acc[32];
    const float* ub = (MODE==0 && p < PP) ? (ubuf + (size_t)bt*128*PP + p) : nullptr;
    const float* tgb = bevs + (size_t)bt*5*64*PP;
#pragma unroll 1
    for (int q=0;q<4;q++){
        if (MODE == 1){
            // W1a quarter with tg from global
            __syncthreads();
            for (int i=tid;i<2048;i+=256){ int c=i>>5, o=i&31; w1buf[i] = w1[(q*32+o)*128 + c]; }
            __syncthreads();
#pragma unroll
            for (int o=0;o<32;o++) acc[o] = b1l[q*32+o];
            if (p < PP){
#pragma unroll
                for (int c=0;c<64;c++){
                    float xv = tgb[(size_t)c*PP + p];
                    ACC32(xv, &w1buf[c*32]);
                }
            }
        }
        // W1b quarter with warp xc
        __syncthreads();
        for (int i=tid;i<2048;i+=256){ int c=i>>5, o=i&31; w1buf[i] = w1[(q*32+o)*128 + 64 + c]; }
        __syncthreads();
        if (MODE == 0){
            if (ub){
#pragma unroll
                for (int o=0;o<32;o++) acc[o] = ub[(size_t)(q*32+o)*PP];
            } else {
#pragma unroll
                for (int o=0;o<32;o++) acc[o] = 0.0f;
            }
        }
#pragma unroll
        for (int c=0;c<64;c++) ACC32(xc[c], &w1buf[c*32]);
        FOLD_Z_QUARTER(q);
    }
    if (p >= PP) return;
    PWF_TAIL(bt*5+n);
}

__global__ __launch_bounds__(256) void k_fuse(const float* __restrict__ bevs,
        const float* __restrict__ logits, const float* __restrict__ maskb,
        const float* __restrict__ denb, const unsigned* __restrict__ misc,
        float* __restrict__ out)
{
    int bt = blockIdx.y;
    int p = blockIdx.x*256 + threadIdx.x;
    if (p >= PP) return;
    int off[9]; bool val[9];
    tap_setup(p, off, val);
    float e[5], ssum = 0.0f;
#pragma unroll
    for (int nn=0;nn<5;nn++){ e[nn] = expf(logits[(size_t)(bt*5+nn)*PP + p]); ssum += e[nn]; }
    float wts[5];
#pragma unroll
    for (int nn=0;nn<5;nn++) wts[nn] = e[nn] / ssum;
    float m9[4][9]; float rden[4]; int iz[4];
#pragma unroll
    for (int k=0;k<4;k++){
        int im12 = bt*4 + k;
        const float* mrow = maskb + (size_t)im12*PP;
#pragma unroll
        for (int t=0;t<9;t++) m9[k][t] = val[t] ? mrow[off[t]] : 0.0f;
        rden[k] = 1.0f/(denb[(size_t)im12*PP + p] + NEPS);
        iz[k] = ((const int*)misc)[25+im12];
    }
    const float* base = bevs + (size_t)bt*5*64*PP;
    for (int c=0;c<64;c++){
        float tgc = base[(size_t)c*PP + p];
        float fused = wts[0]*tgc;
#pragma unroll
        for (int k=0;k<4;k++){
            const float* sc = base + (size_t)(k+1)*64*PP + (size_t)c*PP;
            float num = 0.0f, center = 0.0f;
#pragma unroll
            for (int t=0;t<9;t++){
                if (val[t]){
                    float v = sc[off[t]];
                    num = fmaf(m9[k][t], v, num);
                    if (t==4) center = v;
                }
            }
            float mc = m9[k][4];
            float xc = iz[k] ? center : fmaf(mc, center, (1.0f-mc)*(num*rden[k]));
            fused = fmaf(wts[k+1], xc, fused);
        }
        out[((size_t)bt*64 + c)*PP + p] = fused;
    }
}

extern "C" void kernel_launch(void* const* d_in, const int* in_sizes, int n_in,
                              void* d_out, int out_size, void* d_ws, size_t ws_size,
                              hipStream_t stream)
{
    const float* bevs = (const float*)d_in[0];
    const float* cw  = (const float*)d_in[1];
    const float* cb  = (const float*)d_in[2];
    const float* w1  = (const float*)d_in[3];
    const float* b1  = (const float*)d_in[4];
    const float* w2  = (const float*)d_in[5];
    const float* b2  = (const float*)d_in[6];
    const float* w3  = (const float*)d_in[7];
    const float* b3  = (const float*)d_in[8];
    const float* w4  = (const float*)d_in[9];
    const float* b4  = (const float*)d_in[10];
    float* out = (float*)d_out;
    float* ws = (float*)d_ws;

    bool useU = ws_size >= (size_t)(MISC_FULL + 64) * 4;
    float* com    = ws + OFF_COM;
    float* ent    = ws + OFF_ENT;
    float* maskb  = ws + OFF_MASK;
    float* denb   = ws + OFF_DEN;
    float* logits = ws + OFF_LOGITS;
    float* ubuf   = useU ? (ws + OFF_U) : nullptr;
    unsigned* misc = (unsigned*)(ws + (useU ? MISC_FULL : MISC_MIN));

    dim3 blk(256,1,1);
    int gx = (PP + 255)/256;

    k_init<<<dim3(1),dim3(64),0,stream>>>(misc);
    k_conv<<<dim3(gx,15),blk,0,stream>>>(bevs,cw,cb,com,misc);
    k_ent <<<dim3(gx,15),blk,0,stream>>>(com,ent);
    k_mask<<<dim3(gx,12),blk,0,stream>>>(ent,maskb,misc);
    k_den <<<dim3(gx,12),blk,0,stream>>>(maskb,denb);
    k_fin <<<dim3(1),dim3(64),0,stream>>>(misc, out + (size_t)3*64*PP);
    k_pwf0<<<dim3(gx,3),blk,0,stream>>>(bevs,w1,b1,w2,b2,w3,b3,w4,b4,ubuf,logits);
    if (useU)
        k_pwfn<0><<<dim3(gx,12),blk,0,stream>>>(bevs,w1,b1,w2,b2,w3,b3,w4,b4,maskb,denb,ubuf,misc,logits);
    else
        k_pwfn<1><<<dim3(gx,12),blk,0,stream>>>(bevs,w1,b1,w2,b2,w3,b3,w4,b4,maskb,denb,ubuf,misc,logits);
    k_fuse<<<dim3(gx,3),blk,0,stream>>>(bevs,logits,maskb,denb,misc,out);
}

// Round 3
// 1662.293 us; speedup vs baseline: 1.2882x; 1.2882x over previous
//
#include <hip/hip_runtime.h>
#include <hip/hip_bf16.h>
#include <math.h>

#define PP 40000
#define HDIM 200
#define WDIM 200
#define NEPS 1e-8f

// workspace layout (float offsets)
#define OFF_COM    0            // 15*PP
#define OFF_ENT    (15*PP)      // 15*PP
#define OFF_MASK   (30*PP)      // 12*PP
#define OFF_DEN    (42*PP)      // 12*PP
#define OFF_LOGITS (54*PP)      // 15*PP
#define OFF_MISC   (69*PP)
// misc (uint slots): [0..11] min_ord, [12..23] max_ord, [24] count, [25..36] iszero

typedef __attribute__((ext_vector_type(8))) short bf16x8;
typedef __attribute__((ext_vector_type(4))) float f32x4;

__device__ __forceinline__ short f2bf(float f){
    __hip_bfloat16 h = __float2bfloat16(f);   // RTNE
    return *reinterpret_cast<short*>(&h);
}

__device__ __forceinline__ unsigned f2ord(float f){
    unsigned u = __float_as_uint(f);
    return (u & 0x80000000u) ? ~u : (u | 0x80000000u);
}
__device__ __forceinline__ float ord2f(unsigned u){
    unsigned v = (u & 0x80000000u) ? (u & 0x7fffffffu) : ~u;
    return __uint_as_float(v);
}

__device__ __forceinline__ void tap_setup(int p, int* off, bool* val){
    int h = p / WDIM, w = p - h*WDIM;
#pragma unroll
    for (int ky=0;ky<3;ky++)
#pragma unroll
        for (int kx=0;kx<3;kx++){
            int t = ky*3+kx;
            int hh = h+ky-1, ww = w+kx-1;
            val[t] = (hh>=0)&&(hh<HDIM)&&(ww>=0)&&(ww<WDIM);
            off[t] = hh*WDIM+ww;
        }
}

__global__ void k_init(unsigned* misc){
    int t = threadIdx.x;
    if (t < 12) misc[t] = 0xFFFFFFFFu;        // min (sortable) = +inf
    else if (t < 25) misc[t] = 0u;            // max = -inf, count = 0
}

// compress conv3x3 (64->1) + relu, fused per-image min/max of raw nb values
__global__ __launch_bounds__(256) void k_conv(const float* __restrict__ bevs,
        const float* __restrict__ cw, const float* __restrict__ cb,
        float* __restrict__ com, unsigned* __restrict__ misc)
{
    __shared__ float wl[576];
    int img = blockIdx.y;          // 0..14 = bt*5+n
    int n = img % 5;
    for (int i = threadIdx.x; i < 576; i += 256) wl[i] = cw[i];
    __syncthreads();
    int p = blockIdx.x*256 + threadIdx.x;
    float vmin = INFINITY, vmax = -INFINITY;
    if (p < PP){
        int off[9]; bool val[9];
        tap_setup(p, off, val);
        const float* src = bevs + (size_t)img*64*PP;
        float acc = cb[0];
        for (int c=0;c<64;c++){
            const float* sc = src + (size_t)c*PP;
            const float* wc = &wl[c*9];
#pragma unroll
            for (int t=0;t<9;t++){
                if (val[t]){
                    float v = sc[off[t]];
                    acc = fmaf(wc[t], v, acc);
                    vmin = fminf(vmin, v); vmax = fmaxf(vmax, v);
                }
            }
        }
        com[(size_t)img*PP + p] = fmaxf(acc, 0.0f);
    }
    if (n > 0){
#pragma unroll
        for (int s=32;s>0;s>>=1){
            vmin = fminf(vmin, __shfl_xor(vmin, s, 64));
            vmax = fmaxf(vmax, __shfl_xor(vmax, s, 64));
        }
        if ((threadIdx.x & 63) == 0){
            int im12 = (img/5)*4 + (n-1);
            atomicMin(&misc[im12], f2ord(vmin));
            atomicMax(&misc[12+im12], f2ord(vmax));
        }
    }
}

__global__ __launch_bounds__(256) void k_ent(const float* __restrict__ com,
        float* __restrict__ ent)
{
    int img = blockIdx.y;
    int p = blockIdx.x*256 + threadIdx.x;
    if (p >= PP) return;
    int off[9]; bool val[9];
    tap_setup(p, off, val);
    const float* s = com + (size_t)img*PP;
    float x = s[p];
    float acc = 0.0f;
#pragma unroll
    for (int t=0;t<9;t++){
        float xv = val[t] ? s[off[t]] : 0.0f;   // zero pad
        acc += 1.0f/(1.0f + expf(x - xv));      // sigmoid(xv - x)
    }
    ent[(size_t)img*PP + p] = acc / 9.0f;
}

__global__ __launch_bounds__(256) void k_mask(const float* __restrict__ ent,
        float* __restrict__ maskb, unsigned* __restrict__ misc)
{
    int im12 = blockIdx.y; int bt = im12 >> 2; int n = (im12 & 3) + 1;
    int p = blockIdx.x*256 + threadIdx.x;
    int v = 0;
    if (p < PP){
        float en = ent[(size_t)(bt*5+n)*PP + p];
        float et = ent[(size_t)(bt*5)*PP + p];
        v = en > et;
        maskb[(size_t)im12*PP + p] = (float)v;
    }
    unsigned long long bal = __ballot(v);
    if ((threadIdx.x & 63) == 0) atomicAdd(&misc[24], (unsigned)__popcll(bal));
}

__global__ __launch_bounds__(256) void k_den(const float* __restrict__ maskb,
        float* __restrict__ denb)
{
    int im12 = blockIdx.y;
    int p = blockIdx.x*256 + threadIdx.x;
    if (p >= PP) return;
    int off[9]; bool val[9];
    tap_setup(p, off, val);
    const float* mrow = maskb + (size_t)im12*PP;
    float s = 0.0f;
#pragma unroll
    for (int t=0;t<9;t++) if (val[t]) s += mrow[off[t]];
    denb[(size_t)im12*PP + p] = s;
}

__global__ void k_fin(unsigned* misc, float* bwout){
    int t = threadIdx.x;
    if (t < 12){
        float mn = ord2f(misc[t]);
        float mx = ord2f(misc[12+t]);
        ((int*)misc)[25+t] = (mn + mx == 0.0f) ? 1 : 0;
    }
    if (t == 12) bwout[0] = (float)misc[24] / 480000.0f;
}

// ---------------------------------------------------------------------------
// Fused pwf: all 15 images, MFMA bf16 layers 1-2, fp32 scalar tail (layers 3-4)
// Per block: 64-pixel tile of one image. X = [tg ; feat] built in LDS bf16.
// LDS rows padded to 136 shorts (272 B) -> conflict-free ds_read_b128.
// Each wave: its own 16-px m-tile, full N=128 (L1) then N=32 (L2).
// ---------------------------------------------------------------------------
__global__ __launch_bounds__(256) void k_pwf(const float* __restrict__ bevs,
        const float* __restrict__ w1, const float* __restrict__ b1,
        const float* __restrict__ w2, const float* __restrict__ b2,
        const float* __restrict__ w3, const float* __restrict__ b3,
        const float* __restrict__ w4, const float* __restrict__ b4,
        const float* __restrict__ maskb, const float* __restrict__ denb,
        const unsigned* __restrict__ misc, float* __restrict__ logits)
{
    __shared__ __align__(16) short w1t[128*136];
    __shared__ __align__(16) short w2t[32*136];
    __shared__ __align__(16) short xt[64*136];
    __shared__ __align__(16) float z2[64*33];
    __shared__ float b1l[128], b2l[32], b3l[8], w3l[256], w4l[8], b4l[1];

    int tid = threadIdx.x;
    int img = blockIdx.y, bt = img/5, n = img%5;

    // stage weights (bf16 for MFMA layers, fp32 for tail)
    for (int i=tid;i<16384;i+=256) w1t[(i>>7)*136 + (i&127)] = f2bf(w1[i]);
    for (int i=tid;i<4096;i+=256)  w2t[(i>>7)*136 + (i&127)] = f2bf(w2[i]);
    if (tid<128) b1l[tid]=b1[tid];
    if (tid<32)  b2l[tid]=b2[tid];
    if (tid<8)   b3l[tid]=b3[tid];
    if (tid<256) w3l[tid]=w3[tid];
    if (tid<8)   w4l[tid]=w4[tid];
    if (tid==0)  b4l[0]=b4[0];

    // ---- X fill: 64 px, 128 ch; thread (px = tid&63, q = tid>>6) does 16 ch
    int px = tid&63, q = tid>>6;
    int p = blockIdx.x*64 + px;
    const float* tg = bevs + (size_t)bt*5*64*PP;
    if (n == 0){
#pragma unroll
        for (int ci=0;ci<16;ci++){
            int c = q*16+ci;
            short v = f2bf(tg[(size_t)c*PP + p]);
            xt[px*136 + c] = v;
            xt[px*136 + 64 + c] = v;
        }
    } else {
        int im12 = bt*4 + (n-1);
        int off[9]; bool val[9];
        tap_setup(p, off, val);
        const float* mrow = maskb + (size_t)im12*PP;
        float m9[9];
#pragma unroll
        for (int t=0;t<9;t++) m9[t] = val[t] ? mrow[off[t]] : 0.0f;
        float rden = 1.0f/(denb[(size_t)im12*PP + p] + NEPS);
        int iz = ((const int*)misc)[25+im12];
        float mc = m9[4];
        const float* nbb = bevs + (size_t)(bt*5+n)*64*PP;
#pragma unroll
        for (int ci=0;ci<16;ci++){
            int c = q*16+ci;
            xt[px*136 + c] = f2bf(tg[(size_t)c*PP + p]);
            const float* sc = nbb + (size_t)c*PP;
            float num = 0.0f, center = 0.0f;
#pragma unroll
            for (int t=0;t<9;t++){
                if (val[t]){
                    float v = sc[off[t]];
                    num = fmaf(m9[t], v, num);
                    if (t==4) center = v;
                }
            }
            float xc = iz ? center : fmaf(mc, center, (1.0f-mc)*(num*rden));
            xt[px*136 + 64 + c] = f2bf(xc);
        }
    }
    __syncthreads();

    // ---- layer 1: per-wave 16-px m-tile, N=128 (8 n-tiles), K=128 (4 k-steps)
    int w = tid>>6, l = tid&63;
    int ln = l&15, kg = l>>4;          // ln: A-row / B-col / D-col; kg: k-group
    bf16x8 af[4];
#pragma unroll
    for (int ks=0;ks<4;ks++)
        af[ks] = *(const bf16x8*)&xt[(w*16+ln)*136 + ks*32 + kg*8];
#pragma unroll
    for (int nt=0;nt<8;nt++){
        float bias = b1l[nt*16 + ln];
        f32x4 acc = {bias, bias, bias, bias};
#pragma unroll
        for (int ks=0;ks<4;ks++){
            bf16x8 bf = *(const bf16x8*)&w1t[(nt*16+ln)*136 + ks*32 + kg*8];
            acc = __builtin_amdgcn_mfma_f32_16x16x32_bf16(af[ks], bf, acc, 0, 0, 0);
        }
        // X2 = relu(L1 out) -> back into xt (wave-local region only)
#pragma unroll
        for (int r=0;r<4;r++){
            int pr = w*16 + kg*4 + r;
            xt[pr*136 + nt*16 + ln] = f2bf(fmaxf(acc[r], 0.0f));
        }
    }

    // ---- layer 2: A = X2 (own wave's rows), N=32 (2 n-tiles), K=128
    bf16x8 a2[4];
#pragma unroll
    for (int ks=0;ks<4;ks++)
        a2[ks] = *(const bf16x8*)&xt[(w*16+ln)*136 + ks*32 + kg*8];
#pragma unroll
    for (int nt2=0;nt2<2;nt2++){
        float bias = b2l[nt2*16 + ln];
        f32x4 acc = {bias, bias, bias, bias};
#pragma unroll
        for (int ks=0;ks<4;ks++){
            bf16x8 bf = *(const bf16x8*)&w2t[(nt2*16+ln)*136 + ks*32 + kg*8];
            acc = __builtin_amdgcn_mfma_f32_16x16x32_bf16(a2[ks], bf, acc, 0, 0, 0);
        }
#pragma unroll
        for (int r=0;r<4;r++){
            int pr = w*16 + kg*4 + r;
            z2[pr*33 + nt2*16 + ln] = fmaxf(acc[r], 0.0f);
        }
    }
    __syncthreads();

    // ---- tail: layers 3 (32->8) + 4 (8->1), fp32, one thread per pixel
    if (tid < 64){
        float y3[8];
#pragma unroll
        for (int k=0;k<8;k++) y3[k] = b3l[k];
        for (int j=0;j<32;j++){
            float v = z2[tid*33 + j];
#pragma unroll
            for (int k=0;k<8;k++) y3[k] = fmaf(w3l[k*32+j], v, y3[k]);
        }
        float sres = b4l[0];
#pragma unroll
        for (int k=0;k<8;k++) sres = fmaf(w4l[k], fmaxf(y3[k], 0.0f), sres);
        logits[(size_t)img*PP + blockIdx.x*64 + tid] = fmaxf(sres, 0.0f);
    }
}

__global__ __launch_bounds__(256) void k_fuse(const float* __restrict__ bevs,
        const float* __restrict__ logits, const float* __restrict__ maskb,
        const float* __restrict__ denb, const unsigned* __restrict__ misc,
        float* __restrict__ out)
{
    int bt = blockIdx.y;
    int p = blockIdx.x*256 + threadIdx.x;
    if (p >= PP) return;
    int off[9]; bool val[9];
    tap_setup(p, off, val);
    float e[5], ssum = 0.0f;
#pragma unroll
    for (int nn=0;nn<5;nn++){ e[nn] = expf(logits[(size_t)(bt*5+nn)*PP + p]); ssum += e[nn]; }
    float wts[5];
#pragma unroll
    for (int nn=0;nn<5;nn++) wts[nn] = e[nn] / ssum;
    float m9[4][9]; float rden[4]; int iz[4];
#pragma unroll
    for (int k=0;k<4;k++){
        int im12 = bt*4 + k;
        const float* mrow = maskb + (size_t)im12*PP;
#pragma unroll
        for (int t=0;t<9;t++) m9[k][t] = val[t] ? mrow[off[t]] : 0.0f;
        rden[k] = 1.0f/(denb[(size_t)im12*PP + p] + NEPS);
        iz[k] = ((const int*)misc)[25+im12];
    }
    const float* base = bevs + (size_t)bt*5*64*PP;
    for (int c=0;c<64;c++){
        float tgc = base[(size_t)c*PP + p];
        float fused = wts[0]*tgc;
#pragma unroll
        for (int k=0;k<4;k++){
            const float* sc = base + (size_t)(k+1)*64*PP + (size_t)c*PP;
            float num = 0.0f, center = 0.0f;
#pragma unroll
            for (int t=0;t<9;t++){
                if (val[t]){
                    float v = sc[off[t]];
                    num = fmaf(m9[k][t], v, num);
                    if (t==4) center = v;
                }
            }
            float mc = m9[k][4];
            float xc = iz[k] ? center : fmaf(mc, center, (1.0f-mc)*(num*rden[k]));
            fused = fmaf(wts[k+1], xc, fused);
        }
        out[((size_t)bt*64 + c)*PP + p] = fused;
    }
}

extern "C" void kernel_launch(void* const* d_in, const int* in_sizes, int n_in,
                              void* d_out, int out_size, void* d_ws, size_t ws_size,
                              hipStream_t stream)
{
    const float* bevs = (const float*)d_in[0];
    const float* cw  = (const float*)d_in[1];
    const float* cb  = (const float*)d_in[2];
    const float* w1  = (const float*)d_in[3];
    const float* b1  = (const float*)d_in[4];
    const float* w2  = (const float*)d_in[5];
    const float* b2  = (const float*)d_in[6];
    const float* w3  = (const float*)d_in[7];
    const float* b3  = (const float*)d_in[8];
    const float* w4  = (const float*)d_in[9];
    const float* b4  = (const float*)d_in[10];
    float* out = (float*)d_out;
    float* ws = (float*)d_ws;

    float* com    = ws + OFF_COM;
    float* ent    = ws + OFF_ENT;
    float* maskb  = ws + OFF_MASK;
    float* denb   = ws + OFF_DEN;
    float* logits = ws + OFF_LOGITS;
    unsigned* misc = (unsigned*)(ws + OFF_MISC);

    dim3 blk(256,1,1);
    int gx = (PP + 255)/256;

    k_init<<<dim3(1),dim3(64),0,stream>>>(misc);
    k_conv<<<dim3(gx,15),blk,0,stream>>>(bevs,cw,cb,com,misc);
    k_ent <<<dim3(gx,15),blk,0,stream>>>(com,ent);
    k_mask<<<dim3(gx,12),blk,0,stream>>>(ent,maskb,misc);
    k_den <<<dim3(gx,12),blk,0,stream>>>(maskb,denb);
    k_fin <<<dim3(1),dim3(64),0,stream>>>(misc, out + (size_t)3*64*PP);
    k_pwf <<<dim3(PP/64,15),blk,0,stream>>>(bevs,w1,b1,w2,b2,w3,b3,w4,b4,maskb,denb,misc,logits);
    k_fuse<<<dim3(gx,3),blk,0,stream>>>(bevs,logits,maskb,denb,misc,out);
}

// Round 4
// 831.158 us; speedup vs baseline: 2.5763x; 2.0000x over previous
//
#include <hip/hip_runtime.h>
#include <hip/hip_bf16.h>
#include <math.h>

#define PP 40000
#define HDIM 200
#define WDIM 200
#define NEPS 1e-8f

// workspace layout (float offsets)
#define OFF_COM    0            // 15*PP
#define OFF_ENT    (15*PP)      // 15*PP
#define OFF_MASK   (30*PP)      // 12*PP
#define OFF_DEN    (42*PP)      // 12*PP
#define OFF_LOGITS (54*PP)      // 15*PP
#define OFF_MISC   (69*PP)      // 64 floats
#define OFF_X_F    (69*PP + 64) // X bf16: 15*PP*128 shorts
// bytes needed for new path:
#define WS_NEED ((size_t)(69*PP + 64)*4 + (size_t)15*PP*128*2)

typedef __attribute__((ext_vector_type(8))) short bf16x8;
typedef __attribute__((ext_vector_type(4))) float f32x4;

__device__ __forceinline__ short f2bf(float f){
    __hip_bfloat16 h = __float2bfloat16(f);   // RTNE
    return *reinterpret_cast<short*>(&h);
}
__device__ __forceinline__ float bf2f(short s){
    return __uint_as_float(((unsigned)(unsigned short)s) << 16);
}

__device__ __forceinline__ unsigned f2ord(float f){
    unsigned u = __float_as_uint(f);
    return (u & 0x80000000u) ? ~u : (u | 0x80000000u);
}
__device__ __forceinline__ float ord2f(unsigned u){
    unsigned v = (u & 0x80000000u) ? (u & 0x7fffffffu) : ~u;
    return __uint_as_float(v);
}

__device__ __forceinline__ void tap_setup(int p, int* off, bool* val){
    int h = p / WDIM, w = p - h*WDIM;
#pragma unroll
    for (int ky=0;ky<3;ky++)
#pragma unroll
        for (int kx=0;kx<3;kx++){
            int t = ky*3+kx;
            int hh = h+ky-1, ww = w+kx-1;
            val[t] = (hh>=0)&&(hh<HDIM)&&(ww>=0)&&(ww<WDIM);
            off[t] = hh*WDIM+ww;
        }
}

__global__ void k_init(unsigned* misc){
    int t = threadIdx.x;
    if (t < 12) misc[t] = 0xFFFFFFFFu;        // min (sortable) = +inf
    else if (t < 25) misc[t] = 0u;            // max = -inf, count = 0
}

// compress conv3x3 (64->1) + relu; per-image min/max via center tap only
__global__ __launch_bounds__(256) void k_conv(const float* __restrict__ bevs,
        const float* __restrict__ cw, const float* __restrict__ cb,
        float* __restrict__ com, unsigned* __restrict__ misc)
{
    __shared__ float wl[576];
    int img = blockIdx.y;          // 0..14 = bt*5+n
    int n = img % 5;
    for (int i = threadIdx.x; i < 576; i += 256) wl[i] = cw[i];
    __syncthreads();
    int p = blockIdx.x*256 + threadIdx.x;
    float vmin = INFINITY, vmax = -INFINITY;
    if (p < PP){
        int off[9]; bool val[9];
        tap_setup(p, off, val);
        const float* src = bevs + (size_t)img*64*PP;
        float acc = cb[0];
        for (int c=0;c<64;c++){
            const float* sc = src + (size_t)c*PP;
            float center = sc[p];
            vmin = fminf(vmin, center); vmax = fmaxf(vmax, center);
#pragma unroll
            for (int t=0;t<9;t++){
                if (val[t]){
                    float v = (t==4) ? center : sc[off[t]];
                    acc = fmaf(wl[c*9+t], v, acc);
                }
            }
        }
        com[(size_t)img*PP + p] = fmaxf(acc, 0.0f);
    }
    if (n > 0){
#pragma unroll
        for (int s=32;s>0;s>>=1){
            vmin = fminf(vmin, __shfl_xor(vmin, s, 64));
            vmax = fmaxf(vmax, __shfl_xor(vmax, s, 64));
        }
        if ((threadIdx.x & 63) == 0){
            int im12 = (img/5)*4 + (n-1);
            atomicMin(&misc[im12], f2ord(vmin));
            atomicMax(&misc[12+im12], f2ord(vmax));
        }
    }
}

__global__ __launch_bounds__(256) void k_ent(const float* __restrict__ com,
        float* __restrict__ ent)
{
    int img = blockIdx.y;
    int p = blockIdx.x*256 + threadIdx.x;
    if (p >= PP) return;
    int off[9]; bool val[9];
    tap_setup(p, off, val);
    const float* s = com + (size_t)img*PP;
    float x = s[p];
    float acc = 0.0f;
#pragma unroll
    for (int t=0;t<9;t++){
        float xv = val[t] ? s[off[t]] : 0.0f;   // zero pad
        acc += 1.0f/(1.0f + expf(x - xv));      // sigmoid(xv - x)
    }
    ent[(size_t)img*PP + p] = acc / 9.0f;
}

__global__ __launch_bounds__(256) void k_mask(const float* __restrict__ ent,
        float* __restrict__ maskb, unsigned* __restrict__ misc)
{
    int im12 = blockIdx.y; int bt = im12 >> 2; int n = (im12 & 3) + 1;
    int p = blockIdx.x*256 + threadIdx.x;
    int v = 0;
    if (p < PP){
        float en = ent[(size_t)(bt*5+n)*PP + p];
        float et = ent[(size_t)(bt*5)*PP + p];
        v = en > et;
        maskb[(size_t)im12*PP + p] = (float)v;
    }
    unsigned long long bal = __ballot(v);
    if ((threadIdx.x & 63) == 0) atomicAdd(&misc[24], (unsigned)__popcll(bal));
}

__global__ __launch_bounds__(256) void k_den(const float* __restrict__ maskb,
        float* __restrict__ denb)
{
    int im12 = blockIdx.y;
    int p = blockIdx.x*256 + threadIdx.x;
    if (p >= PP) return;
    int off[9]; bool val[9];
    tap_setup(p, off, val);
    const float* mrow = maskb + (size_t)im12*PP;
    float s = 0.0f;
#pragma unroll
    for (int t=0;t<9;t++) if (val[t]) s += mrow[off[t]];
    denb[(size_t)im12*PP + p] = s;
}

__global__ void k_fin(unsigned* misc, float* bwout){
    int t = threadIdx.x;
    if (t < 12){
        float mn = ord2f(misc[t]);
        float mx = ord2f(misc[12+t]);
        ((int*)misc)[25+t] = (mn + mx == 0.0f) ? 1 : 0;
    }
    if (t == 12) bwout[0] = (float)misc[24] / 480000.0f;
}

// ---------------------------------------------------------------------------
// k_xgen: materialize X[img][px][128] bf16, X = [tg(64) ; feat(64)]
// block = 64 px, 256 threads: thread (px = tid>>2, q = tid&3) handles 16 ch.
// grid (625, 15)
// ---------------------------------------------------------------------------
__global__ __launch_bounds__(256) void k_xgen(const float* __restrict__ bevs,
        const float* __restrict__ maskb, const float* __restrict__ denb,
        const unsigned* __restrict__ misc, short* __restrict__ X)
{
    int tid = threadIdx.x;
    int img = blockIdx.y, bt = img/5, n = img%5;
    int px = blockIdx.x*64 + (tid>>2);
    int q = tid&3;
    int cb = q*16;
    const float* tg = bevs + (size_t)bt*5*64*PP;
    short* xr = X + ((size_t)img*PP + px)*128;

    short tgv[16];
#pragma unroll
    for (int ci=0;ci<16;ci++) tgv[ci] = f2bf(tg[(size_t)(cb+ci)*PP + px]);
    // store tg-half
    *(bf16x8*)&xr[cb]     = *(bf16x8*)&tgv[0];
    *(bf16x8*)&xr[cb + 8] = *(bf16x8*)&tgv[8];

    short fv[16];
    if (n == 0){
#pragma unroll
        for (int ci=0;ci<16;ci++) fv[ci] = tgv[ci];
    } else {
        int im12 = bt*4 + (n-1);
        int off[9]; bool val[9];
        tap_setup(px, off, val);
        const float* mrow = maskb + (size_t)im12*PP;
        float m9[9];
#pragma unroll
        for (int t=0;t<9;t++) m9[t] = val[t] ? mrow[off[t]] : 0.0f;
        float rden = 1.0f/(denb[(size_t)im12*PP + px] + NEPS);
        int iz = ((const int*)misc)[25+im12];
        float mc = m9[4];
        const float* nbb = bevs + (size_t)(bt*5+n)*64*PP;
#pragma unroll
        for (int ci=0;ci<16;ci++){
            const float* sc = nbb + (size_t)(cb+ci)*PP;
            float num = 0.0f, center = 0.0f;
#pragma unroll
            for (int t=0;t<9;t++){
                if (val[t]){
                    float v = sc[off[t]];
                    num = fmaf(m9[t], v, num);
                    if (t==4) center = v;
                }
            }
            float xc = iz ? center : fmaf(mc, center, (1.0f-mc)*(num*rden));
            fv[ci] = f2bf(xc);
        }
    }
    *(bf16x8*)&xr[64 + cb]     = *(bf16x8*)&fv[0];
    *(bf16x8*)&xr[64 + cb + 8] = *(bf16x8*)&fv[8];
}

// ---------------------------------------------------------------------------
// k_mlp: GEMM on X. block = 256 px (4 waves x 64 px = 4 m-tiles of 16).
// Weights staged once per block; A-frags direct from global X; per-wave
// private xt2/z2 LDS regions -> no barriers in the main loop.
// grid (157, 15)
// ---------------------------------------------------------------------------
__global__ __launch_bounds__(256) void k_mlp(const short* __restrict__ X,
        const float* __restrict__ w1, const float* __restrict__ b1,
        const float* __restrict__ w2, const float* __restrict__ b2,
        const float* __restrict__ w3, const float* __restrict__ b3,
        const float* __restrict__ w4, const float* __restrict__ b4,
        float* __restrict__ logits)
{
    __shared__ __align__(16) short w1t[128*136];
    __shared__ __align__(16) short w2t[32*136];
    __shared__ __align__(16) short xt2[4*16*136];
    __shared__ __align__(16) float z2[4*16*33];
    __shared__ float b1l[128], b2l[32], b3l[8], w3l[8*33], w4l[8], b4l[1];

    int tid = threadIdx.x;
    int img = blockIdx.y;

    for (int i=tid;i<16384;i+=256) w1t[(i>>7)*136 + (i&127)] = f2bf(w1[i]);
    for (int i=tid;i<4096;i+=256)  w2t[(i>>7)*136 + (i&127)] = f2bf(w2[i]);
    for (int i=tid;i<256;i+=256)   { }
    if (tid<256) w3l[(tid>>5)*33 + (tid&31)] = w3[tid];
    if (tid<128) b1l[tid]=b1[tid];
    if (tid<32)  b2l[tid]=b2[tid];
    if (tid<8)   b3l[tid]=b3[tid];
    if (tid<8)   w4l[tid]=w4[tid];
    if (tid==0)  b4l[0]=b4[0];
    __syncthreads();

    int w = tid>>6, l = tid&63;
    int ln = l&15, kg = l>>4;
    const short* Ximg = X + (size_t)img*PP*128;
    short* xt2w = &xt2[w*16*136];
    float* z2w  = &z2[w*16*33];
    int px_base = blockIdx.x*256 + w*64;

#pragma unroll 1
    for (int mt=0; mt<4; mt++){
        int prow = px_base + mt*16;
        int arow = prow + ln; if (arow > PP-1) arow = PP-1;
        const short* xr = Ximg + (size_t)arow*128;
        bf16x8 af[4];
#pragma unroll
        for (int ks=0;ks<4;ks++)
            af[ks] = *(const bf16x8*)&xr[ks*32 + kg*8];

        // layer 1: N=128 (8 n-tiles), K=128
#pragma unroll
        for (int nt=0;nt<8;nt++){
            float bias = b1l[nt*16 + ln];
            f32x4 acc = {bias, bias, bias, bias};
#pragma unroll
            for (int ks=0;ks<4;ks++){
                bf16x8 bf = *(const bf16x8*)&w1t[(nt*16+ln)*136 + ks*32 + kg*8];
                acc = __builtin_amdgcn_mfma_f32_16x16x32_bf16(af[ks], bf, acc, 0, 0, 0);
            }
#pragma unroll
            for (int r=0;r<4;r++)
                xt2w[(kg*4+r)*136 + nt*16 + ln] = f2bf(fmaxf(acc[r], 0.0f));
        }

        // layer 2: N=32, K=128 (A = X2 from per-wave LDS)
        bf16x8 a2[4];
#pragma unroll
        for (int ks=0;ks<4;ks++)
            a2[ks] = *(const bf16x8*)&xt2w[ln*136 + ks*32 + kg*8];
#pragma unroll
        for (int nt2=0;nt2<2;nt2++){
            float bias = b2l[nt2*16 + ln];
            f32x4 acc = {bias, bias, bias, bias};
#pragma unroll
            for (int ks=0;ks<4;ks++){
                bf16x8 bf = *(const bf16x8*)&w2t[(nt2*16+ln)*136 + ks*32 + kg*8];
                acc = __builtin_amdgcn_mfma_f32_16x16x32_bf16(a2[ks], bf, acc, 0, 0, 0);
            }
#pragma unroll
            for (int r=0;r<4;r++)
                z2w[(kg*4+r)*33 + nt2*16 + ln] = fmaxf(acc[r], 0.0f);
        }

        // tail: lane (px16 = ln, k-pair = kg): y3 for k = 2kg, 2kg+1
        int k0 = kg*2, k1 = kg*2+1;
        float y0 = b3l[k0], y1 = b3l[k1];
#pragma unroll
        for (int j=0;j<32;j++){
            float v = z2w[ln*33 + j];
            y0 = fmaf(w3l[k0*33+j], v, y0);
            y1 = fmaf(w3l[k1*33+j], v, y1);
        }
        float part = w4l[k0]*fmaxf(y0,0.0f) + w4l[k1]*fmaxf(y1,0.0f);
        part += __shfl_xor(part, 16, 64);
        part += __shfl_xor(part, 32, 64);
        if (kg == 0 && prow + ln < PP)
            logits[(size_t)img*PP + prow + ln] = fmaxf(part + b4l[0], 0.0f);
    }
}

// ---------------------------------------------------------------------------
// k_fuse2: softmax over logits + weighted sum of feats (tg fp32, warp bf16 from X)
// grid (157, 3, 2): 32-ch groups
// ---------------------------------------------------------------------------
__global__ __launch_bounds__(256) void k_fuse2(const float* __restrict__ bevs,
        const float* __restrict__ logits, const short* __restrict__ X,
        float* __restrict__ out)
{
    int bt = blockIdx.y;
    int cb = blockIdx.z*32;
    int p = blockIdx.x*256 + threadIdx.x;
    if (p >= PP) return;
    float e[5], ssum = 0.0f;
#pragma unroll
    for (int nn=0;nn<5;nn++){ e[nn] = expf(logits[(size_t)(bt*5+nn)*PP + p]); ssum += e[nn]; }
    float rs = 1.0f/ssum;
    const float* tgb = bevs + (size_t)bt*5*64*PP;
    float acc[32];
    float w0 = e[0]*rs;
#pragma unroll
    for (int ci=0;ci<32;ci++) acc[ci] = w0*tgb[(size_t)(cb+ci)*PP + p];
#pragma unroll
    for (int k=0;k<4;k++){
        float wk = e[k+1]*rs;
        const short* Xr = X + ((size_t)(bt*5+k+1)*PP + p)*128 + 64 + cb;
#pragma unroll
        for (int c8=0;c8<4;c8++){
            bf16x8 v = *(const bf16x8*)&Xr[c8*8];
#pragma unroll
            for (int j=0;j<8;j++)
                acc[c8*8+j] = fmaf(wk, bf2f(v[j]), acc[c8*8+j]);
        }
    }
#pragma unroll
    for (int ci=0;ci<32;ci++)
        out[((size_t)bt*64 + cb+ci)*PP + p] = acc[ci];
}

// ---------------------------------------------------------------------------
// FALLBACK path (round-3 fused kernels) if ws too small for X
// ---------------------------------------------------------------------------
__global__ __launch_bounds__(256) void k_pwf(const float* __restrict__ bevs,
        const float* __restrict__ w1, const float* __restrict__ b1,
        const float* __restrict__ w2, const float* __restrict__ b2,
        const float* __restrict__ w3, const float* __restrict__ b3,
        const float* __restrict__ w4, const float* __restrict__ b4,
        const float* __restrict__ maskb, const float* __restrict__ denb,
        const unsigned* __restrict__ misc, float* __restrict__ logits)
{
    __shared__ __align__(16) short w1t[128*136];
    __shared__ __align__(16) short w2t[32*136];
    __shared__ __align__(16) short xt[64*136];
    __shared__ __align__(16) float z2[64*33];
    __shared__ float b1l[128], b2l[32], b3l[8], w3l[256], w4l[8], b4l[1];

    int tid = threadIdx.x;
    int img = blockIdx.y, bt = img/5, n = img%5;

    for (int i=tid;i<16384;i+=256) w1t[(i>>7)*136 + (i&127)] = f2bf(w1[i]);
    for (int i=tid;i<4096;i+=256)  w2t[(i>>7)*136 + (i&127)] = f2bf(w2[i]);
    if (tid<128) b1l[tid]=b1[tid];
    if (tid<32)  b2l[tid]=b2[tid];
    if (tid<8)   b3l[tid]=b3[tid];
    if (tid<256) w3l[tid]=w3[tid];
    if (tid<8)   w4l[tid]=w4[tid];
    if (tid==0)  b4l[0]=b4[0];

    int px = tid&63, q = tid>>6;
    int p = blockIdx.x*64 + px;
    const float* tg = bevs + (size_t)bt*5*64*PP;
    if (n == 0){
#pragma unroll
        for (int ci=0;ci<16;ci++){
            int c = q*16+ci;
            short v = f2bf(tg[(size_t)c*PP + p]);
            xt[px*136 + c] = v;
            xt[px*136 + 64 + c] = v;
        }
    } else {
        int im12 = bt*4 + (n-1);
        int off[9]; bool val[9];
        tap_setup(p, off, val);
        const float* mrow = maskb + (size_t)im12*PP;
        float m9[9];
#pragma unroll
        for (int t=0;t<9;t++) m9[t] = val[t] ? mrow[off[t]] : 0.0f;
        float rden = 1.0f/(denb[(size_t)im12*PP + p] + NEPS);
        int iz = ((const int*)misc)[25+im12];
        float mc = m9[4];
        const float* nbb = bevs + (size_t)(bt*5+n)*64*PP;
#pragma unroll
        for (int ci=0;ci<16;ci++){
            int c = q*16+ci;
            xt[px*136 + c] = f2bf(tg[(size_t)c*PP + p]);
            const float* sc = nbb + (size_t)c*PP;
            float num = 0.0f, center = 0.0f;
#pragma unroll
            for (int t=0;t<9;t++){
                if (val[t]){
                    float v = sc[off[t]];
                    num = fmaf(m9[t], v, num);
                    if (t==4) center = v;
                }
            }
            float xc = iz ? center : fmaf(mc, center, (1.0f-mc)*(num*rden));
            xt[px*136 + 64 + c] = f2bf(xc);
        }
    }
    __syncthreads();

    int w = tid>>6, l = tid&63;
    int ln = l&15, kg = l>>4;
    bf16x8 af[4];
#pragma unroll
    for (int ks=0;ks<4;ks++)
        af[ks] = *(const bf16x8*)&xt[(w*16+ln)*136 + ks*32 + kg*8];
#pragma unroll
    for (int nt=0;nt<8;nt++){
        float bias = b1l[nt*16 + ln];
        f32x4 acc = {bias, bias, bias, bias};
#pragma unroll
        for (int ks=0;ks<4;ks++){
            bf16x8 bf = *(const bf16x8*)&w1t[(nt*16+ln)*136 + ks*32 + kg*8];
            acc = __builtin_amdgcn_mfma_f32_16x16x32_bf16(af[ks], bf, acc, 0, 0, 0);
        }
#pragma unroll
        for (int r=0;r<4;r++){
            int pr = w*16 + kg*4 + r;
            xt[pr*136 + nt*16 + ln] = f2bf(fmaxf(acc[r], 0.0f));
        }
    }
    bf16x8 a2[4];
#pragma unroll
    for (int ks=0;ks<4;ks++)
        a2[ks] = *(const bf16x8*)&xt[(w*16+ln)*136 + ks*32 + kg*8];
#pragma unroll
    for (int nt2=0;nt2<2;nt2++){
        float bias = b2l[nt2*16 + ln];
        f32x4 acc = {bias, bias, bias, bias};
#pragma unroll
        for (int ks=0;ks<4;ks++){
            bf16x8 bf = *(const bf16x8*)&w2t[(nt2*16+ln)*136 + ks*32 + kg*8];
            acc = __builtin_amdgcn_mfma_f32_16x16x32_bf16(a2[ks], bf, acc, 0, 0, 0);
        }
#pragma unroll
        for (int r=0;r<4;r++){
            int pr = w*16 + kg*4 + r;
            z2[pr*33 + nt2*16 + ln] = fmaxf(acc[r], 0.0f);
        }
    }
    __syncthreads();
    if (tid < 64){
        float y3[8];
#pragma unroll
        for (int k=0;k<8;k++) y3[k] = b3l[k];
        for (int j=0;j<32;j++){
            float v = z2[tid*33 + j];
#pragma unroll
            for (int k=0;k<8;k++) y3[k] = fmaf(w3l[k*32+j], v, y3[k]);
        }
        float sres = b4l[0];
#pragma unroll
        for (int k=0;k<8;k++) sres = fmaf(w4l[k], fmaxf(y3[k], 0.0f), sres);
        logits[(size_t)img*PP + blockIdx.x*64 + tid] = fmaxf(sres, 0.0f);
    }
}

__global__ __launch_bounds__(256) void k_fuse_old(const float* __restrict__ bevs,
        const float* __restrict__ logits, const float* __restrict__ maskb,
        const float* __restrict__ denb, const unsigned* __restrict__ misc,
        float* __restrict__ out)
{
    int bt = blockIdx.y;
    int p = blockIdx.x*256 + threadIdx.x;
    if (p >= PP) return;
    int off[9]; bool val[9];
    tap_setup(p, off, val);
    float e[5], ssum = 0.0f;
#pragma unroll
    for (int nn=0;nn<5;nn++){ e[nn] = expf(logits[(size_t)(bt*5+nn)*PP + p]); ssum += e[nn]; }
    float wts[5];
#pragma unroll
    for (int nn=0;nn<5;nn++) wts[nn] = e[nn] / ssum;
    float m9[4][9]; float rden[4]; int iz[4];
#pragma unroll
    for (int k=0;k<4;k++){
        int im12 = bt*4 + k;
        const float* mrow = maskb + (size_t)im12*PP;
#pragma unroll
        for (int t=0;t<9;t++) m9[k][t] = val[t] ? mrow[off[t]] : 0.0f;
        rden[k] = 1.0f/(denb[(size_t)im12*PP + p] + NEPS);
        iz[k] = ((const int*)misc)[25+im12];
    }
    const float* base = bevs + (size_t)bt*5*64*PP;
    for (int c=0;c<64;c++){
        float tgc = base[(size_t)c*PP + p];
        float fused = wts[0]*tgc;
#pragma unroll
        for (int k=0;k<4;k++){
            const float* sc = base + (size_t)(k+1)*64*PP + (size_t)c*PP;
            float num = 0.0f, center = 0.0f;
#pragma unroll
            for (int t=0;t<9;t++){
                if (val[t]){
                    float v = sc[off[t]];
                    num = fmaf(m9[k][t], v, num);
                    if (t==4) center = v;
                }
            }
            float mc = m9[k][4];
            float xc = iz[k] ? center : fmaf(mc, center, (1.0f-mc)*(num*rden[k]));
            fused = fmaf(wts[k+1], xc, fused);
        }
        out[((size_t)bt*64 + c)*PP + p] = fused;
    }
}

extern "C" void kernel_launch(void* const* d_in, const int* in_sizes, int n_in,
                              void* d_out, int out_size, void* d_ws, size_t ws_size,
                              hipStream_t stream)
{
    const float* bevs = (const float*)d_in[0];
    const float* cw  = (const float*)d_in[1];
    const float* cb  = (const float*)d_in[2];
    const float* w1  = (const float*)d_in[3];
    const float* b1  = (const float*)d_in[4];
    const float* w2  = (const float*)d_in[5];
    const float* b2  = (const float*)d_in[6];
    const float* w3  = (const float*)d_in[7];
    const float* b3  = (const float*)d_in[8];
    const float* w4  = (const float*)d_in[9];
    const float* b4  = (const float*)d_in[10];
    float* out = (float*)d_out;
    float* ws = (float*)d_ws;

    float* com    = ws + OFF_COM;
    float* ent    = ws + OFF_ENT;
    float* maskb  = ws + OFF_MASK;
    float* denb   = ws + OFF_DEN;
    float* logits = ws + OFF_LOGITS;
    unsigned* misc = (unsigned*)(ws + OFF_MISC);
    short* X      = (short*)(ws + OFF_X_F);

    dim3 blk(256,1,1);
    int gx = (PP + 255)/256;

    k_init<<<dim3(1),dim3(64),0,stream>>>(misc);
    k_conv<<<dim3(gx,15),blk,0,stream>>>(bevs,cw,cb,com,misc);
    k_ent <<<dim3(gx,15),blk,0,stream>>>(com,ent);
    k_mask<<<dim3(gx,12),blk,0,stream>>>(ent,maskb,misc);
    k_den <<<dim3(gx,12),blk,0,stream>>>(maskb,denb);
    k_fin <<<dim3(1),dim3(64),0,stream>>>(misc, out + (size_t)3*64*PP);

    if (ws_size >= WS_NEED){
        k_xgen <<<dim3(PP/64,15),blk,0,stream>>>(bevs,maskb,denb,misc,X);
        k_mlp  <<<dim3(gx,15),blk,0,stream>>>(X,w1,b1,w2,b2,w3,b3,w4,b4,logits);
        k_fuse2<<<dim3(gx,3,2),blk,0,stream>>>(bevs,logits,X,out);
    } else {
        k_pwf  <<<dim3(PP/64,15),blk,0,stream>>>(bevs,w1,b1,w2,b2,w3,b3,w4,b4,maskb,denb,misc,logits);
        k_fuse_old<<<dim3(gx,3),blk,0,stream>>>(bevs,logits,maskb,denb,misc,out);
    }
}

// Round 5
// 556.917 us; speedup vs baseline: 3.8450x; 1.4924x over previous
//
#include <hip/hip_runtime.h>
#include <hip/hip_bf16.h>
#include <math.h>

#define PP 40000
#define HDIM 200
#define WDIM 200
#define NEPS 1e-8f

// workspace layout (float offsets)
#define OFF_COM    0            // 15*PP
#define OFF_ENT    (15*PP)      // 15*PP
#define OFF_MASK   (30*PP)      // 12*PP
#define OFF_DEN    (42*PP)      // 12*PP
#define OFF_LOGITS (54*PP)      // 15*PP
#define OFF_MISC   (69*PP)      // 64 floats
#define OFF_X_F    (69*PP + 64) // X bf16: 15*PP*128 shorts
// bytes needed for new path:
#define WS_NEED ((size_t)(69*PP + 64)*4 + (size_t)15*PP*128*2)

typedef __attribute__((ext_vector_type(8))) short bf16x8;
typedef __attribute__((ext_vector_type(4))) float f32x4;

__device__ __forceinline__ short f2bf(float f){
    __hip_bfloat16 h = __float2bfloat16(f);   // RTNE
    return *reinterpret_cast<short*>(&h);
}
__device__ __forceinline__ float bf2f(short s){
    return __uint_as_float(((unsigned)(unsigned short)s) << 16);
}

__device__ __forceinline__ unsigned f2ord(float f){
    unsigned u = __float_as_uint(f);
    return (u & 0x80000000u) ? ~u : (u | 0x80000000u);
}
__device__ __forceinline__ float ord2f(unsigned u){
    unsigned v = (u & 0x80000000u) ? (u & 0x7fffffffu) : ~u;
    return __uint_as_float(v);
}

// Clamped tap offsets: off[t] always a VALID address (clamped to image),
// val[t] marks true in-bounds. Loads can be unconditional; OOB values are
// annihilated exactly via select/zero-weight (fmaf(w,0,acc)==acc exactly).
__device__ __forceinline__ void tap_setup(int p, int* off, bool* val){
    int h = p / WDIM, w = p - h*WDIM;
#pragma unroll
    for (int ky=0;ky<3;ky++)
#pragma unroll
        for (int kx=0;kx<3;kx++){
            int t = ky*3+kx;
            int hh = h+ky-1, ww = w+kx-1;
            val[t] = (hh>=0)&&(hh<HDIM)&&(ww>=0)&&(ww<WDIM);
            int hc = min(max(hh,0),HDIM-1);
            int wc = min(max(ww,0),WDIM-1);
            off[t] = hc*WDIM+wc;
        }
}

__global__ void k_init(unsigned* misc){
    int t = threadIdx.x;
    if (t < 12) misc[t] = 0xFFFFFFFFu;        // min (sortable) = +inf
    else if (t < 25) misc[t] = 0u;            // max = -inf, count = 0
}

// compress conv3x3 (64->1) + relu; per-image min/max via center tap only.
// Weights read via uniform (scalar) loads directly from global.
__global__ __launch_bounds__(256) void k_conv(const float* __restrict__ bevs,
        const float* __restrict__ cw, const float* __restrict__ cb,
        float* __restrict__ com, unsigned* __restrict__ misc)
{
    int img = blockIdx.y;          // 0..14 = bt*5+n
    int n = img % 5;
    int p = blockIdx.x*256 + threadIdx.x;
    float vmin = INFINITY, vmax = -INFINITY;
    if (p < PP){
        int off[9]; bool val[9];
        tap_setup(p, off, val);
        const float* src = bevs + (size_t)img*64*PP;
        float acc = cb[0];
#pragma unroll 2
        for (int c=0;c<64;c++){
            const float* sc = src + (size_t)c*PP;
            float v[9];
#pragma unroll
            for (int t=0;t<9;t++) v[t] = sc[off[t]];     // unconditional, clamped
            vmin = fminf(vmin, v[4]); vmax = fmaxf(vmax, v[4]);
#pragma unroll
            for (int t=0;t<9;t++)
                acc = fmaf(cw[c*9+t], val[t] ? v[t] : 0.0f, acc);
        }
        com[(size_t)img*PP + p] = fmaxf(acc, 0.0f);
    }
    if (n > 0){
#pragma unroll
        for (int s=32;s>0;s>>=1){
            vmin = fminf(vmin, __shfl_xor(vmin, s, 64));
            vmax = fmaxf(vmax, __shfl_xor(vmax, s, 64));
        }
        if ((threadIdx.x & 63) == 0){
            int im12 = (img/5)*4 + (n-1);
            atomicMin(&misc[im12], f2ord(vmin));
            atomicMax(&misc[12+im12], f2ord(vmax));
        }
    }
}

__global__ __launch_bounds__(256) void k_ent(const float* __restrict__ com,
        float* __restrict__ ent)
{
    int img = blockIdx.y;
    int p = blockIdx.x*256 + threadIdx.x;
    if (p >= PP) return;
    int off[9]; bool val[9];
    tap_setup(p, off, val);
    const float* s = com + (size_t)img*PP;
    float x = s[p];
    float v[9];
#pragma unroll
    for (int t=0;t<9;t++) v[t] = s[off[t]];              // unconditional
    float acc = 0.0f;
#pragma unroll
    for (int t=0;t<9;t++){
        float xv = val[t] ? v[t] : 0.0f;                 // zero pad
        acc += 1.0f/(1.0f + expf(x - xv));               // sigmoid(xv - x)
    }
    ent[(size_t)img*PP + p] = acc / 9.0f;
}

__global__ __launch_bounds__(256) void k_mask(const float* __restrict__ ent,
        float* __restrict__ maskb, unsigned* __restrict__ misc)
{
    int im12 = blockIdx.y; int bt = im12 >> 2; int n = (im12 & 3) + 1;
    int p = blockIdx.x*256 + threadIdx.x;
    int v = 0;
    if (p < PP){
        float en = ent[(size_t)(bt*5+n)*PP + p];
        float et = ent[(size_t)(bt*5)*PP + p];
        v = en > et;
        maskb[(size_t)im12*PP + p] = (float)v;
    }
    unsigned long long bal = __ballot(v);
    if ((threadIdx.x & 63) == 0) atomicAdd(&misc[24], (unsigned)__popcll(bal));
}

__global__ __launch_bounds__(256) void k_den(const float* __restrict__ maskb,
        float* __restrict__ denb)
{
    int im12 = blockIdx.y;
    int p = blockIdx.x*256 + threadIdx.x;
    if (p >= PP) return;
    int off[9]; bool val[9];
    tap_setup(p, off, val);
    const float* mrow = maskb + (size_t)im12*PP;
    float v[9];
#pragma unroll
    for (int t=0;t<9;t++) v[t] = mrow[off[t]];           // unconditional
    float s = 0.0f;
#pragma unroll
    for (int t=0;t<9;t++) s += val[t] ? v[t] : 0.0f;
    denb[(size_t)im12*PP + p] = s;
}

__global__ void k_fin(unsigned* misc, float* bwout){
    int t = threadIdx.x;
    if (t < 12){
        float mn = ord2f(misc[t]);
        float mx = ord2f(misc[12+t]);
        ((int*)misc)[25+t] = (mn + mx == 0.0f) ? 1 : 0;
    }
    if (t == 12) bwout[0] = (float)misc[24] / 480000.0f;
}

// ---------------------------------------------------------------------------
// k_xgen: materialize X[img][px][128] bf16, X = [tg(64) ; feat(64)]
// block = 64 px, 256 threads: thread (px = tid>>2, q = tid&3) handles 16 ch.
// grid (625, 15)
// ---------------------------------------------------------------------------
__global__ __launch_bounds__(256) void k_xgen(const float* __restrict__ bevs,
        const float* __restrict__ maskb, const float* __restrict__ denb,
        const unsigned* __restrict__ misc, short* __restrict__ X)
{
    int tid = threadIdx.x;
    int img = blockIdx.y, bt = img/5, n = img%5;
    int px = blockIdx.x*64 + (tid>>2);
    int q = tid&3;
    int cb = q*16;
    const float* tg = bevs + (size_t)bt*5*64*PP;
    short* xr = X + ((size_t)img*PP + px)*128;

    short tgv[16];
#pragma unroll
    for (int ci=0;ci<16;ci++) tgv[ci] = f2bf(tg[(size_t)(cb+ci)*PP + px]);
    // store tg-half
    *(bf16x8*)&xr[cb]     = *(bf16x8*)&tgv[0];
    *(bf16x8*)&xr[cb + 8] = *(bf16x8*)&tgv[8];

    short fv[16];
    if (n == 0){
#pragma unroll
        for (int ci=0;ci<16;ci++) fv[ci] = tgv[ci];
    } else {
        int im12 = bt*4 + (n-1);
        int off[9]; bool val[9];
        tap_setup(px, off, val);
        const float* mrow = maskb + (size_t)im12*PP;
        float m9[9];
#pragma unroll
        for (int t=0;t<9;t++){
            float mv = mrow[off[t]];                     // unconditional
            m9[t] = val[t] ? mv : 0.0f;                  // zero kills OOB exactly
        }
        float rden = 1.0f/(denb[(size_t)im12*PP + px] + NEPS);
        int iz = ((const int*)misc)[25+im12];
        float mc = m9[4];
        const float* nbb = bevs + (size_t)(bt*5+n)*64*PP;
#pragma unroll 2
        for (int ci=0;ci<16;ci++){
            const float* sc = nbb + (size_t)(cb+ci)*PP;
            float v[9];
#pragma unroll
            for (int t=0;t<9;t++) v[t] = sc[off[t]];     // unconditional
            float num = 0.0f;
#pragma unroll
            for (int t=0;t<9;t++) num = fmaf(m9[t], v[t], num);  // m9=0 => exact no-op
            float center = v[4];
            float xc = iz ? center : fmaf(mc, center, (1.0f-mc)*(num*rden));
            fv[ci] = f2bf(xc);
        }
    }
    *(bf16x8*)&xr[64 + cb]     = *(bf16x8*)&fv[0];
    *(bf16x8*)&xr[64 + cb + 8] = *(bf16x8*)&fv[8];
}

// ---------------------------------------------------------------------------
// k_mlp: GEMM on X. block = 256 px (4 waves x 64 px = 4 m-tiles of 16).
// Weights staged once per block; A-frags direct from global X; per-wave
// private xt2/z2 LDS regions -> no barriers in the main loop.
// grid (157, 15)
// ---------------------------------------------------------------------------
__global__ __launch_bounds__(256) void k_mlp(const short* __restrict__ X,
        const float* __restrict__ w1, const float* __restrict__ b1,
        const float* __restrict__ w2, const float* __restrict__ b2,
        const float* __restrict__ w3, const float* __restrict__ b3,
        const float* __restrict__ w4, const float* __restrict__ b4,
        float* __restrict__ logits)
{
    __shared__ __align__(16) short w1t[128*136];
    __shared__ __align__(16) short w2t[32*136];
    __shared__ __align__(16) short xt2[4*16*136];
    __shared__ __align__(16) float z2[4*16*33];
    __shared__ float b1l[128], b2l[32], b3l[8], w3l[8*33], w4l[8], b4l[1];

    int tid = threadIdx.x;
    int img = blockIdx.y;

    for (int i=tid;i<16384;i+=256) w1t[(i>>7)*136 + (i&127)] = f2bf(w1[i]);
    for (int i=tid;i<4096;i+=256)  w2t[(i>>7)*136 + (i&127)] = f2bf(w2[i]);
    if (tid<256) w3l[(tid>>5)*33 + (tid&31)] = w3[tid];
    if (tid<128) b1l[tid]=b1[tid];
    if (tid<32)  b2l[tid]=b2[tid];
    if (tid<8)   b3l[tid]=b3[tid];
    if (tid<8)   w4l[tid]=w4[tid];
    if (tid==0)  b4l[0]=b4[0];
    __syncthreads();

    int w = tid>>6, l = tid&63;
    int ln = l&15, kg = l>>4;
    const short* Ximg = X + (size_t)img*PP*128;
    short* xt2w = &xt2[w*16*136];
    float* z2w  = &z2[w*16*33];
    int px_base = blockIdx.x*256 + w*64;

#pragma unroll 1
    for (int mt=0; mt<4; mt++){
        int prow = px_base + mt*16;
        int arow = prow + ln; if (arow > PP-1) arow = PP-1;
        const short* xr = Ximg + (size_t)arow*128;
        bf16x8 af[4];
#pragma unroll
        for (int ks=0;ks<4;ks++)
            af[ks] = *(const bf16x8*)&xr[ks*32 + kg*8];

        // layer 1: N=128 (8 n-tiles), K=128
#pragma unroll
        for (int nt=0;nt<8;nt++){
            float bias = b1l[nt*16 + ln];
            f32x4 acc = {bias, bias, bias, bias};
#pragma unroll
            for (int ks=0;ks<4;ks++){
                bf16x8 bf = *(const bf16x8*)&w1t[(nt*16+ln)*136 + ks*32 + kg*8];
                acc = __builtin_amdgcn_mfma_f32_16x16x32_bf16(af[ks], bf, acc, 0, 0, 0);
            }
#pragma unroll
            for (int r=0;r<4;r++)
                xt2w[(kg*4+r)*136 + nt*16 + ln] = f2bf(fmaxf(acc[r], 0.0f));
        }

        // layer 2: N=32, K=128 (A = X2 from per-wave LDS)
        bf16x8 a2[4];
#pragma unroll
        for (int ks=0;ks<4;ks++)
            a2[ks] = *(const bf16x8*)&xt2w[ln*136 + ks*32 + kg*8];
#pragma unroll
        for (int nt2=0;nt2<2;nt2++){
            float bias = b2l[nt2*16 + ln];
            f32x4 acc = {bias, bias, bias, bias};
#pragma unroll
            for (int ks=0;ks<4;ks++){
                bf16x8 bf = *(const bf16x8*)&w2t[(nt2*16+ln)*136 + ks*32 + kg*8];
                acc = __builtin_amdgcn_mfma_f32_16x16x32_bf16(a2[ks], bf, acc, 0, 0, 0);
            }
#pragma unroll
            for (int r=0;r<4;r++)
                z2w[(kg*4+r)*33 + nt2*16 + ln] = fmaxf(acc[r], 0.0f);
        }

        // tail: lane (px16 = ln, k-pair = kg): y3 for k = 2kg, 2kg+1
        int k0 = kg*2, k1 = kg*2+1;
        float y0 = b3l[k0], y1 = b3l[k1];
#pragma unroll
        for (int j=0;j<32;j++){
            float v = z2w[ln*33 + j];
            y0 = fmaf(w3l[k0*33+j], v, y0);
            y1 = fmaf(w3l[k1*33+j], v, y1);
        }
        float part = w4l[k0]*fmaxf(y0,0.0f) + w4l[k1]*fmaxf(y1,0.0f);
        part += __shfl_xor(part, 16, 64);
        part += __shfl_xor(part, 32, 64);
        if (kg == 0 && prow + ln < PP)
            logits[(size_t)img*PP + prow + ln] = fmaxf(part + b4l[0], 0.0f);
    }
}

// ---------------------------------------------------------------------------
// k_fuse2: softmax over logits + weighted sum of feats (tg fp32, warp bf16 from X)
// grid (157, 3, 2): 32-ch groups
// ---------------------------------------------------------------------------
__global__ __launch_bounds__(256) void k_fuse2(const float* __restrict__ bevs,
        const float* __restrict__ logits, const short* __restrict__ X,
        float* __restrict__ out)
{
    int bt = blockIdx.y;
    int cb = blockIdx.z*32;
    int p = blockIdx.x*256 + threadIdx.x;
    if (p >= PP) return;
    float e[5], ssum = 0.0f;
#pragma unroll
    for (int nn=0;nn<5;nn++){ e[nn] = expf(logits[(size_t)(bt*5+nn)*PP + p]); ssum += e[nn]; }
    float rs = 1.0f/ssum;
    const float* tgb = bevs + (size_t)bt*5*64*PP;
    float acc[32];
    float w0 = e[0]*rs;
#pragma unroll
    for (int ci=0;ci<32;ci++) acc[ci] = w0*tgb[(size_t)(cb+ci)*PP + p];
#pragma unroll
    for (int k=0;k<4;k++){
        float wk = e[k+1]*rs;
        const short* Xr = X + ((size_t)(bt*5+k+1)*PP + p)*128 + 64 + cb;
#pragma unroll
        for (int c8=0;c8<4;c8++){
            bf16x8 v = *(const bf16x8*)&Xr[c8*8];
#pragma unroll
            for (int j=0;j<8;j++)
                acc[c8*8+j] = fmaf(wk, bf2f(v[j]), acc[c8*8+j]);
        }
    }
#pragma unroll
    for (int ci=0;ci<32;ci++)
        out[((size_t)bt*64 + cb+ci)*PP + p] = acc[ci];
}

// ---------------------------------------------------------------------------
// FALLBACK path (round-3 fused kernels) if ws too small for X
// ---------------------------------------------------------------------------
__global__ __launch_bounds__(256) void k_pwf(const float* __restrict__ bevs,
        const float* __restrict__ w1, const float* __restrict__ b1,
        const float* __restrict__ w2, const float* __restrict__ b2,
        const float* __restrict__ w3, const float* __restrict__ b3,
        const float* __restrict__ w4, const float* __restrict__ b4,
        const float* __restrict__ maskb, const float* __restrict__ denb,
        const unsigned* __restrict__ misc, float* __restrict__ logits)
{
    __shared__ __align__(16) short w1t[128*136];
    __shared__ __align__(16) short w2t[32*136];
    __shared__ __align__(16) short xt[64*136];
    __shared__ __align__(16) float z2[64*33];
    __shared__ float b1l[128], b2l[32], b3l[8], w3l[256], w4l[8], b4l[1];

    int tid = threadIdx.x;
    int img = blockIdx.y, bt = img/5, n = img%5;

    for (int i=tid;i<16384;i+=256) w1t[(i>>7)*136 + (i&127)] = f2bf(w1[i]);
    for (int i=tid;i<4096;i+=256)  w2t[(i>>7)*136 + (i&127)] = f2bf(w2[i]);
    if (tid<128) b1l[tid]=b1[tid];
    if (tid<32)  b2l[tid]=b2[tid];
    if (tid<8)   b3l[tid]=b3[tid];
    if (tid<256) w3l[tid]=w3[tid];
    if (tid<8)   w4l[tid]=w4[tid];
    if (tid==0)  b4l[0]=b4[0];

    int px = tid&63, q = tid>>6;
    int p = blockIdx.x*64 + px;
    const float* tg = bevs + (size_t)bt*5*64*PP;
    if (n == 0){
#pragma unroll
        for (int ci=0;ci<16;ci++){
            int c = q*16+ci;
            short v = f2bf(tg[(size_t)c*PP + p]);
            xt[px*136 + c] = v;
            xt[px*136 + 64 + c] = v;
        }
    } else {
        int im12 = bt*4 + (n-1);
        int off[9]; bool val[9];
        tap_setup(p, off, val);
        const float* mrow = maskb + (size_t)im12*PP;
        float m9[9];
#pragma unroll
        for (int t=0;t<9;t++) m9[t] = val[t] ? mrow[off[t]] : 0.0f;
        float rden = 1.0f/(denb[(size_t)im12*PP + p] + NEPS);
        int iz = ((const int*)misc)[25+im12];
        float mc = m9[4];
        const float* nbb = bevs + (size_t)(bt*5+n)*64*PP;
#pragma unroll
        for (int ci=0;ci<16;ci++){
            int c = q*16+ci;
            xt[px*136 + c] = f2bf(tg[(size_t)c*PP + p]);
            const float* sc = nbb + (size_t)c*PP;
            float num = 0.0f, center = 0.0f;
#pragma unroll
            for (int t=0;t<9;t++){
                if (val[t]){
                    float v = sc[off[t]];
                    num = fmaf(m9[t], v, num);
                    if (t==4) center = v;
                }
            }
            float xc = iz ? center : fmaf(mc, center, (1.0f-mc)*(num*rden));
            xt[px*136 + 64 + c] = f2bf(xc);
        }
    }
    __syncthreads();

    int w = tid>>6, l = tid&63;
    int ln = l&15, kg = l>>4;
    bf16x8 af[4];
#pragma unroll
    for (int ks=0;ks<4;ks++)
        af[ks] = *(const bf16x8*)&xt[(w*16+ln)*136 + ks*32 + kg*8];
#pragma unroll
    for (int nt=0;nt<8;nt++){
        float bias = b1l[nt*16 + ln];
        f32x4 acc = {bias, bias, bias, bias};
#pragma unroll
        for (int ks=0;ks<4;ks++){
            bf16x8 bf = *(const bf16x8*)&w1t[(nt*16+ln)*136 + ks*32 + kg*8];
            acc = __builtin_amdgcn_mfma_f32_16x16x32_bf16(af[ks], bf, acc, 0, 0, 0);
        }
#pragma unroll
        for (int r=0;r<4;r++){
            int pr = w*16 + kg*4 + r;
            xt[pr*136 + nt*16 + ln] = f2bf(fmaxf(acc[r], 0.0f));
        }
    }
    bf16x8 a2[4];
#pragma unroll
    for (int ks=0;ks<4;ks++)
        a2[ks] = *(const bf16x8*)&xt[(w*16+ln)*136 + ks*32 + kg*8];
#pragma unroll
    for (int nt2=0;nt2<2;nt2++){
        float bias = b2l[nt2*16 + ln];
        f32x4 acc = {bias, bias, bias, bias};
#pragma unroll
        for (int ks=0;ks<4;ks++){
            bf16x8 bf = *(const bf16x8*)&w2t[(nt2*16+ln)*136 + ks*32 + kg*8];
            acc = __builtin_amdgcn_mfma_f32_16x16x32_bf16(a2[ks], bf, acc, 0, 0, 0);
        }
#pragma unroll
        for (int r=0;r<4;r++){
            int pr = w*16 + kg*4 + r;
            z2[pr*33 + nt2*16 + ln] = fmaxf(acc[r], 0.0f);
        }
    }
    __syncthreads();
    if (tid < 64){
        float y3[8];
#pragma unroll
        for (int k=0;k<8;k++) y3[k] = b3l[k];
        for (int j=0;j<32;j++){
            float v = z2[tid*33 + j];
#pragma unroll
            for (int k=0;k<8;k++) y3[k] = fmaf(w3l[k*32+j], v, y3[k]);
        }
        float sres = b4l[0];
#pragma unroll
        for (int k=0;k<8;k++) sres = fmaf(w4l[k], fmaxf(y3[k], 0.0f), sres);
        logits[(size_t)img*PP + blockIdx.x*64 + tid] = fmaxf(sres, 0.0f);
    }
}

__global__ __launch_bounds__(256) void k_fuse_old(const float* __restrict__ bevs,
        const float* __restrict__ logits, const float* __restrict__ maskb,
        const float* __restrict__ denb, const unsigned* __restrict__ misc,
        float* __restrict__ out)
{
    int bt = blockIdx.y;
    int p = blockIdx.x*256 + threadIdx.x;
    if (p >= PP) return;
    int off[9]; bool val[9];
    tap_setup(p, off, val);
    float e[5], ssum = 0.0f;
#pragma unroll
    for (int nn=0;nn<5;nn++){ e[nn] = expf(logits[(size_t)(bt*5+nn)*PP + p]); ssum += e[nn]; }
    float wts[5];
#pragma unroll
    for (int nn=0;nn<5;nn++) wts[nn] = e[nn] / ssum;
    float m9[4][9]; float rden[4]; int iz[4];
#pragma unroll
    for (int k=0;k<4;k++){
        int im12 = bt*4 + k;
        const float* mrow = maskb + (size_t)im12*PP;
#pragma unroll
        for (int t=0;t<9;t++) m9[k][t] = val[t] ? mrow[off[t]] : 0.0f;
        rden[k] = 1.0f/(denb[(size_t)im12*PP + p] + NEPS);
        iz[k] = ((const int*)misc)[25+im12];
    }
    const float* base = bevs + (size_t)bt*5*64*PP;
    for (int c=0;c<64;c++){
        float tgc = base[(size_t)c*PP + p];
        float fused = wts[0]*tgc;
#pragma unroll
        for (int k=0;k<4;k++){
            const float* sc = base + (size_t)(k+1)*64*PP + (size_t)c*PP;
            float num = 0.0f, center = 0.0f;
#pragma unroll
            for (int t=0;t<9;t++){
                if (val[t]){
                    float v = sc[off[t]];
                    num = fmaf(m9[k][t], v, num);
                    if (t==4) center = v;
                }
            }
            float mc = m9[k][4];
            float xc = iz[k] ? center : fmaf(mc, center, (1.0f-mc)*(num*rden[k]));
            fused = fmaf(wts[k+1], xc, fused);
        }
        out[((size_t)bt*64 + c)*PP + p] = fused;
    }
}

extern "C" void kernel_launch(void* const* d_in, const int* in_sizes, int n_in,
                              void* d_out, int out_size, void* d_ws, size_t ws_size,
                              hipStream_t stream)
{
    const float* bevs = (const float*)d_in[0];
    const float* cw  = (const float*)d_in[1];
    const float* cb  = (const float*)d_in[2];
    const float* w1  = (const float*)d_in[3];
    const float* b1  = (const float*)d_in[4];
    const float* w2  = (const float*)d_in[5];
    const float* b2  = (const float*)d_in[6];
    const float* w3  = (const float*)d_in[7];
    const float* b3  = (const float*)d_in[8];
    const float* w4  = (const float*)d_in[9];
    const float* b4  = (const float*)d_in[10];
    float* out = (float*)d_out;
    float* ws = (float*)d_ws;

    float* com    = ws + OFF_COM;
    float* ent    = ws + OFF_ENT;
    float* maskb  = ws + OFF_MASK;
    float* denb   = ws + OFF_DEN;
    float* logits = ws + OFF_LOGITS;
    unsigned* misc = (unsigned*)(ws + OFF_MISC);
    short* X      = (short*)(ws + OFF_X_F);

    dim3 blk(256,1,1);
    int gx = (PP + 255)/256;

    k_init<<<dim3(1),dim3(64),0,stream>>>(misc);
    k_conv<<<dim3(gx,15),blk,0,stream>>>(bevs,cw,cb,com,misc);
    k_ent <<<dim3(gx,15),blk,0,stream>>>(com,ent);
    k_mask<<<dim3(gx,12),blk,0,stream>>>(ent,maskb,misc);
    k_den <<<dim3(gx,12),blk,0,stream>>>(maskb,denb);
    k_fin <<<dim3(1),dim3(64),0,stream>>>(misc, out + (size_t)3*64*PP);

    if (ws_size >= WS_NEED){
        k_xgen <<<dim3(PP/64,15),blk,0,stream>>>(bevs,maskb,denb,misc,X);
        k_mlp  <<<dim3(gx,15),blk,0,stream>>>(X,w1,b1,w2,b2,w3,b3,w4,b4,logits);
        k_fuse2<<<dim3(gx,3,2),blk,0,stream>>>(bevs,logits,X,out);
    } else {
        k_pwf  <<<dim3(PP/64,15),blk,0,stream>>>(bevs,w1,b1,w2,b2,w3,b3,w4,b4,maskb,denb,misc,logits);
        k_fuse_old<<<dim3(gx,3),blk,0,stream>>>(bevs,logits,maskb,denb,misc,out);
    }
}

// Round 6
// 453.961 us; speedup vs baseline: 4.7170x; 1.2268x over previous
//
#include <hip/hip_runtime.h>
#include <hip/hip_bf16.h>
#include <math.h>

#define PP 40000
#define HDIM 200
#define WDIM 200
#define NEPS 1e-8f

// workspace layout (float offsets)
#define OFF_COM    0            // 15*PP
#define OFF_ENT    (15*PP)      // 15*PP
#define OFF_MASK   (30*PP)      // 12*PP
#define OFF_DEN    (42*PP)      // 12*PP
#define OFF_LOGITS (54*PP)      // 15*PP
#define OFF_MISC   (69*PP)      // 64 floats
#define OFF_X_F    (69*PP + 64) // X bf16: 15*PP*128 shorts; z fp32 (15*9*PP) overlaps here (dead before X written)
// bytes needed for new path:
#define WS_NEED ((size_t)(69*PP + 64)*4 + (size_t)15*PP*128*2)

typedef __attribute__((ext_vector_type(8))) short bf16x8;
typedef __attribute__((ext_vector_type(4))) float f32x4;

__device__ __forceinline__ short f2bf(float f){
    __hip_bfloat16 h = __float2bfloat16(f);   // RTNE
    return *reinterpret_cast<short*>(&h);
}
__device__ __forceinline__ float bf2f(short s){
    return __uint_as_float(((unsigned)(unsigned short)s) << 16);
}

__device__ __forceinline__ unsigned f2ord(float f){
    unsigned u = __float_as_uint(f);
    return (u & 0x80000000u) ? ~u : (u | 0x80000000u);
}
__device__ __forceinline__ float ord2f(unsigned u){
    unsigned v = (u & 0x80000000u) ? (u & 0x7fffffffu) : ~u;
    return __uint_as_float(v);
}

// Clamped tap offsets: off[t] always a VALID address (clamped to image),
// val[t] marks true in-bounds. Loads can be unconditional; OOB values are
// annihilated exactly via select/zero-weight (fmaf(w,0,acc)==acc exactly).
__device__ __forceinline__ void tap_setup(int p, int* off, bool* val){
    int h = p / WDIM, w = p - h*WDIM;
#pragma unroll
    for (int ky=0;ky<3;ky++)
#pragma unroll
        for (int kx=0;kx<3;kx++){
            int t = ky*3+kx;
            int hh = h+ky-1, ww = w+kx-1;
            val[t] = (hh>=0)&&(hh<HDIM)&&(ww>=0)&&(ww<WDIM);
            int hc = min(max(hh,0),HDIM-1);
            int wc = min(max(ww,0),WDIM-1);
            off[t] = hc*WDIM+wc;
        }
}

__global__ void k_init(unsigned* misc){
    int t = threadIdx.x;
    if (t < 12) misc[t] = 0xFFFFFFFFu;        // min (sortable) = +inf
    else if (t < 25) misc[t] = 0u;            // max = -inf, count = 0
}

// ---------------------------------------------------------------------------
// conv pass 1: z_t(q) = sum_c w[c,t] * x[c,q]  (9 weighted channel sums)
// One clean stream over bevs (float4, 4 px/thread). min/max fused.
// z layout: [img][t][PP].  grid (40, 15), block 256.
// ---------------------------------------------------------------------------
__global__ __launch_bounds__(256) void k_csum(const float* __restrict__ bevs,
        const float* __restrict__ cw, unsigned* __restrict__ misc,
        float* __restrict__ z)
{
    int img = blockIdx.y;          // 0..14 = bt*5+n
    int n = img % 5;
    int idx = blockIdx.x*256 + threadIdx.x;   // 4-px group id, 0..9999
    bool act = idx < PP/4;
    int p = idx*4;
    float vmin = INFINITY, vmax = -INFINITY;
    f32x4 acc[9];
#pragma unroll
    for (int t=0;t<9;t++) acc[t] = (f32x4){0.f,0.f,0.f,0.f};
    if (act){
        const float* src = bevs + (size_t)img*64*PP;
#pragma unroll 2
        for (int c=0;c<64;c++){
            f32x4 v = *(const f32x4*)&src[(size_t)c*PP + p];
            vmin = fminf(fminf(fminf(vmin, v[0]), fminf(v[1], v[2])), v[3]);
            vmax = fmaxf(fmaxf(fmaxf(vmax, v[0]), fmaxf(v[1], v[2])), v[3]);
#pragma unroll
            for (int t=0;t<9;t++){
                float w = cw[c*9+t];
#pragma unroll
                for (int j=0;j<4;j++) acc[t][j] = fmaf(w, v[j], acc[t][j]);
            }
        }
        float* zimg = z + (size_t)img*9*PP;
#pragma unroll
        for (int t=0;t<9;t++)
            *(f32x4*)&zimg[(size_t)t*PP + p] = acc[t];
    }
    if (n > 0){
#pragma unroll
        for (int s=32;s>0;s>>=1){
            vmin = fminf(vmin, __shfl_xor(vmin, s, 64));
            vmax = fmaxf(vmax, __shfl_xor(vmax, s, 64));
        }
        if ((threadIdx.x & 63) == 0){
            int im12 = (img/5)*4 + (n-1);
            atomicMin(&misc[im12], f2ord(vmin));
            atomicMax(&misc[12+im12], f2ord(vmax));
        }
    }
}

// conv pass 2: com(p) = relu(cb + sum_t [val] z_t(p+delta_t))
__global__ __launch_bounds__(256) void k_cfin(const float* __restrict__ z,
        const float* __restrict__ cb, float* __restrict__ com)
{
    int img = blockIdx.y;
    int p = blockIdx.x*256 + threadIdx.x;
    if (p >= PP) return;
    int off[9]; bool val[9];
    tap_setup(p, off, val);
    const float* zimg = z + (size_t)img*9*PP;
    float v[9];
#pragma unroll
    for (int t=0;t<9;t++) v[t] = zimg[(size_t)t*PP + off[t]];   // unconditional
    float acc = cb[0];
#pragma unroll
    for (int t=0;t<9;t++) acc += val[t] ? v[t] : 0.0f;
    com[(size_t)img*PP + p] = fmaxf(acc, 0.0f);
}

// ---------------------------------------------------------------------------
// FALLBACK conv (round-5 version) if ws too small for z/X
// ---------------------------------------------------------------------------
__global__ __launch_bounds__(256) void k_conv(const float* __restrict__ bevs,
        const float* __restrict__ cw, const float* __restrict__ cb,
        float* __restrict__ com, unsigned* __restrict__ misc)
{
    int img = blockIdx.y;          // 0..14 = bt*5+n
    int n = img % 5;
    int p = blockIdx.x*256 + threadIdx.x;
    float vmin = INFINITY, vmax = -INFINITY;
    if (p < PP){
        int off[9]; bool val[9];
        tap_setup(p, off, val);
        const float* src = bevs + (size_t)img*64*PP;
        float acc = cb[0];
#pragma unroll 2
        for (int c=0;c<64;c++){
            const float* sc = src + (size_t)c*PP;
            float v[9];
#pragma unroll
            for (int t=0;t<9;t++) v[t] = sc[off[t]];     // unconditional, clamped
            vmin = fminf(vmin, v[4]); vmax = fmaxf(vmax, v[4]);
#pragma unroll
            for (int t=0;t<9;t++)
                acc = fmaf(cw[c*9+t], val[t] ? v[t] : 0.0f, acc);
        }
        com[(size_t)img*PP + p] = fmaxf(acc, 0.0f);
    }
    if (n > 0){
#pragma unroll
        for (int s=32;s>0;s>>=1){
            vmin = fminf(vmin, __shfl_xor(vmin, s, 64));
            vmax = fmaxf(vmax, __shfl_xor(vmax, s, 64));
        }
        if ((threadIdx.x & 63) == 0){
            int im12 = (img/5)*4 + (n-1);
            atomicMin(&misc[im12], f2ord(vmin));
            atomicMax(&misc[12+im12], f2ord(vmax));
        }
    }
}

__global__ __launch_bounds__(256) void k_ent(const float* __restrict__ com,
        float* __restrict__ ent)
{
    int img = blockIdx.y;
    int p = blockIdx.x*256 + threadIdx.x;
    if (p >= PP) return;
    int off[9]; bool val[9];
    tap_setup(p, off, val);
    const float* s = com + (size_t)img*PP;
    float x = s[p];
    float v[9];
#pragma unroll
    for (int t=0;t<9;t++) v[t] = s[off[t]];              // unconditional
    float acc = 0.0f;
#pragma unroll
    for (int t=0;t<9;t++){
        float xv = val[t] ? v[t] : 0.0f;                 // zero pad
        acc += 1.0f/(1.0f + expf(x - xv));               // sigmoid(xv - x)
    }
    ent[(size_t)img*PP + p] = acc / 9.0f;
}

__global__ __launch_bounds__(256) void k_mask(const float* __restrict__ ent,
        float* __restrict__ maskb, unsigned* __restrict__ misc)
{
    int im12 = blockIdx.y; int bt = im12 >> 2; int n = (im12 & 3) + 1;
    int p = blockIdx.x*256 + threadIdx.x;
    int v = 0;
    if (p < PP){
        float en = ent[(size_t)(bt*5+n)*PP + p];
        float et = ent[(size_t)(bt*5)*PP + p];
        v = en > et;
        maskb[(size_t)im12*PP + p] = (float)v;
    }
    unsigned long long bal = __ballot(v);
    if ((threadIdx.x & 63) == 0) atomicAdd(&misc[24], (unsigned)__popcll(bal));
}

__global__ __launch_bounds__(256) void k_den(const float* __restrict__ maskb,
        float* __restrict__ denb)
{
    int im12 = blockIdx.y;
    int p = blockIdx.x*256 + threadIdx.x;
    if (p >= PP) return;
    int off[9]; bool val[9];
    tap_setup(p, off, val);
    const float* mrow = maskb + (size_t)im12*PP;
    float v[9];
#pragma unroll
    for (int t=0;t<9;t++) v[t] = mrow[off[t]];           // unconditional
    float s = 0.0f;
#pragma unroll
    for (int t=0;t<9;t++) s += val[t] ? v[t] : 0.0f;
    denb[(size_t)im12*PP + p] = s;
}

__global__ void k_fin(unsigned* misc, float* bwout){
    int t = threadIdx.x;
    if (t < 12){
        float mn = ord2f(misc[t]);
        float mx = ord2f(misc[12+t]);
        ((int*)misc)[25+t] = (mn + mx == 0.0f) ? 1 : 0;
    }
    if (t == 12) bwout[0] = (float)misc[24] / 480000.0f;
}

// ---------------------------------------------------------------------------
// k_xgen: materialize X[img][px][128] bf16, X = [tg(64) ; feat(64)]
// block = 64 px, 256 threads: thread (px = tid>>2, q = tid&3) handles 16 ch.
// grid (625, 15)
// ---------------------------------------------------------------------------
__global__ __launch_bounds__(256) void k_xgen(const float* __restrict__ bevs,
        const float* __restrict__ maskb, const float* __restrict__ denb,
        const unsigned* __restrict__ misc, short* __restrict__ X)
{
    int tid = threadIdx.x;
    int img = blockIdx.y, bt = img/5, n = img%5;
    int px = blockIdx.x*64 + (tid>>2);
    int q = tid&3;
    int cb = q*16;
    const float* tg = bevs + (size_t)bt*5*64*PP;
    short* xr = X + ((size_t)img*PP + px)*128;

    short tgv[16];
#pragma unroll
    for (int ci=0;ci<16;ci++) tgv[ci] = f2bf(tg[(size_t)(cb+ci)*PP + px]);
    // store tg-half
    *(bf16x8*)&xr[cb]     = *(bf16x8*)&tgv[0];
    *(bf16x8*)&xr[cb + 8] = *(bf16x8*)&tgv[8];

    short fv[16];
    if (n == 0){
#pragma unroll
        for (int ci=0;ci<16;ci++) fv[ci] = tgv[ci];
    } else {
        int im12 = bt*4 + (n-1);
        int off[9]; bool val[9];
        tap_setup(px, off, val);
        const float* mrow = maskb + (size_t)im12*PP;
        float m9[9];
#pragma unroll
        for (int t=0;t<9;t++){
            float mv = mrow[off[t]];                     // unconditional
            m9[t] = val[t] ? mv : 0.0f;                  // zero kills OOB exactly
        }
        float rden = 1.0f/(denb[(size_t)im12*PP + px] + NEPS);
        int iz = ((const int*)misc)[25+im12];
        float mc = m9[4];
        const float* nbb = bevs + (size_t)(bt*5+n)*64*PP;
#pragma unroll 2
        for (int ci=0;ci<16;ci++){
            const float* sc = nbb + (size_t)(cb+ci)*PP;
            float v[9];
#pragma unroll
            for (int t=0;t<9;t++) v[t] = sc[off[t]];     // unconditional
            float num = 0.0f;
#pragma unroll
            for (int t=0;t<9;t++) num = fmaf(m9[t], v[t], num);  // m9=0 => exact no-op
            float center = v[4];
            float xc = iz ? center : fmaf(mc, center, (1.0f-mc)*(num*rden));
            fv[ci] = f2bf(xc);
        }
    }
    *(bf16x8*)&xr[64 + cb]     = *(bf16x8*)&fv[0];
    *(bf16x8*)&xr[64 + cb + 8] = *(bf16x8*)&fv[8];
}

// ---------------------------------------------------------------------------
// k_mlp: GEMM on X. block = 256 px (4 waves x 64 px = 4 m-tiles of 16).
// Weights staged once per block; A-frags direct from global X; per-wave
// private xt2/z2 LDS regions -> no barriers in the main loop.
// grid (157, 15)
// ---------------------------------------------------------------------------
__global__ __launch_bounds__(256) void k_mlp(const short* __restrict__ X,
        const float* __restrict__ w1, const float* __restrict__ b1,
        const float* __restrict__ w2, const float* __restrict__ b2,
        const float* __restrict__ w3, const float* __restrict__ b3,
        const float* __restrict__ w4, const float* __restrict__ b4,
        float* __restrict__ logits)
{
    __shared__ __align__(16) short w1t[128*136];
    __shared__ __align__(16) short w2t[32*136];
    __shared__ __align__(16) short xt2[4*16*136];
    __shared__ __align__(16) float z2[4*16*33];
    __shared__ float b1l[128], b2l[32], b3l[8], w3l[8*33], w4l[8], b4l[1];

    int tid = threadIdx.x;
    int img = blockIdx.y;

    for (int i=tid;i<16384;i+=256) w1t[(i>>7)*136 + (i&127)] = f2bf(w1[i]);
    for (int i=tid;i<4096;i+=256)  w2t[(i>>7)*136 + (i&127)] = f2bf(w2[i]);
    if (tid<256) w3l[(tid>>5)*33 + (tid&31)] = w3[tid];
    if (tid<128) b1l[tid]=b1[tid];
    if (tid<32)  b2l[tid]=b2[tid];
    if (tid<8)   b3l[tid]=b3[tid];
    if (tid<8)   w4l[tid]=w4[tid];
    if (tid==0)  b4l[0]=b4[0];
    __syncthreads();

    int w = tid>>6, l = tid&63;
    int ln = l&15, kg = l>>4;
    const short* Ximg = X + (size_t)img*PP*128;
    short* xt2w = &xt2[w*16*136];
    float* z2w  = &z2[w*16*33];
    int px_base = blockIdx.x*256 + w*64;

#pragma unroll 1
    for (int mt=0; mt<4; mt++){
        int prow = px_base + mt*16;
        int arow = prow + ln; if (arow > PP-1) arow = PP-1;
        const short* xr = Ximg + (size_t)arow*128;
        bf16x8 af[4];
#pragma unroll
        for (int ks=0;ks<4;ks++)
            af[ks] = *(const bf16x8*)&xr[ks*32 + kg*8];

        // layer 1: N=128 (8 n-tiles), K=128
#pragma unroll
        for (int nt=0;nt<8;nt++){
            float bias = b1l[nt*16 + ln];
            f32x4 acc = {bias, bias, bias, bias};
#pragma unroll
            for (int ks=0;ks<4;ks++){
                bf16x8 bf = *(const bf16x8*)&w1t[(nt*16+ln)*136 + ks*32 + kg*8];
                acc = __builtin_amdgcn_mfma_f32_16x16x32_bf16(af[ks], bf, acc, 0, 0, 0);
            }
#pragma unroll
            for (int r=0;r<4;r++)
                xt2w[(kg*4+r)*136 + nt*16 + ln] = f2bf(fmaxf(acc[r], 0.0f));
        }

        // layer 2: N=32, K=128 (A = X2 from per-wave LDS)
        bf16x8 a2[4];
#pragma unroll
        for (int ks=0;ks<4;ks++)
            a2[ks] = *(const bf16x8*)&xt2w[ln*136 + ks*32 + kg*8];
#pragma unroll
        for (int nt2=0;nt2<2;nt2++){
            float bias = b2l[nt2*16 + ln];
            f32x4 acc = {bias, bias, bias, bias};
#pragma unroll
            for (int ks=0;ks<4;ks++){
                bf16x8 bf = *(const bf16x8*)&w2t[(nt2*16+ln)*136 + ks*32 + kg*8];
                acc = __builtin_amdgcn_mfma_f32_16x16x32_bf16(a2[ks], bf, acc, 0, 0, 0);
            }
#pragma unroll
            for (int r=0;r<4;r++)
                z2w[(kg*4+r)*33 + nt2*16 + ln] = fmaxf(acc[r], 0.0f);
        }

        // tail: lane (px16 = ln, k-pair = kg): y3 for k = 2kg, 2kg+1
        int k0 = kg*2, k1 = kg*2+1;
        float y0 = b3l[k0], y1 = b3l[k1];
#pragma unroll
        for (int j=0;j<32;j++){
            float v = z2w[ln*33 + j];
            y0 = fmaf(w3l[k0*33+j], v, y0);
            y1 = fmaf(w3l[k1*33+j], v, y1);
        }
        float part = w4l[k0]*fmaxf(y0,0.0f) + w4l[k1]*fmaxf(y1,0.0f);
        part += __shfl_xor(part, 16, 64);
        part += __shfl_xor(part, 32, 64);
        if (kg == 0 && prow + ln < PP)
            logits[(size_t)img*PP + prow + ln] = fmaxf(part + b4l[0], 0.0f);
    }
}

// ---------------------------------------------------------------------------
// k_fuse2: softmax over logits + weighted sum of feats (tg fp32, warp bf16 from X)
// grid (157, 3, 2): 32-ch groups
// ---------------------------------------------------------------------------
__global__ __launch_bounds__(256) void k_fuse2(const float* __restrict__ bevs,
        const float* __restrict__ logits, const short* __restrict__ X,
        float* __restrict__ out)
{
    int bt = blockIdx.y;
    int cb = blockIdx.z*32;
    int p = blockIdx.x*256 + threadIdx.x;
    if (p >= PP) return;
    float e[5], ssum = 0.0f;
#pragma unroll
    for (int nn=0;nn<5;nn++){ e[nn] = expf(logits[(size_t)(bt*5+nn)*PP + p]); ssum += e[nn]; }
    float rs = 1.0f/ssum;
    const float* tgb = bevs + (size_t)bt*5*64*PP;
    float acc[32];
    float w0 = e[0]*rs;
#pragma unroll
    for (int ci=0;ci<32;ci++) acc[ci] = w0*tgb[(size_t)(cb+ci)*PP + p];
#pragma unroll
    for (int k=0;k<4;k++){
        float wk = e[k+1]*rs;
        const short* Xr = X + ((size_t)(bt*5+k+1)*PP + p)*128 + 64 + cb;
#pragma unroll
        for (int c8=0;c8<4;c8++){
            bf16x8 v = *(const bf16x8*)&Xr[c8*8];
#pragma unroll
            for (int j=0;j<8;j++)
                acc[c8*8+j] = fmaf(wk, bf2f(v[j]), acc[c8*8+j]);
        }
    }
#pragma unroll
    for (int ci=0;ci<32;ci++)
        out[((size_t)bt*64 + cb+ci)*PP + p] = acc[ci];
}

// ---------------------------------------------------------------------------
// FALLBACK path (round-3 fused kernels) if ws too small for X
// ---------------------------------------------------------------------------
__global__ __launch_bounds__(256) void k_pwf(const float* __restrict__ bevs,
        const float* __restrict__ w1, const float* __restrict__ b1,
        const float* __restrict__ w2, const float* __restrict__ b2,
        const float* __restrict__ w3, const float* __restrict__ b3,
        const float* __restrict__ w4, const float* __restrict__ b4,
        const float* __restrict__ maskb, const float* __restrict__ denb,
        const unsigned* __restrict__ misc, float* __restrict__ logits)
{
    __shared__ __align__(16) short w1t[128*136];
    __shared__ __align__(16) short w2t[32*136];
    __shared__ __align__(16) short xt[64*136];
    __shared__ __align__(16) float z2[64*33];
    __shared__ float b1l[128], b2l[32], b3l[8], w3l[256], w4l[8], b4l[1];

    int tid = threadIdx.x;
    int img = blockIdx.y, bt = img/5, n = img%5;

    for (int i=tid;i<16384;i+=256) w1t[(i>>7)*136 + (i&127)] = f2bf(w1[i]);
    for (int i=tid;i<4096;i+=256)  w2t[(i>>7)*136 + (i&127)] = f2bf(w2[i]);
    if (tid<128) b1l[tid]=b1[tid];
    if (tid<32)  b2l[tid]=b2[tid];
    if (tid<8)   b3l[tid]=b3[tid];
    if (tid<256) w3l[tid]=w3[tid];
    if (tid<8)   w4l[tid]=w4[tid];
    if (tid==0)  b4l[0]=b4[0];

    int px = tid&63, q = tid>>6;
    int p = blockIdx.x*64 + px;
    const float* tg = bevs + (size_t)bt*5*64*PP;
    if (n == 0){
#pragma unroll
        for (int ci=0;ci<16;ci++){
            int c = q*16+ci;
            short v = f2bf(tg[(size_t)c*PP + p]);
            xt[px*136 + c] = v;
            xt[px*136 + 64 + c] = v;
        }
    } else {
        int im12 = bt*4 + (n-1);
        int off[9]; bool val[9];
        tap_setup(p, off, val);
        const float* mrow = maskb + (size_t)im12*PP;
        float m9[9];
#pragma unroll
        for (int t=0;t<9;t++) m9[t] = val[t] ? mrow[off[t]] : 0.0f;
        float rden = 1.0f/(denb[(size_t)im12*PP + p] + NEPS);
        int iz = ((const int*)misc)[25+im12];
        float mc = m9[4];
        const float* nbb = bevs + (size_t)(bt*5+n)*64*PP;
#pragma unroll
        for (int ci=0;ci<16;ci++){
            int c = q*16+ci;
            xt[px*136 + c] = f2bf(tg[(size_t)c*PP + p]);
            const float* sc = nbb + (size_t)c*PP;
            float num = 0.0f, center = 0.0f;
#pragma unroll
            for (int t=0;t<9;t++){
                if (val[t]){
                    float v = sc[off[t]];
                    num = fmaf(m9[t], v, num);
                    if (t==4) center = v;
                }
            }
            float xc = iz ? center : fmaf(mc, center, (1.0f-mc)*(num*rden));
            xt[px*136 + 64 + c] = f2bf(xc);
        }
    }
    __syncthreads();

    int w = tid>>6, l = tid&63;
    int ln = l&15, kg = l>>4;
    bf16x8 af[4];
#pragma unroll
    for (int ks=0;ks<4;ks++)
        af[ks] = *(const bf16x8*)&xt[(w*16+ln)*136 + ks*32 + kg*8];
#pragma unroll
    for (int nt=0;nt<8;nt++){
        float bias = b1l[nt*16 + ln];
        f32x4 acc = {bias, bias, bias, bias};
#pragma unroll
        for (int ks=0;ks<4;ks++){
            bf16x8 bf = *(const bf16x8*)&w1t[(nt*16+ln)*136 + ks*32 + kg*8];
            acc = __builtin_amdgcn_mfma_f32_16x16x32_bf16(af[ks], bf, acc, 0, 0, 0);
        }
#pragma unroll
        for (int r=0;r<4;r++){
            int pr = w*16 + kg*4 + r;
            xt[pr*136 + nt*16 + ln] = f2bf(fmaxf(acc[r], 0.0f));
        }
    }
    bf16x8 a2[4];
#pragma unroll
    for (int ks=0;ks<4;ks++)
        a2[ks] = *(const bf16x8*)&xt[(w*16+ln)*136 + ks*32 + kg*8];
#pragma unroll
    for (int nt2=0;nt2<2;nt2++){
        float bias = b2l[nt2*16 + ln];
        f32x4 acc = {bias, bias, bias, bias};
#pragma unroll
        for (int ks=0;ks<4;ks++){
            bf16x8 bf = *(const bf16x8*)&w2t[(nt2*16+ln)*136 + ks*32 + kg*8];
            acc = __builtin_amdgcn_mfma_f32_16x16x32_bf16(a2[ks], bf, acc, 0, 0, 0);
        }
#pragma unroll
        for (int r=0;r<4;r++){
            int pr = w*16 + kg*4 + r;
            z2[pr*33 + nt2*16 + ln] = fmaxf(acc[r], 0.0f);
        }
    }
    __syncthreads();
    if (tid < 64){
        float y3[8];
#pragma unroll
        for (int k=0;k<8;k++) y3[k] = b3l[k];
        for (int j=0;j<32;j++){
            float v = z2[tid*33 + j];
#pragma unroll
            for (int k=0;k<8;k++) y3[k] = fmaf(w3l[k*32+j], v, y3[k]);
        }
        float sres = b4l[0];
#pragma unroll
        for (int k=0;k<8;k++) sres = fmaf(w4l[k], fmaxf(y3[k], 0.0f), sres);
        logits[(size_t)img*PP + blockIdx.x*64 + tid] = fmaxf(sres, 0.0f);
    }
}

__global__ __launch_bounds__(256) void k_fuse_old(const float* __restrict__ bevs,
        const float* __restrict__ logits, const float* __restrict__ maskb,
        const float* __restrict__ denb, const unsigned* __restrict__ misc,
        float* __restrict__ out)
{
    int bt = blockIdx.y;
    int p = blockIdx.x*256 + threadIdx.x;
    if (p >= PP) return;
    int off[9]; bool val[9];
    tap_setup(p, off, val);
    float e[5], ssum = 0.0f;
#pragma unroll
    for (int nn=0;nn<5;nn++){ e[nn] = expf(logits[(size_t)(bt*5+nn)*PP + p]); ssum += e[nn]; }
    float wts[5];
#pragma unroll
    for (int nn=0;nn<5;nn++) wts[nn] = e[nn] / ssum;
    float m9[4][9]; float rden[4]; int iz[4];
#pragma unroll
    for (int k=0;k<4;k++){
        int im12 = bt*4 + k;
        const float* mrow = maskb + (size_t)im12*PP;
#pragma unroll
        for (int t=0;t<9;t++) m9[k][t] = val[t] ? mrow[off[t]] : 0.0f;
        rden[k] = 1.0f/(denb[(size_t)im12*PP + p] + NEPS);
        iz[k] = ((const int*)misc)[25+im12];
    }
    const float* base = bevs + (size_t)bt*5*64*PP;
    for (int c=0;c<64;c++){
        float tgc = base[(size_t)c*PP + p];
        float fused = wts[0]*tgc;
#pragma unroll
        for (int k=0;k<4;k++){
            const float* sc = base + (size_t)(k+1)*64*PP + (size_t)c*PP;
            float num = 0.0f, center = 0.0f;
#pragma unroll
            for (int t=0;t<9;t++){
                if (val[t]){
                    float v = sc[off[t]];
                    num = fmaf(m9[k][t], v, num);
                    if (t==4) center = v;
                }
            }
            float mc = m9[k][4];
            float xc = iz[k] ? center : fmaf(mc, center, (1.0f-mc)*(num*rden[k]));
            fused = fmaf(wts[k+1], xc, fused);
        }
        out[((size_t)bt*64 + c)*PP + p] = fused;
    }
}

extern "C" void kernel_launch(void* const* d_in, const int* in_sizes, int n_in,
                              void* d_out, int out_size, void* d_ws, size_t ws_size,
                              hipStream_t stream)
{
    const float* bevs = (const float*)d_in[0];
    const float* cw  = (const float*)d_in[1];
    const float* cb  = (const float*)d_in[2];
    const float* w1  = (const float*)d_in[3];
    const float* b1  = (const float*)d_in[4];
    const float* w2  = (const float*)d_in[5];
    const float* b2  = (const float*)d_in[6];
    const float* w3  = (const float*)d_in[7];
    const float* b3  = (const float*)d_in[8];
    const float* w4  = (const float*)d_in[9];
    const float* b4  = (const float*)d_in[10];
    float* out = (float*)d_out;
    float* ws = (float*)d_ws;

    float* com    = ws + OFF_COM;
    float* ent    = ws + OFF_ENT;
    float* maskb  = ws + OFF_MASK;
    float* denb   = ws + OFF_DEN;
    float* logits = ws + OFF_LOGITS;
    unsigned* misc = (unsigned*)(ws + OFF_MISC);
    short* X      = (short*)(ws + OFF_X_F);
    float* z      = (float*)(ws + OFF_X_F);   // overlaps X; dead before X written

    dim3 blk(256,1,1);
    int gx = (PP + 255)/256;
    bool big = ws_size >= WS_NEED;

    k_init<<<dim3(1),dim3(64),0,stream>>>(misc);
    if (big){
        k_csum<<<dim3((PP/4+255)/256,15),blk,0,stream>>>(bevs,cw,misc,z);
        k_cfin<<<dim3(gx,15),blk,0,stream>>>(z,cb,com);
    } else {
        k_conv<<<dim3(gx,15),blk,0,stream>>>(bevs,cw,cb,com,misc);
    }
    k_ent <<<dim3(gx,15),blk,0,stream>>>(com,ent);
    k_mask<<<dim3(gx,12),blk,0,stream>>>(ent,maskb,misc);
    k_den <<<dim3(gx,12),blk,0,stream>>>(maskb,denb);
    k_fin <<<dim3(1),dim3(64),0,stream>>>(misc, out + (size_t)3*64*PP);

    if (big){
        k_xgen <<<dim3(PP/64,15),blk,0,stream>>>(bevs,maskb,denb,misc,X);
        k_mlp  <<<dim3(gx,15),blk,0,stream>>>(X,w1,b1,w2,b2,w3,b3,w4,b4,logits);
        k_fuse2<<<dim3(gx,3,2),blk,0,stream>>>(bevs,logits,X,out);
    } else {
        k_pwf  <<<dim3(PP/64,15),blk,0,stream>>>(bevs,w1,b1,w2,b2,w3,b3,w4,b4,maskb,denb,misc,logits);
        k_fuse_old<<<dim3(gx,3),blk,0,stream>>>(bevs,logits,maskb,denb,misc,out);
    }
}

// Round 7
// 408.965 us; speedup vs baseline: 5.2360x; 1.1100x over previous
//
#include <hip/hip_runtime.h>
#include <hip/hip_bf16.h>
#include <math.h>

#define PP 40000
#define HDIM 200
#define WDIM 200
#define NEPS 1e-8f

// workspace layout (float offsets)
#define OFF_COM    0            // 15*PP
#define OFF_ENT    (15*PP)      // 15*PP
#define OFF_MASK   (30*PP)      // 12*PP
#define OFF_DEN    (42*PP)      // 12*PP
#define OFF_LOGITS (54*PP)      // 15*PP
#define OFF_MISC   (69*PP)      // 64 floats
#define OFF_XTG_F  (69*PP + 64)             // Xtg bf16: 3*PP*64 shorts = 3*PP*32 floats
#define OFF_XFT_F  (OFF_XTG_F + 3*PP*32)    // Xft bf16: 12*PP*64 shorts; z fp32 (15*9*PP) overlaps (dead before Xft written)
#define WS_NEED ((size_t)(69*PP + 64)*4 + (size_t)15*PP*64*2)

typedef __attribute__((ext_vector_type(8))) short bf16x8;
typedef __attribute__((ext_vector_type(4))) float f32x4;

__device__ __forceinline__ short f2bf(float f){
    __hip_bfloat16 h = __float2bfloat16(f);   // RTNE
    return *reinterpret_cast<short*>(&h);
}
__device__ __forceinline__ float bf2f(short s){
    return __uint_as_float(((unsigned)(unsigned short)s) << 16);
}

__device__ __forceinline__ unsigned f2ord(float f){
    unsigned u = __float_as_uint(f);
    return (u & 0x80000000u) ? ~u : (u | 0x80000000u);
}
__device__ __forceinline__ float ord2f(unsigned u){
    unsigned v = (u & 0x80000000u) ? (u & 0x7fffffffu) : ~u;
    return __uint_as_float(v);
}

// Clamped tap offsets (per-pixel scalar form, used by small kernels)
__device__ __forceinline__ void tap_setup(int p, int* off, bool* val){
    int h = p / WDIM, w = p - h*WDIM;
#pragma unroll
    for (int ky=0;ky<3;ky++)
#pragma unroll
        for (int kx=0;kx<3;kx++){
            int t = ky*3+kx;
            int hh = h+ky-1, ww = w+kx-1;
            val[t] = (hh>=0)&&(hh<HDIM)&&(ww>=0)&&(ww<WDIM);
            int hc = min(max(hh,0),HDIM-1);
            int wc = min(max(ww,0),WDIM-1);
            off[t] = hc*WDIM+wc;
        }
}

__global__ void k_init(unsigned* misc){
    int t = threadIdx.x;
    if (t < 12) misc[t] = 0xFFFFFFFFu;        // min (sortable) = +inf
    else if (t < 25) misc[t] = 0u;            // max = -inf, count = 0
}

// ---------------------------------------------------------------------------
// conv pass 1: z_t(q) = sum_c w[c,t] * x[c,q]; min/max fused.
// ---------------------------------------------------------------------------
__global__ __launch_bounds__(256) void k_csum(const float* __restrict__ bevs,
        const float* __restrict__ cw, unsigned* __restrict__ misc,
        float* __restrict__ z)
{
    int img = blockIdx.y;
    int n = img % 5;
    int idx = blockIdx.x*256 + threadIdx.x;
    bool act = idx < PP/4;
    int p = idx*4;
    float vmin = INFINITY, vmax = -INFINITY;
    f32x4 acc[9];
#pragma unroll
    for (int t=0;t<9;t++) acc[t] = (f32x4){0.f,0.f,0.f,0.f};
    if (act){
        const float* src = bevs + (size_t)img*64*PP;
#pragma unroll 2
        for (int c=0;c<64;c++){
            f32x4 v = *(const f32x4*)&src[(size_t)c*PP + p];
            vmin = fminf(fminf(fminf(vmin, v[0]), fminf(v[1], v[2])), v[3]);
            vmax = fmaxf(fmaxf(fmaxf(vmax, v[0]), fmaxf(v[1], v[2])), v[3]);
#pragma unroll
            for (int t=0;t<9;t++){
                float w = cw[c*9+t];
#pragma unroll
                for (int j=0;j<4;j++) acc[t][j] = fmaf(w, v[j], acc[t][j]);
            }
        }
        float* zimg = z + (size_t)img*9*PP;
#pragma unroll
        for (int t=0;t<9;t++)
            *(f32x4*)&zimg[(size_t)t*PP + p] = acc[t];
    }
    if (n > 0){
#pragma unroll
        for (int s=32;s>0;s>>=1){
            vmin = fminf(vmin, __shfl_xor(vmin, s, 64));
            vmax = fmaxf(vmax, __shfl_xor(vmax, s, 64));
        }
        if ((threadIdx.x & 63) == 0){
            int im12 = (img/5)*4 + (n-1);
            atomicMin(&misc[im12], f2ord(vmin));
            atomicMax(&misc[12+im12], f2ord(vmax));
        }
    }
}

// conv pass 2: com(p) = relu(cb + sum_t [val] z_t(p+delta_t))
__global__ __launch_bounds__(256) void k_cfin(const float* __restrict__ z,
        const float* __restrict__ cb, float* __restrict__ com)
{
    int img = blockIdx.y;
    int p = blockIdx.x*256 + threadIdx.x;
    if (p >= PP) return;
    int off[9]; bool val[9];
    tap_setup(p, off, val);
    const float* zimg = z + (size_t)img*9*PP;
    float v[9];
#pragma unroll
    for (int t=0;t<9;t++) v[t] = zimg[(size_t)t*PP + off[t]];
    float acc = cb[0];
#pragma unroll
    for (int t=0;t<9;t++) acc += val[t] ? v[t] : 0.0f;
    com[(size_t)img*PP + p] = fmaxf(acc, 0.0f);
}

// ---------------------------------------------------------------------------
// FALLBACK conv if ws too small
// ---------------------------------------------------------------------------
__global__ __launch_bounds__(256) void k_conv(const float* __restrict__ bevs,
        const float* __restrict__ cw, const float* __restrict__ cb,
        float* __restrict__ com, unsigned* __restrict__ misc)
{
    int img = blockIdx.y;
    int n = img % 5;
    int p = blockIdx.x*256 + threadIdx.x;
    float vmin = INFINITY, vmax = -INFINITY;
    if (p < PP){
        int off[9]; bool val[9];
        tap_setup(p, off, val);
        const float* src = bevs + (size_t)img*64*PP;
        float acc = cb[0];
#pragma unroll 2
        for (int c=0;c<64;c++){
            const float* sc = src + (size_t)c*PP;
            float v[9];
#pragma unroll
            for (int t=0;t<9;t++) v[t] = sc[off[t]];
            vmin = fminf(vmin, v[4]); vmax = fmaxf(vmax, v[4]);
#pragma unroll
            for (int t=0;t<9;t++)
                acc = fmaf(cw[c*9+t], val[t] ? v[t] : 0.0f, acc);
        }
        com[(size_t)img*PP + p] = fmaxf(acc, 0.0f);
    }
    if (n > 0){
#pragma unroll
        for (int s=32;s>0;s>>=1){
            vmin = fminf(vmin, __shfl_xor(vmin, s, 64));
            vmax = fmaxf(vmax, __shfl_xor(vmax, s, 64));
        }
        if ((threadIdx.x & 63) == 0){
            int im12 = (img/5)*4 + (n-1);
            atomicMin(&misc[im12], f2ord(vmin));
            atomicMax(&misc[12+im12], f2ord(vmax));
        }
    }
}

__global__ __launch_bounds__(256) void k_ent(const float* __restrict__ com,
        float* __restrict__ ent)
{
    int img = blockIdx.y;
    int p = blockIdx.x*256 + threadIdx.x;
    if (p >= PP) return;
    int off[9]; bool val[9];
    tap_setup(p, off, val);
    const float* s = com + (size_t)img*PP;
    float x = s[p];
    float v[9];
#pragma unroll
    for (int t=0;t<9;t++) v[t] = s[off[t]];
    float acc = 0.0f;
#pragma unroll
    for (int t=0;t<9;t++){
        float xv = val[t] ? v[t] : 0.0f;
        acc += 1.0f/(1.0f + expf(x - xv));
    }
    ent[(size_t)img*PP + p] = acc / 9.0f;
}

__global__ __launch_bounds__(256) void k_mask(const float* __restrict__ ent,
        float* __restrict__ maskb, unsigned* __restrict__ misc)
{
    int im12 = blockIdx.y; int bt = im12 >> 2; int n = (im12 & 3) + 1;
    int p = blockIdx.x*256 + threadIdx.x;
    int v = 0;
    if (p < PP){
        float en = ent[(size_t)(bt*5+n)*PP + p];
        float et = ent[(size_t)(bt*5)*PP + p];
        v = en > et;
        maskb[(size_t)im12*PP + p] = (float)v;
    }
    unsigned long long bal = __ballot(v);
    if ((threadIdx.x & 63) == 0) atomicAdd(&misc[24], (unsigned)__popcll(bal));
}

__global__ __launch_bounds__(256) void k_den(const float* __restrict__ maskb,
        float* __restrict__ denb)
{
    int im12 = blockIdx.y;
    int p = blockIdx.x*256 + threadIdx.x;
    if (p >= PP) return;
    int off[9]; bool val[9];
    tap_setup(p, off, val);
    const float* mrow = maskb + (size_t)im12*PP;
    float v[9];
#pragma unroll
    for (int t=0;t<9;t++) v[t] = mrow[off[t]];
    float s = 0.0f;
#pragma unroll
    for (int t=0;t<9;t++) s += val[t] ? v[t] : 0.0f;
    denb[(size_t)im12*PP + p] = s;
}

__global__ void k_fin(unsigned* misc, float* bwout){
    int t = threadIdx.x;
    if (t < 12){
        float mn = ord2f(misc[t]);
        float mx = ord2f(misc[12+t]);
        ((int*)misc)[25+t] = (mn + mx == 0.0f) ? 1 : 0;
    }
    if (t == 12) bwout[0] = (float)misc[24] / 480000.0f;
}

// ---------------------------------------------------------------------------
// k_xtg: Xtg[bt][px][64] = bf16(tg), LDS transpose. grid (625, 3), block 256.
// ---------------------------------------------------------------------------
__global__ __launch_bounds__(256) void k_xtg(const float* __restrict__ bevs,
        short* __restrict__ Xtg)
{
    __shared__ short tile[64][72];     // [px_local][ch], rows 144B (16B-mult)
    int tid = threadIdx.x;
    int bt = blockIdx.y;
    int px0 = blockIdx.x*64;
    const float* tg = bevs + (size_t)bt*5*64*PP;
    int c = tid>>2, q = tid&3;
#pragma unroll
    for (int j=0;j<4;j++){
        int pxl = q*16 + j*4;
        f32x4 v = *(const f32x4*)&tg[(size_t)c*PP + px0 + pxl];
#pragma unroll
        for (int e=0;e<4;e++) tile[pxl+e][c] = f2bf(v[e]);
    }
    __syncthreads();
    int pxl = tid>>2;
    short* dst = Xtg + ((size_t)bt*PP + px0 + pxl)*64 + q*16;
    *(bf16x8*)&dst[0] = *(bf16x8*)&tile[pxl][q*16];
    *(bf16x8*)&dst[8] = *(bf16x8*)&tile[pxl][q*16+8];
}

// ---------------------------------------------------------------------------
// k_xft: Xft[im12][px][64] = bf16(warp). Thread owns 4 consecutive px.
// All loads are 16B-aligned f32x4 row windows (W=200 % 4 == 0; groups never
// cross rows). OOB taps annihilated exactly via zeroed mask values.
// grid (40, 12), block 256.
// ---------------------------------------------------------------------------
__global__ __launch_bounds__(256) void k_xft(const float* __restrict__ bevs,
        const float* __restrict__ maskb, const float* __restrict__ denb,
        const unsigned* __restrict__ misc, short* __restrict__ Xft)
{
    int im12 = blockIdx.y; int bt = im12 >> 2; int n = (im12 & 3) + 1;
    int idx = blockIdx.x*256 + threadIdx.x;
    if (idx >= PP/4) return;
    int p = idx*4;
    int row = p / WDIM, col0 = p - row*WDIM;
    int s0 = max(col0-4, 0), s2 = min(col0+4, WDIM-4);
    int rowc[3]; bool rowok[3];
#pragma unroll
    for (int r=0;r<3;r++){
        int rr = row + r - 1;
        rowok[r] = (rr>=0) && (rr<HDIM);
        rowc[r] = min(max(rr,0),HDIM-1) * WDIM;
    }
    bool colok[6];
#pragma unroll
    for (int k=0;k<6;k++){
        int cc = col0 + k - 1;
        colok[k] = (cc>=0) && (cc<WDIM);
    }
    // mask window: m6[r][k], k=0..5 <-> col col0-1+k ... annihilates OOB
    const float* mrow = maskb + (size_t)im12*PP;
    float m6[3][6];
#pragma unroll
    for (int r=0;r<3;r++){
        f32x4 a0 = *(const f32x4*)&mrow[rowc[r] + s0];
        f32x4 a1 = *(const f32x4*)&mrow[rowc[r] + col0];
        f32x4 a2 = *(const f32x4*)&mrow[rowc[r] + s2];
        float mv[6] = {a0[3], a1[0], a1[1], a1[2], a1[3], a2[0]};
#pragma unroll
        for (int k=0;k<6;k++)
            m6[r][k] = (rowok[r] && colok[k]) ? mv[k] : 0.0f;
    }
    f32x4 den4 = *(const f32x4*)&denb[(size_t)im12*PP + p];
    float rden[4];
#pragma unroll
    for (int j=0;j<4;j++) rden[j] = 1.0f/(den4[j] + NEPS);
    int iz = ((const int*)misc)[25+im12];
    const float* nbb = bevs + (size_t)(bt*5+n)*64*PP;
    short* xr = Xft + (size_t)im12*PP*64;

#pragma unroll 1
    for (int ch=0; ch<4; ch++){
        short fv0[16], fv1[16], fv2[16], fv3[16];
#pragma unroll
        for (int ci=0;ci<16;ci++){
            int c = ch*16 + ci;
            const float* sc = nbb + (size_t)c*PP;
            f32x4 v0[3], v1[3], v2[3];
#pragma unroll
            for (int r=0;r<3;r++){
                v0[r] = *(const f32x4*)&sc[rowc[r] + s0];
                v1[r] = *(const f32x4*)&sc[rowc[r] + col0];
                v2[r] = *(const f32x4*)&sc[rowc[r] + s2];
            }
            // v at (r, k): k=0 -> v0[r].w ; 1..4 -> v1[r][k-1] ; 5 -> v2[r].x
            float num[4];
#pragma unroll
            for (int j=0;j<4;j++) num[j] = 0.0f;
#pragma unroll
            for (int r=0;r<3;r++){
                float vv[6] = {v0[r][3], v1[r][0], v1[r][1], v1[r][2], v1[r][3], v2[r][0]};
#pragma unroll
                for (int j=0;j<4;j++){
#pragma unroll
                    for (int dk=0;dk<3;dk++)
                        num[j] = fmaf(m6[r][j+dk], vv[j+dk], num[j]);
                }
            }
            short out4[4];
#pragma unroll
            for (int j=0;j<4;j++){
                float center = v1[1][j];
                float mc = m6[1][j+1];
                float xc = iz ? center : fmaf(mc, center, (1.0f-mc)*(num[j]*rden[j]));
                out4[j] = f2bf(xc);
            }
            fv0[ci]=out4[0]; fv1[ci]=out4[1]; fv2[ci]=out4[2]; fv3[ci]=out4[3];
        }
        short* x0 = xr + (size_t)(p+0)*64 + ch*16;
        short* x1 = xr + (size_t)(p+1)*64 + ch*16;
        short* x2 = xr + (size_t)(p+2)*64 + ch*16;
        short* x3 = xr + (size_t)(p+3)*64 + ch*16;
        *(bf16x8*)&x0[0] = *(bf16x8*)&fv0[0]; *(bf16x8*)&x0[8] = *(bf16x8*)&fv0[8];
        *(bf16x8*)&x1[0] = *(bf16x8*)&fv1[0]; *(bf16x8*)&x1[8] = *(bf16x8*)&fv1[8];
        *(bf16x8*)&x2[0] = *(bf16x8*)&fv2[0]; *(bf16x8*)&x2[8] = *(bf16x8*)&fv2[8];
        *(bf16x8*)&x3[0] = *(bf16x8*)&fv3[0]; *(bf16x8*)&x3[8] = *(bf16x8*)&fv3[8];
    }
}

// ---------------------------------------------------------------------------
// k_mlp: GEMM. A-frags: k0..63 from Xtg, k64..127 from Xft (n=0: Xtg again).
// grid (157, 15), block 256.
// ---------------------------------------------------------------------------
__global__ __launch_bounds__(256) void k_mlp(const short* __restrict__ Xtg,
        const short* __restrict__ Xft,
        const float* __restrict__ w1, const float* __restrict__ b1,
        const float* __restrict__ w2, const float* __restrict__ b2,
        const float* __restrict__ w3, const float* __restrict__ b3,
        const float* __restrict__ w4, const float* __restrict__ b4,
        float* __restrict__ logits)
{
    __shared__ __align__(16) short w1t[128*136];
    __shared__ __align__(16) short w2t[32*136];
    __shared__ __align__(16) short xt2[4*16*136];
    __shared__ __align__(16) float z2[4*16*33];
    __shared__ float b1l[128], b2l[32], b3l[8], w3l[8*33], w4l[8], b4l[1];

    int tid = threadIdx.x;
    int img = blockIdx.y, bt = img/5, n = img%5;

    for (int i=tid;i<16384;i+=256) w1t[(i>>7)*136 + (i&127)] = f2bf(w1[i]);
    for (int i=tid;i<4096;i+=256)  w2t[(i>>7)*136 + (i&127)] = f2bf(w2[i]);
    if (tid<256) w3l[(tid>>5)*33 + (tid&31)] = w3[tid];
    if (tid<128) b1l[tid]=b1[tid];
    if (tid<32)  b2l[tid]=b2[tid];
    if (tid<8)   b3l[tid]=b3[tid];
    if (tid<8)   w4l[tid]=w4[tid];
    if (tid==0)  b4l[0]=b4[0];
    __syncthreads();

    int w = tid>>6, l = tid&63;
    int ln = l&15, kg = l>>4;
    const short* xtgb = Xtg + (size_t)bt*PP*64;
    const short* xftb = (n>0) ? (Xft + (size_t)(bt*4+n-1)*PP*64) : xtgb;
    short* xt2w = &xt2[w*16*136];
    float* z2w  = &z2[w*16*33];
    int px_base = blockIdx.x*256 + w*64;

#pragma unroll 1
    for (int mt=0; mt<4; mt++){
        int prow = px_base + mt*16;
        int arow = prow + ln; if (arow > PP-1) arow = PP-1;
        const short* xr0 = xtgb + (size_t)arow*64;
        const short* xr1 = xftb + (size_t)arow*64;
        bf16x8 af[4];
        af[0] = *(const bf16x8*)&xr0[kg*8];
        af[1] = *(const bf16x8*)&xr0[32 + kg*8];
        af[2] = *(const bf16x8*)&xr1[kg*8];
        af[3] = *(const bf16x8*)&xr1[32 + kg*8];

        // layer 1: N=128 (8 n-tiles), K=128
#pragma unroll
        for (int nt=0;nt<8;nt++){
            float bias = b1l[nt*16 + ln];
            f32x4 acc = {bias, bias, bias, bias};
#pragma unroll
            for (int ks=0;ks<4;ks++){
                bf16x8 bf = *(const bf16x8*)&w1t[(nt*16+ln)*136 + ks*32 + kg*8];
                acc = __builtin_amdgcn_mfma_f32_16x16x32_bf16(af[ks], bf, acc, 0, 0, 0);
            }
#pragma unroll
            for (int r=0;r<4;r++)
                xt2w[(kg*4+r)*136 + nt*16 + ln] = f2bf(fmaxf(acc[r], 0.0f));
        }

        // layer 2: N=32, K=128
        bf16x8 a2[4];
#pragma unroll
        for (int ks=0;ks<4;ks++)
            a2[ks] = *(const bf16x8*)&xt2w[ln*136 + ks*32 + kg*8];
#pragma unroll
        for (int nt2=0;nt2<2;nt2++){
            float bias = b2l[nt2*16 + ln];
            f32x4 acc = {bias, bias, bias, bias};
#pragma unroll
            for (int ks=0;ks<4;ks++){
                bf16x8 bf = *(const bf16x8*)&w2t[(nt2*16+ln)*136 + ks*32 + kg*8];
                acc = __builtin_amdgcn_mfma_f32_16x16x32_bf16(a2[ks], bf, acc, 0, 0, 0);
            }
#pragma unroll
            for (int r=0;r<4;r++)
                z2w[(kg*4+r)*33 + nt2*16 + ln] = fmaxf(acc[r], 0.0f);
        }

        // tail
        int k0 = kg*2, k1 = kg*2+1;
        float y0 = b3l[k0], y1 = b3l[k1];
#pragma unroll
        for (int j=0;j<32;j++){
            float v = z2w[ln*33 + j];
            y0 = fmaf(w3l[k0*33+j], v, y0);
            y1 = fmaf(w3l[k1*33+j], v, y1);
        }
        float part = w4l[k0]*fmaxf(y0,0.0f) + w4l[k1]*fmaxf(y1,0.0f);
        part += __shfl_xor(part, 16, 64);
        part += __shfl_xor(part, 32, 64);
        if (kg == 0 && prow + ln < PP)
            logits[(size_t)img*PP + prow + ln] = fmaxf(part + b4l[0], 0.0f);
    }
}

// ---------------------------------------------------------------------------
// k_fuse2: softmax + weighted sum (tg fp32 from bevs, warp bf16 from Xft)
// grid (157, 3, 2)
// ---------------------------------------------------------------------------
__global__ __launch_bounds__(256) void k_fuse2(const float* __restrict__ bevs,
        const float* __restrict__ logits, const short* __restrict__ Xft,
        float* __restrict__ out)
{
    int bt = blockIdx.y;
    int cb = blockIdx.z*32;
    int p = blockIdx.x*256 + threadIdx.x;
    if (p >= PP) return;
    float e[5], ssum = 0.0f;
#pragma unroll
    for (int nn=0;nn<5;nn++){ e[nn] = expf(logits[(size_t)(bt*5+nn)*PP + p]); ssum += e[nn]; }
    float rs = 1.0f/ssum;
    const float* tgb = bevs + (size_t)bt*5*64*PP;
    float acc[32];
    float w0 = e[0]*rs;
#pragma unroll
    for (int ci=0;ci<32;ci++) acc[ci] = w0*tgb[(size_t)(cb+ci)*PP + p];
#pragma unroll
    for (int k=0;k<4;k++){
        float wk = e[k+1]*rs;
        const short* Xr = Xft + ((size_t)(bt*4+k)*PP + p)*64 + cb;
#pragma unroll
        for (int c8=0;c8<4;c8++){
            bf16x8 v = *(const bf16x8*)&Xr[c8*8];
#pragma unroll
            for (int j=0;j<8;j++)
                acc[c8*8+j] = fmaf(wk, bf2f(v[j]), acc[c8*8+j]);
        }
    }
#pragma unroll
    for (int ci=0;ci<32;ci++)
        out[((size_t)bt*64 + cb+ci)*PP + p] = acc[ci];
}

// ---------------------------------------------------------------------------
// FALLBACK path (fused kernels) if ws too small
// ---------------------------------------------------------------------------
__global__ __launch_bounds__(256) void k_pwf(const float* __restrict__ bevs,
        const float* __restrict__ w1, const float* __restrict__ b1,
        const float* __restrict__ w2, const float* __restrict__ b2,
        const float* __restrict__ w3, const float* __restrict__ b3,
        const float* __restrict__ w4, const float* __restrict__ b4,
        const float* __restrict__ maskb, const float* __restrict__ denb,
        const unsigned* __restrict__ misc, float* __restrict__ logits)
{
    __shared__ __align__(16) short w1t[128*136];
    __shared__ __align__(16) short w2t[32*136];
    __shared__ __align__(16) short xt[64*136];
    __shared__ __align__(16) float z2[64*33];
    __shared__ float b1l[128], b2l[32], b3l[8], w3l[256], w4l[8], b4l[1];

    int tid = threadIdx.x;
    int img = blockIdx.y, bt = img/5, n = img%5;

    for (int i=tid;i<16384;i+=256) w1t[(i>>7)*136 + (i&127)] = f2bf(w1[i]);
    for (int i=tid;i<4096;i+=256)  w2t[(i>>7)*136 + (i&127)] = f2bf(w2[i]);
    if (tid<128) b1l[tid]=b1[tid];
    if (tid<32)  b2l[tid]=b2[tid];
    if (tid<8)   b3l[tid]=b3[tid];
    if (tid<256) w3l[tid]=w3[tid];
    if (tid<8)   w4l[tid]=w4[tid];
    if (tid==0)  b4l[0]=b4[0];

    int px = tid&63, q = tid>>6;
    int p = blockIdx.x*64 + px;
    const float* tg = bevs + (size_t)bt*5*64*PP;
    if (n == 0){
#pragma unroll
        for (int ci=0;ci<16;ci++){
            int c = q*16+ci;
            short v = f2bf(tg[(size_t)c*PP + p]);
            xt[px*136 + c] = v;
            xt[px*136 + 64 + c] = v;
        }
    } else {
        int im12 = bt*4 + (n-1);
        int off[9]; bool val[9];
        tap_setup(p, off, val);
        const float* mrow = maskb + (size_t)im12*PP;
        float m9[9];
#pragma unroll
        for (int t=0;t<9;t++) m9[t] = val[t] ? mrow[off[t]] : 0.0f;
        float rden = 1.0f/(denb[(size_t)im12*PP + p] + NEPS);
        int iz = ((const int*)misc)[25+im12];
        float mc = m9[4];
        const float* nbb = bevs + (size_t)(bt*5+n)*64*PP;
#pragma unroll
        for (int ci=0;ci<16;ci++){
            int c = q*16+ci;
            xt[px*136 + c] = f2bf(tg[(size_t)c*PP + p]);
            const float* sc = nbb + (size_t)c*PP;
            float num = 0.0f, center = 0.0f;
#pragma unroll
            for (int t=0;t<9;t++){
                if (val[t]){
                    float v = sc[off[t]];
                    num = fmaf(m9[t], v, num);
                    if (t==4) center = v;
                }
            }
            float xc = iz ? center : fmaf(mc, center, (1.0f-mc)*(num*rden));
            xt[px*136 + 64 + c] = f2bf(xc);
        }
    }
    __syncthreads();

    int w = tid>>6, l = tid&63;
    int ln = l&15, kg = l>>4;
    bf16x8 af[4];
#pragma unroll
    for (int ks=0;ks<4;ks++)
        af[ks] = *(const bf16x8*)&xt[(w*16+ln)*136 + ks*32 + kg*8];
#pragma unroll
    for (int nt=0;nt<8;nt++){
        float bias = b1l[nt*16 + ln];
        f32x4 acc = {bias, bias, bias, bias};
#pragma unroll
        for (int ks=0;ks<4;ks++){
            bf16x8 bf = *(const bf16x8*)&w1t[(nt*16+ln)*136 + ks*32 + kg*8];
            acc = __builtin_amdgcn_mfma_f32_16x16x32_bf16(af[ks], bf, acc, 0, 0, 0);
        }
#pragma unroll
        for (int r=0;r<4;r++){
            int pr = w*16 + kg*4 + r;
            xt[pr*136 + nt*16 + ln] = f2bf(fmaxf(acc[r], 0.0f));
        }
    }
    bf16x8 a2[4];
#pragma unroll
    for (int ks=0;ks<4;ks++)
        a2[ks] = *(const bf16x8*)&xt[(w*16+ln)*136 + ks*32 + kg*8];
#pragma unroll
    for (int nt2=0;nt2<2;nt2++){
        float bias = b2l[nt2*16 + ln];
        f32x4 acc = {bias, bias, bias, bias};
#pragma unroll
        for (int ks=0;ks<4;ks++){
            bf16x8 bf = *(const bf16x8*)&w2t[(nt2*16+ln)*136 + ks*32 + kg*8];
            acc = __builtin_amdgcn_mfma_f32_16x16x32_bf16(a2[ks], bf, acc, 0, 0, 0);
        }
#pragma unroll
        for (int r=0;r<4;r++){
            int pr = w*16 + kg*4 + r;
            z2[pr*33 + nt2*16 + ln] = fmaxf(acc[r], 0.0f);
        }
    }
    __syncthreads();
    if (tid < 64){
        float y3[8];
#pragma unroll
        for (int k=0;k<8;k++) y3[k] = b3l[k];
        for (int j=0;j<32;j++){
            float v = z2[tid*33 + j];
#pragma unroll
            for (int k=0;k<8;k++) y3[k] = fmaf(w3l[k*32+j], v, y3[k]);
        }
        float sres = b4l[0];
#pragma unroll
        for (int k=0;k<8;k++) sres = fmaf(w4l[k], fmaxf(y3[k], 0.0f), sres);
        logits[(size_t)img*PP + blockIdx.x*64 + tid] = fmaxf(sres, 0.0f);
    }
}

__global__ __launch_bounds__(256) void k_fuse_old(const float* __restrict__ bevs,
        const float* __restrict__ logits, const float* __restrict__ maskb,
        const float* __restrict__ denb, const unsigned* __restrict__ misc,
        float* __restrict__ out)
{
    int bt = blockIdx.y;
    int p = blockIdx.x*256 + threadIdx.x;
    if (p >= PP) return;
    int off[9]; bool val[9];
    tap_setup(p, off, val);
    float e[5], ssum = 0.0f;
#pragma unroll
    for (int nn=0;nn<5;nn++){ e[nn] = expf(logits[(size_t)(bt*5+nn)*PP + p]); ssum += e[nn]; }
    float wts[5];
#pragma unroll
    for (int nn=0;nn<5;nn++) wts[nn] = e[nn] / ssum;
    float m9[4][9]; float rden[4]; int iz[4];
#pragma unroll
    for (int k=0;k<4;k++){
        int im12 = bt*4 + k;
        const float* mrow = maskb + (size_t)im12*PP;
#pragma unroll
        for (int t=0;t<9;t++) m9[k][t] = val[t] ? mrow[off[t]] : 0.0f;
        rden[k] = 1.0f/(denb[(size_t)im12*PP + p] + NEPS);
        iz[k] = ((const int*)misc)[25+im12];
    }
    const float* base = bevs + (size_t)bt*5*64*PP;
    for (int c=0;c<64;c++){
        float tgc = base[(size_t)c*PP + p];
        float fused = wts[0]*tgc;
#pragma unroll
        for (int k=0;k<4;k++){
            const float* sc = base + (size_t)(k+1)*64*PP + (size_t)c*PP;
            float num = 0.0f, center = 0.0f;
#pragma unroll
            for (int t=0;t<9;t++){
                if (val[t]){
                    float v = sc[off[t]];
                    num = fmaf(m9[k][t], v, num);
                    if (t==4) center = v;
                }
            }
            float mc = m9[k][4];
            float xc = iz[k] ? center : fmaf(mc, center, (1.0f-mc)*(num*rden[k]));
            fused = fmaf(wts[k+1], xc, fused);
        }
        out[((size_t)bt*64 + c)*PP + p] = fused;
    }
}

extern "C" void kernel_launch(void* const* d_in, const int* in_sizes, int n_in,
                              void* d_out, int out_size, void* d_ws, size_t ws_size,
                              hipStream_t stream)
{
    const float* bevs = (const float*)d_in[0];
    const float* cw  = (const float*)d_in[1];
    const float* cb  = (const float*)d_in[2];
    const float* w1  = (const float*)d_in[3];
    const float* b1  = (const float*)d_in[4];
    const float* w2  = (const float*)d_in[5];
    const float* b2  = (const float*)d_in[6];
    const float* w3  = (const float*)d_in[7];
    const float* b3  = (const float*)d_in[8];
    const float* w4  = (const float*)d_in[9];
    const float* b4  = (const float*)d_in[10];
    float* out = (float*)d_out;
    float* ws = (float*)d_ws;

    float* com    = ws + OFF_COM;
    float* ent    = ws + OFF_ENT;
    float* maskb  = ws + OFF_MASK;
    float* denb   = ws + OFF_DEN;
    float* logits = ws + OFF_LOGITS;
    unsigned* misc = (unsigned*)(ws + OFF_MISC);
    short* Xtg    = (short*)(ws + OFF_XTG_F);
    short* Xft    = (short*)(ws + OFF_XFT_F);
    float* z      = (float*)(ws + OFF_XFT_F);   // overlaps Xft; dead before Xft written

    dim3 blk(256,1,1);
    int gx = (PP + 255)/256;
    bool big = ws_size >= WS_NEED;

    k_init<<<dim3(1),dim3(64),0,stream>>>(misc);
    if (big){
        k_csum<<<dim3((PP/4+255)/256,15),blk,0,stream>>>(bevs,cw,misc,z);
        k_cfin<<<dim3(gx,15),blk,0,stream>>>(z,cb,com);
        k_xtg <<<dim3(PP/64,3),blk,0,stream>>>(bevs,Xtg);
    } else {
        k_conv<<<dim3(gx,15),blk,0,stream>>>(bevs,cw,cb,com,misc);
    }
    k_ent <<<dim3(gx,15),blk,0,stream>>>(com,ent);
    k_mask<<<dim3(gx,12),blk,0,stream>>>(ent,maskb,misc);
    k_den <<<dim3(gx,12),blk,0,stream>>>(maskb,denb);
    k_fin <<<dim3(1),dim3(64),0,stream>>>(misc, out + (size_t)3*64*PP);

    if (big){
        k_xft  <<<dim3((PP/4+255)/256,12),blk,0,stream>>>(bevs,maskb,denb,misc,Xft);
        k_mlp  <<<dim3(gx,15),blk,0,stream>>>(Xtg,Xft,w1,b1,w2,b2,w3,b3,w4,b4,logits);
        k_fuse2<<<dim3(gx,3,2),blk,0,stream>>>(bevs,logits,Xft,out);
    } else {
        k_pwf  <<<dim3(PP/64,15),blk,0,stream>>>(bevs,w1,b1,w2,b2,w3,b3,w4,b4,maskb,denb,misc,logits);
        k_fuse_old<<<dim3(gx,3),blk,0,stream>>>(bevs,logits,maskb,denb,misc,out);
    }
}

// Round 8
// 370.661 us; speedup vs baseline: 5.7771x; 1.1033x over previous
//
#include <hip/hip_runtime.h>
#include <hip/hip_bf16.h>
#include <math.h>

#define PP 40000
#define HDIM 200
#define WDIM 200
#define NEPS 1e-8f

// workspace layout (float offsets)
#define OFF_COM    0            // 15*PP
#define OFF_ENT    (15*PP)      // 15*PP
#define OFF_MASK   (30*PP)      // 12*PP
#define OFF_DEN    (42*PP)      // 12*PP
#define OFF_LOGITS (54*PP)      // 15*PP
#define OFF_MISC   (69*PP)      // 64 floats
#define OFF_XTG_F  (69*PP + 64)             // Xtg bf16: 3*PP*64 shorts = 3*PP*32 floats
#define OFF_XFT_F  (OFF_XTG_F + 3*PP*32)    // Xft bf16: 12*PP*64 shorts; z fp32 (15*9*PP) overlaps (dead before Xft written)
#define WS_NEED ((size_t)(69*PP + 64)*4 + (size_t)15*PP*64*2)

typedef __attribute__((ext_vector_type(8))) short bf16x8;
typedef __attribute__((ext_vector_type(4))) float f32x4;

__device__ __forceinline__ short f2bf(float f){
    __hip_bfloat16 h = __float2bfloat16(f);   // RTNE
    return *reinterpret_cast<short*>(&h);
}
__device__ __forceinline__ float bf2f(short s){
    return __uint_as_float(((unsigned)(unsigned short)s) << 16);
}

__device__ __forceinline__ unsigned f2ord(float f){
    unsigned u = __float_as_uint(f);
    return (u & 0x80000000u) ? ~u : (u | 0x80000000u);
}
__device__ __forceinline__ float ord2f(unsigned u){
    unsigned v = (u & 0x80000000u) ? (u & 0x7fffffffu) : ~u;
    return __uint_as_float(v);
}

// Clamped tap offsets (per-pixel scalar form, used by small kernels)
__device__ __forceinline__ void tap_setup(int p, int* off, bool* val){
    int h = p / WDIM, w = p - h*WDIM;
#pragma unroll
    for (int ky=0;ky<3;ky++)
#pragma unroll
        for (int kx=0;kx<3;kx++){
            int t = ky*3+kx;
            int hh = h+ky-1, ww = w+kx-1;
            val[t] = (hh>=0)&&(hh<HDIM)&&(ww>=0)&&(ww<WDIM);
            int hc = min(max(hh,0),HDIM-1);
            int wc = min(max(ww,0),WDIM-1);
            off[t] = hc*WDIM+wc;
        }
}

__global__ void k_init(unsigned* misc){
    int t = threadIdx.x;
    if (t < 12) misc[t] = 0xFFFFFFFFu;        // min (sortable) = +inf
    else if (t < 25) misc[t] = 0u;            // max = -inf, count = 0
}

// ---------------------------------------------------------------------------
// conv pass 1: z_t(q) = sum_c w[c,t] * x[c,q]; min/max fused.
// ---------------------------------------------------------------------------
__global__ __launch_bounds__(256) void k_csum(const float* __restrict__ bevs,
        const float* __restrict__ cw, unsigned* __restrict__ misc,
        float* __restrict__ z)
{
    int img = blockIdx.y;
    int n = img % 5;
    int idx = blockIdx.x*256 + threadIdx.x;
    bool act = idx < PP/4;
    int p = idx*4;
    float vmin = INFINITY, vmax = -INFINITY;
    f32x4 acc[9];
#pragma unroll
    for (int t=0;t<9;t++) acc[t] = (f32x4){0.f,0.f,0.f,0.f};
    if (act){
        const float* src = bevs + (size_t)img*64*PP;
#pragma unroll 2
        for (int c=0;c<64;c++){
            f32x4 v = *(const f32x4*)&src[(size_t)c*PP + p];
            vmin = fminf(fminf(fminf(vmin, v[0]), fminf(v[1], v[2])), v[3]);
            vmax = fmaxf(fmaxf(fmaxf(vmax, v[0]), fmaxf(v[1], v[2])), v[3]);
#pragma unroll
            for (int t=0;t<9;t++){
                float w = cw[c*9+t];
#pragma unroll
                for (int j=0;j<4;j++) acc[t][j] = fmaf(w, v[j], acc[t][j]);
            }
        }
        float* zimg = z + (size_t)img*9*PP;
#pragma unroll
        for (int t=0;t<9;t++)
            *(f32x4*)&zimg[(size_t)t*PP + p] = acc[t];
    }
    if (n > 0){
#pragma unroll
        for (int s=32;s>0;s>>=1){
            vmin = fminf(vmin, __shfl_xor(vmin, s, 64));
            vmax = fmaxf(vmax, __shfl_xor(vmax, s, 64));
        }
        if ((threadIdx.x & 63) == 0){
            int im12 = (img/5)*4 + (n-1);
            atomicMin(&misc[im12], f2ord(vmin));
            atomicMax(&misc[12+im12], f2ord(vmax));
        }
    }
}

// conv pass 2: com(p) = relu(cb + sum_t [val] z_t(p+delta_t))
__global__ __launch_bounds__(256) void k_cfin(const float* __restrict__ z,
        const float* __restrict__ cb, float* __restrict__ com)
{
    int img = blockIdx.y;
    int p = blockIdx.x*256 + threadIdx.x;
    if (p >= PP) return;
    int off[9]; bool val[9];
    tap_setup(p, off, val);
    const float* zimg = z + (size_t)img*9*PP;
    float v[9];
#pragma unroll
    for (int t=0;t<9;t++) v[t] = zimg[(size_t)t*PP + off[t]];
    float acc = cb[0];
#pragma unroll
    for (int t=0;t<9;t++) acc += val[t] ? v[t] : 0.0f;
    com[(size_t)img*PP + p] = fmaxf(acc, 0.0f);
}

// ---------------------------------------------------------------------------
// FALLBACK conv if ws too small
// ---------------------------------------------------------------------------
__global__ __launch_bounds__(256) void k_conv(const float* __restrict__ bevs,
        const float* __restrict__ cw, const float* __restrict__ cb,
        float* __restrict__ com, unsigned* __restrict__ misc)
{
    int img = blockIdx.y;
    int n = img % 5;
    int p = blockIdx.x*256 + threadIdx.x;
    float vmin = INFINITY, vmax = -INFINITY;
    if (p < PP){
        int off[9]; bool val[9];
        tap_setup(p, off, val);
        const float* src = bevs + (size_t)img*64*PP;
        float acc = cb[0];
#pragma unroll 2
        for (int c=0;c<64;c++){
            const float* sc = src + (size_t)c*PP;
            float v[9];
#pragma unroll
            for (int t=0;t<9;t++) v[t] = sc[off[t]];
            vmin = fminf(vmin, v[4]); vmax = fmaxf(vmax, v[4]);
#pragma unroll
            for (int t=0;t<9;t++)
                acc = fmaf(cw[c*9+t], val[t] ? v[t] : 0.0f, acc);
        }
        com[(size_t)img*PP + p] = fmaxf(acc, 0.0f);
    }
    if (n > 0){
#pragma unroll
        for (int s=32;s>0;s>>=1){
            vmin = fminf(vmin, __shfl_xor(vmin, s, 64));
            vmax = fmaxf(vmax, __shfl_xor(vmax, s, 64));
        }
        if ((threadIdx.x & 63) == 0){
            int im12 = (img/5)*4 + (n-1);
            atomicMin(&misc[im12], f2ord(vmin));
            atomicMax(&misc[12+im12], f2ord(vmax));
        }
    }
}

__global__ __launch_bounds__(256) void k_ent(const float* __restrict__ com,
        float* __restrict__ ent)
{
    int img = blockIdx.y;
    int p = blockIdx.x*256 + threadIdx.x;
    if (p >= PP) return;
    int off[9]; bool val[9];
    tap_setup(p, off, val);
    const float* s = com + (size_t)img*PP;
    float x = s[p];
    float v[9];
#pragma unroll
    for (int t=0;t<9;t++) v[t] = s[off[t]];
    float acc = 0.0f;
#pragma unroll
    for (int t=0;t<9;t++){
        float xv = val[t] ? v[t] : 0.0f;
        acc += 1.0f/(1.0f + expf(x - xv));
    }
    ent[(size_t)img*PP + p] = acc / 9.0f;
}

__global__ __launch_bounds__(256) void k_mask(const float* __restrict__ ent,
        float* __restrict__ maskb, unsigned* __restrict__ misc)
{
    int im12 = blockIdx.y; int bt = im12 >> 2; int n = (im12 & 3) + 1;
    int p = blockIdx.x*256 + threadIdx.x;
    int v = 0;
    if (p < PP){
        float en = ent[(size_t)(bt*5+n)*PP + p];
        float et = ent[(size_t)(bt*5)*PP + p];
        v = en > et;
        maskb[(size_t)im12*PP + p] = (float)v;
    }
    unsigned long long bal = __ballot(v);
    if ((threadIdx.x & 63) == 0) atomicAdd(&misc[24], (unsigned)__popcll(bal));
}

__global__ __launch_bounds__(256) void k_den(const float* __restrict__ maskb,
        float* __restrict__ denb)
{
    int im12 = blockIdx.y;
    int p = blockIdx.x*256 + threadIdx.x;
    if (p >= PP) return;
    int off[9]; bool val[9];
    tap_setup(p, off, val);
    const float* mrow = maskb + (size_t)im12*PP;
    float v[9];
#pragma unroll
    for (int t=0;t<9;t++) v[t] = mrow[off[t]];
    float s = 0.0f;
#pragma unroll
    for (int t=0;t<9;t++) s += val[t] ? v[t] : 0.0f;
    denb[(size_t)im12*PP + p] = s;
}

__global__ void k_fin(unsigned* misc, float* bwout){
    int t = threadIdx.x;
    if (t < 12){
        float mn = ord2f(misc[t]);
        float mx = ord2f(misc[12+t]);
        ((int*)misc)[25+t] = (mn + mx == 0.0f) ? 1 : 0;
    }
    if (t == 12) bwout[0] = (float)misc[24] / 480000.0f;
}

// ---------------------------------------------------------------------------
// k_xtg: Xtg[bt][px][64] = bf16(tg), LDS transpose. grid (625, 3), block 256.
// ---------------------------------------------------------------------------
__global__ __launch_bounds__(256) void k_xtg(const float* __restrict__ bevs,
        short* __restrict__ Xtg)
{
    __shared__ short tile[64][72];     // [px_local][ch], rows 144B (16B-mult)
    int tid = threadIdx.x;
    int bt = blockIdx.y;
    int px0 = blockIdx.x*64;
    const float* tg = bevs + (size_t)bt*5*64*PP;
    int c = tid>>2, q = tid&3;
#pragma unroll
    for (int j=0;j<4;j++){
        int pxl = q*16 + j*4;
        f32x4 v = *(const f32x4*)&tg[(size_t)c*PP + px0 + pxl];
#pragma unroll
        for (int e=0;e<4;e++) tile[pxl+e][c] = f2bf(v[e]);
    }
    __syncthreads();
    int pxl = tid>>2;
    short* dst = Xtg + ((size_t)bt*PP + px0 + pxl)*64 + q*16;
    *(bf16x8*)&dst[0] = *(bf16x8*)&tile[pxl][q*16];
    *(bf16x8*)&dst[8] = *(bf16x8*)&tile[pxl][q*16+8];
}

// ---------------------------------------------------------------------------
// k_xft: Xft[im12][px][64] = bf16(warp). Thread owns 4 consecutive px x 8 ch.
// Channel-split across blockIdx.z (8 chunks) for 8x more TLP.
// All loads are 16B-aligned f32x4 row windows (W=200 % 4 == 0; groups never
// cross rows). OOB taps annihilated exactly via zeroed mask values.
// grid (40, 12, 8), block 256.
// ---------------------------------------------------------------------------
__global__ __launch_bounds__(256) void k_xft(const float* __restrict__ bevs,
        const float* __restrict__ maskb, const float* __restrict__ denb,
        const unsigned* __restrict__ misc, short* __restrict__ Xft)
{
    int im12 = blockIdx.y; int bt = im12 >> 2; int n = (im12 & 3) + 1;
    int chb = blockIdx.z*8;
    int idx = blockIdx.x*256 + threadIdx.x;
    if (idx >= PP/4) return;
    int p = idx*4;
    int row = p / WDIM, col0 = p - row*WDIM;
    int s0 = max(col0-4, 0), s2 = min(col0+4, WDIM-4);
    int rowc[3]; bool rowok[3];
#pragma unroll
    for (int r=0;r<3;r++){
        int rr = row + r - 1;
        rowok[r] = (rr>=0) && (rr<HDIM);
        rowc[r] = min(max(rr,0),HDIM-1) * WDIM;
    }
    bool colok[6];
#pragma unroll
    for (int k=0;k<6;k++){
        int cc = col0 + k - 1;
        colok[k] = (cc>=0) && (cc<WDIM);
    }
    // mask window: m6[r][k], k=0..5 <-> col col0-1+k ... annihilates OOB
    const float* mrow = maskb + (size_t)im12*PP;
    float m6[3][6];
#pragma unroll
    for (int r=0;r<3;r++){
        f32x4 a0 = *(const f32x4*)&mrow[rowc[r] + s0];
        f32x4 a1 = *(const f32x4*)&mrow[rowc[r] + col0];
        f32x4 a2 = *(const f32x4*)&mrow[rowc[r] + s2];
        float mv[6] = {a0[3], a1[0], a1[1], a1[2], a1[3], a2[0]};
#pragma unroll
        for (int k=0;k<6;k++)
            m6[r][k] = (rowok[r] && colok[k]) ? mv[k] : 0.0f;
    }
    f32x4 den4 = *(const f32x4*)&denb[(size_t)im12*PP + p];
    float rden[4];
#pragma unroll
    for (int j=0;j<4;j++) rden[j] = 1.0f/(den4[j] + NEPS);
    int iz = ((const int*)misc)[25+im12];
    const float* nbb = bevs + (size_t)(bt*5+n)*64*PP;
    short* xr = Xft + (size_t)im12*PP*64;

    short fv0[8], fv1[8], fv2[8], fv3[8];
#pragma unroll
    for (int ci=0;ci<8;ci++){
        int c = chb + ci;
        const float* sc = nbb + (size_t)c*PP;
        f32x4 v0[3], v1[3], v2[3];
#pragma unroll
        for (int r=0;r<3;r++){
            v0[r] = *(const f32x4*)&sc[rowc[r] + s0];
            v1[r] = *(const f32x4*)&sc[rowc[r] + col0];
            v2[r] = *(const f32x4*)&sc[rowc[r] + s2];
        }
        // v at (r, k): k=0 -> v0[r].w ; 1..4 -> v1[r][k-1] ; 5 -> v2[r].x
        float num[4];
#pragma unroll
        for (int j=0;j<4;j++) num[j] = 0.0f;
#pragma unroll
        for (int r=0;r<3;r++){
            float vv[6] = {v0[r][3], v1[r][0], v1[r][1], v1[r][2], v1[r][3], v2[r][0]};
#pragma unroll
            for (int j=0;j<4;j++){
#pragma unroll
                for (int dk=0;dk<3;dk++)
                    num[j] = fmaf(m6[r][j+dk], vv[j+dk], num[j]);
            }
        }
        short out4[4];
#pragma unroll
        for (int j=0;j<4;j++){
            float center = v1[1][j];
            float mc = m6[1][j+1];
            float xc = iz ? center : fmaf(mc, center, (1.0f-mc)*(num[j]*rden[j]));
            out4[j] = f2bf(xc);
        }
        fv0[ci]=out4[0]; fv1[ci]=out4[1]; fv2[ci]=out4[2]; fv3[ci]=out4[3];
    }
    *(bf16x8*)&xr[(size_t)(p+0)*64 + chb] = *(bf16x8*)&fv0[0];
    *(bf16x8*)&xr[(size_t)(p+1)*64 + chb] = *(bf16x8*)&fv1[0];
    *(bf16x8*)&xr[(size_t)(p+2)*64 + chb] = *(bf16x8*)&fv2[0];
    *(bf16x8*)&xr[(size_t)(p+3)*64 + chb] = *(bf16x8*)&fv3[0];
}

// ---------------------------------------------------------------------------
// k_mlp: GEMM. A-frags: k0..63 from Xtg, k64..127 from Xft (n=0: Xtg again).
// grid (157, 15), block 256.
// ---------------------------------------------------------------------------
__global__ __launch_bounds__(256) void k_mlp(const short* __restrict__ Xtg,
        const short* __restrict__ Xft,
        const float* __restrict__ w1, const float* __restrict__ b1,
        const float* __restrict__ w2, const float* __restrict__ b2,
        const float* __restrict__ w3, const float* __restrict__ b3,
        const float* __restrict__ w4, const float* __restrict__ b4,
        float* __restrict__ logits)
{
    __shared__ __align__(16) short w1t[128*136];
    __shared__ __align__(16) short w2t[32*136];
    __shared__ __align__(16) short xt2[4*16*136];
    __shared__ __align__(16) float z2[4*16*33];
    __shared__ float b1l[128], b2l[32], b3l[8], w3l[8*33], w4l[8], b4l[1];

    int tid = threadIdx.x;
    int img = blockIdx.y, bt = img/5, n = img%5;

    for (int i=tid;i<16384;i+=256) w1t[(i>>7)*136 + (i&127)] = f2bf(w1[i]);
    for (int i=tid;i<4096;i+=256)  w2t[(i>>7)*136 + (i&127)] = f2bf(w2[i]);
    if (tid<256) w3l[(tid>>5)*33 + (tid&31)] = w3[tid];
    if (tid<128) b1l[tid]=b1[tid];
    if (tid<32)  b2l[tid]=b2[tid];
    if (tid<8)   b3l[tid]=b3[tid];
    if (tid<8)   w4l[tid]=w4[tid];
    if (tid==0)  b4l[0]=b4[0];
    __syncthreads();

    int w = tid>>6, l = tid&63;
    int ln = l&15, kg = l>>4;
    const short* xtgb = Xtg + (size_t)bt*PP*64;
    const short* xftb = (n>0) ? (Xft + (size_t)(bt*4+n-1)*PP*64) : xtgb;
    short* xt2w = &xt2[w*16*136];
    float* z2w  = &z2[w*16*33];
    int px_base = blockIdx.x*256 + w*64;

#pragma unroll 1
    for (int mt=0; mt<4; mt++){
        int prow = px_base + mt*16;
        int arow = prow + ln; if (arow > PP-1) arow = PP-1;
        const short* xr0 = xtgb + (size_t)arow*64;
        const short* xr1 = xftb + (size_t)arow*64;
        bf16x8 af[4];
        af[0] = *(const bf16x8*)&xr0[kg*8];
        af[1] = *(const bf16x8*)&xr0[32 + kg*8];
        af[2] = *(const bf16x8*)&xr1[kg*8];
        af[3] = *(const bf16x8*)&xr1[32 + kg*8];

        // layer 1: N=128 (8 n-tiles), K=128
#pragma unroll
        for (int nt=0;nt<8;nt++){
            float bias = b1l[nt*16 + ln];
            f32x4 acc = {bias, bias, bias, bias};
#pragma unroll
            for (int ks=0;ks<4;ks++){
                bf16x8 bf = *(const bf16x8*)&w1t[(nt*16+ln)*136 + ks*32 + kg*8];
                acc = __builtin_amdgcn_mfma_f32_16x16x32_bf16(af[ks], bf, acc, 0, 0, 0);
            }
#pragma unroll
            for (int r=0;r<4;r++)
                xt2w[(kg*4+r)*136 + nt*16 + ln] = f2bf(fmaxf(acc[r], 0.0f));
        }

        // layer 2: N=32, K=128
        bf16x8 a2[4];
#pragma unroll
        for (int ks=0;ks<4;ks++)
            a2[ks] = *(const bf16x8*)&xt2w[ln*136 + ks*32 + kg*8];
#pragma unroll
        for (int nt2=0;nt2<2;nt2++){
            float bias = b2l[nt2*16 + ln];
            f32x4 acc = {bias, bias, bias, bias};
#pragma unroll
            for (int ks=0;ks<4;ks++){
                bf16x8 bf = *(const bf16x8*)&w2t[(nt2*16+ln)*136 + ks*32 + kg*8];
                acc = __builtin_amdgcn_mfma_f32_16x16x32_bf16(a2[ks], bf, acc, 0, 0, 0);
            }
#pragma unroll
            for (int r=0;r<4;r++)
                z2w[(kg*4+r)*33 + nt2*16 + ln] = fmaxf(acc[r], 0.0f);
        }

        // tail
        int k0 = kg*2, k1 = kg*2+1;
        float y0 = b3l[k0], y1 = b3l[k1];
#pragma unroll
        for (int j=0;j<32;j++){
            float v = z2w[ln*33 + j];
            y0 = fmaf(w3l[k0*33+j], v, y0);
            y1 = fmaf(w3l[k1*33+j], v, y1);
        }
        float part = w4l[k0]*fmaxf(y0,0.0f) + w4l[k1]*fmaxf(y1,0.0f);
        part += __shfl_xor(part, 16, 64);
        part += __shfl_xor(part, 32, 64);
        if (kg == 0 && prow + ln < PP)
            logits[(size_t)img*PP + prow + ln] = fmaxf(part + b4l[0], 0.0f);
    }
}

// ---------------------------------------------------------------------------
// k_fuse2: softmax + weighted sum (tg fp32 from bevs, warp bf16 from Xft)
// grid (157, 3, 2)
// ---------------------------------------------------------------------------
__global__ __launch_bounds__(256) void k_fuse2(const float* __restrict__ bevs,
        const float* __restrict__ logits, const short* __restrict__ Xft,
        float* __restrict__ out)
{
    int bt = blockIdx.y;
    int cb = blockIdx.z*32;
    int p = blockIdx.x*256 + threadIdx.x;
    if (p >= PP) return;
    float e[5], ssum = 0.0f;
#pragma unroll
    for (int nn=0;nn<5;nn++){ e[nn] = expf(logits[(size_t)(bt*5+nn)*PP + p]); ssum += e[nn]; }
    float rs = 1.0f/ssum;
    const float* tgb = bevs + (size_t)bt*5*64*PP;
    float acc[32];
    float w0 = e[0]*rs;
#pragma unroll
    for (int ci=0;ci<32;ci++) acc[ci] = w0*tgb[(size_t)(cb+ci)*PP + p];
#pragma unroll
    for (int k=0;k<4;k++){
        float wk = e[k+1]*rs;
        const short* Xr = Xft + ((size_t)(bt*4+k)*PP + p)*64 + cb;
#pragma unroll
        for (int c8=0;c8<4;c8++){
            bf16x8 v = *(const bf16x8*)&Xr[c8*8];
#pragma unroll
            for (int j=0;j<8;j++)
                acc[c8*8+j] = fmaf(wk, bf2f(v[j]), acc[c8*8+j]);
        }
    }
#pragma unroll
    for (int ci=0;ci<32;ci++)
        out[((size_t)bt*64 + cb+ci)*PP + p] = acc[ci];
}

// ---------------------------------------------------------------------------
// FALLBACK path (fused kernels) if ws too small
// ---------------------------------------------------------------------------
__global__ __launch_bounds__(256) void k_pwf(const float* __restrict__ bevs,
        const float* __restrict__ w1, const float* __restrict__ b1,
        const float* __restrict__ w2, const float* __restrict__ b2,
        const float* __restrict__ w3, const float* __restrict__ b3,
        const float* __restrict__ w4, const float* __restrict__ b4,
        const float* __restrict__ maskb, const float* __restrict__ denb,
        const unsigned* __restrict__ misc, float* __restrict__ logits)
{
    __shared__ __align__(16) short w1t[128*136];
    __shared__ __align__(16) short w2t[32*136];
    __shared__ __align__(16) short xt[64*136];
    __shared__ __align__(16) float z2[64*33];
    __shared__ float b1l[128], b2l[32], b3l[8], w3l[256], w4l[8], b4l[1];

    int tid = threadIdx.x;
    int img = blockIdx.y, bt = img/5, n = img%5;

    for (int i=tid;i<16384;i+=256) w1t[(i>>7)*136 + (i&127)] = f2bf(w1[i]);
    for (int i=tid;i<4096;i+=256)  w2t[(i>>7)*136 + (i&127)] = f2bf(w2[i]);
    if (tid<128) b1l[tid]=b1[tid];
    if (tid<32)  b2l[tid]=b2[tid];
    if (tid<8)   b3l[tid]=b3[tid];
    if (tid<256) w3l[tid]=w3[tid];
    if (tid<8)   w4l[tid]=w4[tid];
    if (tid==0)  b4l[0]=b4[0];

    int px = tid&63, q = tid>>6;
    int p = blockIdx.x*64 + px;
    const float* tg = bevs + (size_t)bt*5*64*PP;
    if (n == 0){
#pragma unroll
        for (int ci=0;ci<16;ci++){
            int c = q*16+ci;
            short v = f2bf(tg[(size_t)c*PP + p]);
            xt[px*136 + c] = v;
            xt[px*136 + 64 + c] = v;
        }
    } else {
        int im12 = bt*4 + (n-1);
        int off[9]; bool val[9];
        tap_setup(p, off, val);
        const float* mrow = maskb + (size_t)im12*PP;
        float m9[9];
#pragma unroll
        for (int t=0;t<9;t++) m9[t] = val[t] ? mrow[off[t]] : 0.0f;
        float rden = 1.0f/(denb[(size_t)im12*PP + p] + NEPS);
        int iz = ((const int*)misc)[25+im12];
        float mc = m9[4];
        const float* nbb = bevs + (size_t)(bt*5+n)*64*PP;
#pragma unroll
        for (int ci=0;ci<16;ci++){
            int c = q*16+ci;
            xt[px*136 + c] = f2bf(tg[(size_t)c*PP + p]);
            const float* sc = nbb + (size_t)c*PP;
            float num = 0.0f, center = 0.0f;
#pragma unroll
            for (int t=0;t<9;t++){
                if (val[t]){
                    float v = sc[off[t]];
                    num = fmaf(m9[t], v, num);
                    if (t==4) center = v;
                }
            }
            float xc = iz ? center : fmaf(mc, center, (1.0f-mc)*(num*rden));
            xt[px*136 + 64 + c] = f2bf(xc);
        }
    }
    __syncthreads();

    int w = tid>>6, l = tid&63;
    int ln = l&15, kg = l>>4;
    bf16x8 af[4];
#pragma unroll
    for (int ks=0;ks<4;ks++)
        af[ks] = *(const bf16x8*)&xt[(w*16+ln)*136 + ks*32 + kg*8];
#pragma unroll
    for (int nt=0;nt<8;nt++){
        float bias = b1l[nt*16 + ln];
        f32x4 acc = {bias, bias, bias, bias};
#pragma unroll
        for (int ks=0;ks<4;ks++){
            bf16x8 bf = *(const bf16x8*)&w1t[(nt*16+ln)*136 + ks*32 + kg*8];
            acc = __builtin_amdgcn_mfma_f32_16x16x32_bf16(af[ks], bf, acc, 0, 0, 0);
        }
#pragma unroll
        for (int r=0;r<4;r++){
            int pr = w*16 + kg*4 + r;
            xt[pr*136 + nt*16 + ln] = f2bf(fmaxf(acc[r], 0.0f));
        }
    }
    bf16x8 a2[4];
#pragma unroll
    for (int ks=0;ks<4;ks++)
        a2[ks] = *(const bf16x8*)&xt[(w*16+ln)*136 + ks*32 + kg*8];
#pragma unroll
    for (int nt2=0;nt2<2;nt2++){
        float bias = b2l[nt2*16 + ln];
        f32x4 acc = {bias, bias, bias, bias};
#pragma unroll
        for (int ks=0;ks<4;ks++){
            bf16x8 bf = *(const bf16x8*)&w2t[(nt2*16+ln)*136 + ks*32 + kg*8];
            acc = __builtin_amdgcn_mfma_f32_16x16x32_bf16(a2[ks], bf, acc, 0, 0, 0);
        }
#pragma unroll
        for (int r=0;r<4;r++){
            int pr = w*16 + kg*4 + r;
            z2[pr*33 + nt2*16 + ln] = fmaxf(acc[r], 0.0f);
        }
    }
    __syncthreads();
    if (tid < 64){
        float y3[8];
#pragma unroll
        for (int k=0;k<8;k++) y3[k] = b3l[k];
        for (int j=0;j<32;j++){
            float v = z2[tid*33 + j];
#pragma unroll
            for (int k=0;k<8;k++) y3[k] = fmaf(w3l[k*32+j], v, y3[k]);
        }
        float sres = b4l[0];
#pragma unroll
        for (int k=0;k<8;k++) sres = fmaf(w4l[k], fmaxf(y3[k], 0.0f), sres);
        logits[(size_t)img*PP + blockIdx.x*64 + tid] = fmaxf(sres, 0.0f);
    }
}

__global__ __launch_bounds__(256) void k_fuse_old(const float* __restrict__ bevs,
        const float* __restrict__ logits, const float* __restrict__ maskb,
        const float* __restrict__ denb, const unsigned* __restrict__ misc,
        float* __restrict__ out)
{
    int bt = blockIdx.y;
    int p = blockIdx.x*256 + threadIdx.x;
    if (p >= PP) return;
    int off[9]; bool val[9];
    tap_setup(p, off, val);
    float e[5], ssum = 0.0f;
#pragma unroll
    for (int nn=0;nn<5;nn++){ e[nn] = expf(logits[(size_t)(bt*5+nn)*PP + p]); ssum += e[nn]; }
    float wts[5];
#pragma unroll
    for (int nn=0;nn<5;nn++) wts[nn] = e[nn] / ssum;
    float m9[4][9]; float rden[4]; int iz[4];
#pragma unroll
    for (int k=0;k<4;k++){
        int im12 = bt*4 + k;
        const float* mrow = maskb + (size_t)im12*PP;
#pragma unroll
        for (int t=0;t<9;t++) m9[k][t] = val[t] ? mrow[off[t]] : 0.0f;
        rden[k] = 1.0f/(denb[(size_t)im12*PP + p] + NEPS);
        iz[k] = ((const int*)misc)[25+im12];
    }
    const float* base = bevs + (size_t)bt*5*64*PP;
    for (int c=0;c<64;c++){
        float tgc = base[(size_t)c*PP + p];
        float fused = wts[0]*tgc;
#pragma unroll
        for (int k=0;k<4;k++){
            const float* sc = base + (size_t)(k+1)*64*PP + (size_t)c*PP;
            float num = 0.0f, center = 0.0f;
#pragma unroll
            for (int t=0;t<9;t++){
                if (val[t]){
                    float v = sc[off[t]];
                    num = fmaf(m9[k][t], v, num);
                    if (t==4) center = v;
                }
            }
            float mc = m9[k][4];
            float xc = iz[k] ? center : fmaf(mc, center, (1.0f-mc)*(num*rden[k]));
            fused = fmaf(wts[k+1], xc, fused);
        }
        out[((size_t)bt*64 + c)*PP + p] = fused;
    }
}

extern "C" void kernel_launch(void* const* d_in, const int* in_sizes, int n_in,
                              void* d_out, int out_size, void* d_ws, size_t ws_size,
                              hipStream_t stream)
{
    const float* bevs = (const float*)d_in[0];
    const float* cw  = (const float*)d_in[1];
    const float* cb  = (const float*)d_in[2];
    const float* w1  = (const float*)d_in[3];
    const float* b1  = (const float*)d_in[4];
    const float* w2  = (const float*)d_in[5];
    const float* b2  = (const float*)d_in[6];
    const float* w3  = (const float*)d_in[7];
    const float* b3  = (const float*)d_in[8];
    const float* w4  = (const float*)d_in[9];
    const float* b4  = (const float*)d_in[10];
    float* out = (float*)d_out;
    float* ws = (float*)d_ws;

    float* com    = ws + OFF_COM;
    float* ent    = ws + OFF_ENT;
    float* maskb  = ws + OFF_MASK;
    float* denb   = ws + OFF_DEN;
    float* logits = ws + OFF_LOGITS;
    unsigned* misc = (unsigned*)(ws + OFF_MISC);
    short* Xtg    = (short*)(ws + OFF_XTG_F);
    short* Xft    = (short*)(ws + OFF_XFT_F);
    float* z      = (float*)(ws + OFF_XFT_F);   // overlaps Xft; dead before Xft written

    dim3 blk(256,1,1);
    int gx = (PP + 255)/256;
    bool big = ws_size >= WS_NEED;

    k_init<<<dim3(1),dim3(64),0,stream>>>(misc);
    if (big){
        k_csum<<<dim3((PP/4+255)/256,15),blk,0,stream>>>(bevs,cw,misc,z);
        k_cfin<<<dim3(gx,15),blk,0,stream>>>(z,cb,com);
        k_xtg <<<dim3(PP/64,3),blk,0,stream>>>(bevs,Xtg);
    } else {
        k_conv<<<dim3(gx,15),blk,0,stream>>>(bevs,cw,cb,com,misc);
    }
    k_ent <<<dim3(gx,15),blk,0,stream>>>(com,ent);
    k_mask<<<dim3(gx,12),blk,0,stream>>>(ent,maskb,misc);
    k_den <<<dim3(gx,12),blk,0,stream>>>(maskb,denb);
    k_fin <<<dim3(1),dim3(64),0,stream>>>(misc, out + (size_t)3*64*PP);

    if (big){
        k_xft  <<<dim3((PP/4+255)/256,12,8),blk,0,stream>>>(bevs,maskb,denb,misc,Xft);
        k_mlp  <<<dim3(gx,15),blk,0,stream>>>(Xtg,Xft,w1,b1,w2,b2,w3,b3,w4,b4,logits);
        k_fuse2<<<dim3(gx,3,2),blk,0,stream>>>(bevs,logits,Xft,out);
    } else {
        k_pwf  <<<dim3(PP/64,15),blk,0,stream>>>(bevs,w1,b1,w2,b2,w3,b3,w4,b4,maskb,denb,misc,logits);
        k_fuse_old<<<dim3(gx,3),blk,0,stream>>>(bevs,logits,maskb,denb,misc,out);
    }
}

// Round 9
// 348.230 us; speedup vs baseline: 6.1492x; 1.0644x over previous
//
#include <hip/hip_runtime.h>
#include <hip/hip_bf16.h>
#include <math.h>

#define PP 40000
#define HDIM 200
#define WDIM 200
#define NEPS 1e-8f

// workspace layout (float offsets)
#define OFF_COM    0            // 15*PP
#define OFF_ENT    (15*PP)      // 15*PP
#define OFF_MASK   (30*PP)      // 12*PP
#define OFF_DEN    (42*PP)      // 12*PP
#define OFF_LOGITS (54*PP)      // 15*PP
#define OFF_MISC   (69*PP)      // 64 floats
#define OFF_XTG_F  (69*PP + 64)             // Xtg bf16 [bt][8][PP][8]: 3*PP*64 shorts
#define OFF_XFT_F  (OFF_XTG_F + 3*PP*32)    // Xft bf16 [im12][8][PP][8]: 12*PP*64 shorts; z fp32 overlaps (dead before Xft written)
#define WS_NEED ((size_t)(69*PP + 64)*4 + (size_t)15*PP*64*2)

typedef __attribute__((ext_vector_type(8))) short bf16x8;
typedef __attribute__((ext_vector_type(4))) float f32x4;

__device__ __forceinline__ short f2bf(float f){
    __hip_bfloat16 h = __float2bfloat16(f);   // RTNE
    return *reinterpret_cast<short*>(&h);
}
__device__ __forceinline__ float bf2f(short s){
    return __uint_as_float(((unsigned)(unsigned short)s) << 16);
}

__device__ __forceinline__ unsigned f2ord(float f){
    unsigned u = __float_as_uint(f);
    return (u & 0x80000000u) ? ~u : (u | 0x80000000u);
}
__device__ __forceinline__ float ord2f(unsigned u){
    unsigned v = (u & 0x80000000u) ? (u & 0x7fffffffu) : ~u;
    return __uint_as_float(v);
}

// Clamped tap offsets (per-pixel scalar form, used by small kernels)
__device__ __forceinline__ void tap_setup(int p, int* off, bool* val){
    int h = p / WDIM, w = p - h*WDIM;
#pragma unroll
    for (int ky=0;ky<3;ky++)
#pragma unroll
        for (int kx=0;kx<3;kx++){
            int t = ky*3+kx;
            int hh = h+ky-1, ww = w+kx-1;
            val[t] = (hh>=0)&&(hh<HDIM)&&(ww>=0)&&(ww<WDIM);
            int hc = min(max(hh,0),HDIM-1);
            int wc = min(max(ww,0),WDIM-1);
            off[t] = hc*WDIM+wc;
        }
}

__global__ void k_init(unsigned* misc){
    int t = threadIdx.x;
    if (t < 12) misc[t] = 0xFFFFFFFFu;        // min (sortable) = +inf
    else if (t < 25) misc[t] = 0u;            // max = -inf, count = 0
}

// ---------------------------------------------------------------------------
// conv pass 1: z_t(q) = sum_c w[c,t] * x[c,q]; min/max fused.
// ---------------------------------------------------------------------------
__global__ __launch_bounds__(256) void k_csum(const float* __restrict__ bevs,
        const float* __restrict__ cw, unsigned* __restrict__ misc,
        float* __restrict__ z)
{
    int img = blockIdx.y;
    int n = img % 5;
    int idx = blockIdx.x*256 + threadIdx.x;
    bool act = idx < PP/4;
    int p = idx*4;
    float vmin = INFINITY, vmax = -INFINITY;
    f32x4 acc[9];
#pragma unroll
    for (int t=0;t<9;t++) acc[t] = (f32x4){0.f,0.f,0.f,0.f};
    if (act){
        const float* src = bevs + (size_t)img*64*PP;
#pragma unroll 2
        for (int c=0;c<64;c++){
            f32x4 v = *(const f32x4*)&src[(size_t)c*PP + p];
            vmin = fminf(fminf(fminf(vmin, v[0]), fminf(v[1], v[2])), v[3]);
            vmax = fmaxf(fmaxf(fmaxf(vmax, v[0]), fmaxf(v[1], v[2])), v[3]);
#pragma unroll
            for (int t=0;t<9;t++){
                float w = cw[c*9+t];
#pragma unroll
                for (int j=0;j<4;j++) acc[t][j] = fmaf(w, v[j], acc[t][j]);
            }
        }
        float* zimg = z + (size_t)img*9*PP;
#pragma unroll
        for (int t=0;t<9;t++)
            *(f32x4*)&zimg[(size_t)t*PP + p] = acc[t];
    }
    if (n > 0){
#pragma unroll
        for (int s=32;s>0;s>>=1){
            vmin = fminf(vmin, __shfl_xor(vmin, s, 64));
            vmax = fmaxf(vmax, __shfl_xor(vmax, s, 64));
        }
        if ((threadIdx.x & 63) == 0){
            int im12 = (img/5)*4 + (n-1);
            atomicMin(&misc[im12], f2ord(vmin));
            atomicMax(&misc[12+im12], f2ord(vmax));
        }
    }
}

// conv pass 2: com(p) = relu(cb + sum_t [val] z_t(p+delta_t))
__global__ __launch_bounds__(256) void k_cfin(const float* __restrict__ z,
        const float* __restrict__ cb, float* __restrict__ com)
{
    int img = blockIdx.y;
    int p = blockIdx.x*256 + threadIdx.x;
    if (p >= PP) return;
    int off[9]; bool val[9];
    tap_setup(p, off, val);
    const float* zimg = z + (size_t)img*9*PP;
    float v[9];
#pragma unroll
    for (int t=0;t<9;t++) v[t] = zimg[(size_t)t*PP + off[t]];
    float acc = cb[0];
#pragma unroll
    for (int t=0;t<9;t++) acc += val[t] ? v[t] : 0.0f;
    com[(size_t)img*PP + p] = fmaxf(acc, 0.0f);
}

// ---------------------------------------------------------------------------
// FALLBACK conv if ws too small
// ---------------------------------------------------------------------------
__global__ __launch_bounds__(256) void k_conv(const float* __restrict__ bevs,
        const float* __restrict__ cw, const float* __restrict__ cb,
        float* __restrict__ com, unsigned* __restrict__ misc)
{
    int img = blockIdx.y;
    int n = img % 5;
    int p = blockIdx.x*256 + threadIdx.x;
    float vmin = INFINITY, vmax = -INFINITY;
    if (p < PP){
        int off[9]; bool val[9];
        tap_setup(p, off, val);
        const float* src = bevs + (size_t)img*64*PP;
        float acc = cb[0];
#pragma unroll 2
        for (int c=0;c<64;c++){
            const float* sc = src + (size_t)c*PP;
            float v[9];
#pragma unroll
            for (int t=0;t<9;t++) v[t] = sc[off[t]];
            vmin = fminf(vmin, v[4]); vmax = fmaxf(vmax, v[4]);
#pragma unroll
            for (int t=0;t<9;t++)
                acc = fmaf(cw[c*9+t], val[t] ? v[t] : 0.0f, acc);
        }
        com[(size_t)img*PP + p] = fmaxf(acc, 0.0f);
    }
    if (n > 0){
#pragma unroll
        for (int s=32;s>0;s>>=1){
            vmin = fminf(vmin, __shfl_xor(vmin, s, 64));
            vmax = fmaxf(vmax, __shfl_xor(vmax, s, 64));
        }
        if ((threadIdx.x & 63) == 0){
            int im12 = (img/5)*4 + (n-1);
            atomicMin(&misc[im12], f2ord(vmin));
            atomicMax(&misc[12+im12], f2ord(vmax));
        }
    }
}

__global__ __launch_bounds__(256) void k_ent(const float* __restrict__ com,
        float* __restrict__ ent)
{
    int img = blockIdx.y;
    int p = blockIdx.x*256 + threadIdx.x;
    if (p >= PP) return;
    int off[9]; bool val[9];
    tap_setup(p, off, val);
    const float* s = com + (size_t)img*PP;
    float x = s[p];
    float v[9];
#pragma unroll
    for (int t=0;t<9;t++) v[t] = s[off[t]];
    float acc = 0.0f;
#pragma unroll
    for (int t=0;t<9;t++){
        float xv = val[t] ? v[t] : 0.0f;
        acc += 1.0f/(1.0f + expf(x - xv));
    }
    ent[(size_t)img*PP + p] = acc / 9.0f;
}

__global__ __launch_bounds__(256) void k_mask(const float* __restrict__ ent,
        float* __restrict__ maskb, unsigned* __restrict__ misc)
{
    int im12 = blockIdx.y; int bt = im12 >> 2; int n = (im12 & 3) + 1;
    int p = blockIdx.x*256 + threadIdx.x;
    int v = 0;
    if (p < PP){
        float en = ent[(size_t)(bt*5+n)*PP + p];
        float et = ent[(size_t)(bt*5)*PP + p];
        v = en > et;
        maskb[(size_t)im12*PP + p] = (float)v;
    }
    unsigned long long bal = __ballot(v);
    if ((threadIdx.x & 63) == 0) atomicAdd(&misc[24], (unsigned)__popcll(bal));
}

__global__ __launch_bounds__(256) void k_den(const float* __restrict__ maskb,
        float* __restrict__ denb)
{
    int im12 = blockIdx.y;
    int p = blockIdx.x*256 + threadIdx.x;
    if (p >= PP) return;
    int off[9]; bool val[9];
    tap_setup(p, off, val);
    const float* mrow = maskb + (size_t)im12*PP;
    float v[9];
#pragma unroll
    for (int t=0;t<9;t++) v[t] = mrow[off[t]];
    float s = 0.0f;
#pragma unroll
    for (int t=0;t<9;t++) s += val[t] ? v[t] : 0.0f;
    denb[(size_t)im12*PP + p] = s;
}

__global__ void k_fin(unsigned* misc, float* bwout){
    int t = threadIdx.x;
    if (t < 12){
        float mn = ord2f(misc[t]);
        float mx = ord2f(misc[12+t]);
        ((int*)misc)[25+t] = (mn + mx == 0.0f) ? 1 : 0;
    }
    if (t == 12) bwout[0] = (float)misc[24] / 480000.0f;
}

// ---------------------------------------------------------------------------
// k_xtg: Xtg[bt][chunk=8][PP][8] = bf16(tg), LDS transpose.
// grid (625, 3), block 256.
// ---------------------------------------------------------------------------
__global__ __launch_bounds__(256) void k_xtg(const float* __restrict__ bevs,
        short* __restrict__ Xtg)
{
    __shared__ short tile[64][72];     // [px_local][ch], rows 144B (16B-mult)
    int tid = threadIdx.x;
    int bt = blockIdx.y;
    int px0 = blockIdx.x*64;
    const float* tg = bevs + (size_t)bt*5*64*PP;
    int c = tid>>2, q = tid&3;
#pragma unroll
    for (int j=0;j<4;j++){
        int pxl = q*16 + j*4;
        f32x4 v = *(const f32x4*)&tg[(size_t)c*PP + px0 + pxl];
#pragma unroll
        for (int e=0;e<4;e++) tile[pxl+e][c] = f2bf(v[e]);
    }
    __syncthreads();
    // store: lane-contiguous pixels -> coalesced 16B stores per chunk
    int pxl = tid&63, qq = tid>>6;     // qq: 0..3 -> chunks 2qq, 2qq+1
    short* base = Xtg + (size_t)bt*PP*64;
    *(bf16x8*)&base[((size_t)(2*qq  )*PP + px0 + pxl)*8] = *(bf16x8*)&tile[pxl][qq*16];
    *(bf16x8*)&base[((size_t)(2*qq+1)*PP + px0 + pxl)*8] = *(bf16x8*)&tile[pxl][qq*16+8];
}

// ---------------------------------------------------------------------------
// k_xft: Xft[im12][chunk=8][PP][8] = bf16(warp). Thread: 4 consecutive px x 8 ch.
// chunk = blockIdx.z. Stores are 64B-contiguous per thread (no partial lines).
// All loads are 16B-aligned f32x4 row windows. OOB annihilated via zeroed mask.
// grid (40, 12, 8), block 256.
// ---------------------------------------------------------------------------
__global__ __launch_bounds__(256) void k_xft(const float* __restrict__ bevs,
        const float* __restrict__ maskb, const float* __restrict__ denb,
        const unsigned* __restrict__ misc, short* __restrict__ Xft)
{
    int im12 = blockIdx.y; int bt = im12 >> 2; int n = (im12 & 3) + 1;
    int chunk = blockIdx.z;
    int chb = chunk*8;
    int idx = blockIdx.x*256 + threadIdx.x;
    if (idx >= PP/4) return;
    int p = idx*4;
    int row = p / WDIM, col0 = p - row*WDIM;
    int s0 = max(col0-4, 0), s2 = min(col0+4, WDIM-4);
    int rowc[3]; bool rowok[3];
#pragma unroll
    for (int r=0;r<3;r++){
        int rr = row + r - 1;
        rowok[r] = (rr>=0) && (rr<HDIM);
        rowc[r] = min(max(rr,0),HDIM-1) * WDIM;
    }
    bool colok[6];
#pragma unroll
    for (int k=0;k<6;k++){
        int cc = col0 + k - 1;
        colok[k] = (cc>=0) && (cc<WDIM);
    }
    const float* mrow = maskb + (size_t)im12*PP;
    float m6[3][6];
#pragma unroll
    for (int r=0;r<3;r++){
        f32x4 a0 = *(const f32x4*)&mrow[rowc[r] + s0];
        f32x4 a1 = *(const f32x4*)&mrow[rowc[r] + col0];
        f32x4 a2 = *(const f32x4*)&mrow[rowc[r] + s2];
        float mv[6] = {a0[3], a1[0], a1[1], a1[2], a1[3], a2[0]};
#pragma unroll
        for (int k=0;k<6;k++)
            m6[r][k] = (rowok[r] && colok[k]) ? mv[k] : 0.0f;
    }
    f32x4 den4 = *(const f32x4*)&denb[(size_t)im12*PP + p];
    float rden[4];
#pragma unroll
    for (int j=0;j<4;j++) rden[j] = 1.0f/(den4[j] + NEPS);
    int iz = ((const int*)misc)[25+im12];
    const float* nbb = bevs + (size_t)(bt*5+n)*64*PP;

    short fv0[8], fv1[8], fv2[8], fv3[8];
#pragma unroll
    for (int ci=0;ci<8;ci++){
        int c = chb + ci;
        const float* sc = nbb + (size_t)c*PP;
        f32x4 v0[3], v1[3], v2[3];
#pragma unroll
        for (int r=0;r<3;r++){
            v0[r] = *(const f32x4*)&sc[rowc[r] + s0];
            v1[r] = *(const f32x4*)&sc[rowc[r] + col0];
            v2[r] = *(const f32x4*)&sc[rowc[r] + s2];
        }
        float num[4];
#pragma unroll
        for (int j=0;j<4;j++) num[j] = 0.0f;
#pragma unroll
        for (int r=0;r<3;r++){
            float vv[6] = {v0[r][3], v1[r][0], v1[r][1], v1[r][2], v1[r][3], v2[r][0]};
#pragma unroll
            for (int j=0;j<4;j++){
#pragma unroll
                for (int dk=0;dk<3;dk++)
                    num[j] = fmaf(m6[r][j+dk], vv[j+dk], num[j]);
            }
        }
        short out4[4];
#pragma unroll
        for (int j=0;j<4;j++){
            float center = v1[1][j];
            float mc = m6[1][j+1];
            float xc = iz ? center : fmaf(mc, center, (1.0f-mc)*(num[j]*rden[j]));
            out4[j] = f2bf(xc);
        }
        fv0[ci]=out4[0]; fv1[ci]=out4[1]; fv2[ci]=out4[2]; fv3[ci]=out4[3];
    }
    short* xc0 = Xft + (size_t)im12*PP*64 + ((size_t)chunk*PP + p)*8;
    *(bf16x8*)&xc0[0]  = *(bf16x8*)&fv0[0];
    *(bf16x8*)&xc0[8]  = *(bf16x8*)&fv1[0];
    *(bf16x8*)&xc0[16] = *(bf16x8*)&fv2[0];
    *(bf16x8*)&xc0[24] = *(bf16x8*)&fv3[0];
}

// ---------------------------------------------------------------------------
// k_mlp: GEMM. A-frags: chunks kg / kg+4 from Xtg (k0..63) and Xft (k64..127).
// grid (157, 15), block 256.
// ---------------------------------------------------------------------------
__global__ __launch_bounds__(256) void k_mlp(const short* __restrict__ Xtg,
        const short* __restrict__ Xft,
        const float* __restrict__ w1, const float* __restrict__ b1,
        const float* __restrict__ w2, const float* __restrict__ b2,
        const float* __restrict__ w3, const float* __restrict__ b3,
        const float* __restrict__ w4, const float* __restrict__ b4,
        float* __restrict__ logits)
{
    __shared__ __align__(16) short w1t[128*136];
    __shared__ __align__(16) short w2t[32*136];
    __shared__ __align__(16) short xt2[4*16*136];
    __shared__ __align__(16) float z2[4*16*33];
    __shared__ float b1l[128], b2l[32], b3l[8], w3l[8*33], w4l[8], b4l[1];

    int tid = threadIdx.x;
    int img = blockIdx.y, bt = img/5, n = img%5;

    for (int i=tid;i<16384;i+=256) w1t[(i>>7)*136 + (i&127)] = f2bf(w1[i]);
    for (int i=tid;i<4096;i+=256)  w2t[(i>>7)*136 + (i&127)] = f2bf(w2[i]);
    if (tid<256) w3l[(tid>>5)*33 + (tid&31)] = w3[tid];
    if (tid<128) b1l[tid]=b1[tid];
    if (tid<32)  b2l[tid]=b2[tid];
    if (tid<8)   b3l[tid]=b3[tid];
    if (tid<8)   w4l[tid]=w4[tid];
    if (tid==0)  b4l[0]=b4[0];
    __syncthreads();

    int w = tid>>6, l = tid&63;
    int ln = l&15, kg = l>>4;
    const short* xtgb = Xtg + (size_t)bt*PP*64;
    const short* xftb = (n>0) ? (Xft + (size_t)(bt*4+n-1)*PP*64) : xtgb;
    short* xt2w = &xt2[w*16*136];
    float* z2w  = &z2[w*16*33];
    int px_base = blockIdx.x*256 + w*64;

#pragma unroll 1
    for (int mt=0; mt<4; mt++){
        int prow = px_base + mt*16;
        int arow = prow + ln; if (arow > PP-1) arow = PP-1;
        bf16x8 af[4];
        af[0] = *(const bf16x8*)&xtgb[((size_t)kg*PP     + arow)*8];
        af[1] = *(const bf16x8*)&xtgb[((size_t)(kg+4)*PP + arow)*8];
        af[2] = *(const bf16x8*)&xftb[((size_t)kg*PP     + arow)*8];
        af[3] = *(const bf16x8*)&xftb[((size_t)(kg+4)*PP + arow)*8];

        // layer 1: N=128 (8 n-tiles), K=128
#pragma unroll
        for (int nt=0;nt<8;nt++){
            float bias = b1l[nt*16 + ln];
            f32x4 acc = {bias, bias, bias, bias};
#pragma unroll
            for (int ks=0;ks<4;ks++){
                bf16x8 bf = *(const bf16x8*)&w1t[(nt*16+ln)*136 + ks*32 + kg*8];
                acc = __builtin_amdgcn_mfma_f32_16x16x32_bf16(af[ks], bf, acc, 0, 0, 0);
            }
#pragma unroll
            for (int r=0;r<4;r++)
                xt2w[(kg*4+r)*136 + nt*16 + ln] = f2bf(fmaxf(acc[r], 0.0f));
        }

        // layer 2: N=32, K=128
        bf16x8 a2[4];
#pragma unroll
        for (int ks=0;ks<4;ks++)
            a2[ks] = *(const bf16x8*)&xt2w[ln*136 + ks*32 + kg*8];
#pragma unroll
        for (int nt2=0;nt2<2;nt2++){
            float bias = b2l[nt2*16 + ln];
            f32x4 acc = {bias, bias, bias, bias};
#pragma unroll
            for (int ks=0;ks<4;ks++){
                bf16x8 bf = *(const bf16x8*)&w2t[(nt2*16+ln)*136 + ks*32 + kg*8];
                acc = __builtin_amdgcn_mfma_f32_16x16x32_bf16(a2[ks], bf, acc, 0, 0, 0);
            }
#pragma unroll
            for (int r=0;r<4;r++)
                z2w[(kg*4+r)*33 + nt2*16 + ln] = fmaxf(acc[r], 0.0f);
        }

        // tail
        int k0 = kg*2, k1 = kg*2+1;
        float y0 = b3l[k0], y1 = b3l[k1];
#pragma unroll
        for (int j=0;j<32;j++){
            float v = z2w[ln*33 + j];
            y0 = fmaf(w3l[k0*33+j], v, y0);
            y1 = fmaf(w3l[k1*33+j], v, y1);
        }
        float part = w4l[k0]*fmaxf(y0,0.0f) + w4l[k1]*fmaxf(y1,0.0f);
        part += __shfl_xor(part, 16, 64);
        part += __shfl_xor(part, 32, 64);
        if (kg == 0 && prow + ln < PP)
            logits[(size_t)img*PP + prow + ln] = fmaxf(part + b4l[0], 0.0f);
    }
}

// ---------------------------------------------------------------------------
// k_fuse2: softmax + weighted sum (tg fp32 from bevs, warp bf16 from Xft chunks)
// grid (157, 3, 2)
// ---------------------------------------------------------------------------
__global__ __launch_bounds__(256) void k_fuse2(const float* __restrict__ bevs,
        const float* __restrict__ logits, const short* __restrict__ Xft,
        float* __restrict__ out)
{
    int bt = blockIdx.y;
    int cb = blockIdx.z*32;
    int chunk0 = cb>>3;
    int p = blockIdx.x*256 + threadIdx.x;
    if (p >= PP) return;
    float e[5], ssum = 0.0f;
#pragma unroll
    for (int nn=0;nn<5;nn++){ e[nn] = expf(logits[(size_t)(bt*5+nn)*PP + p]); ssum += e[nn]; }
    float rs = 1.0f/ssum;
    const float* tgb = bevs + (size_t)bt*5*64*PP;
    float acc[32];
    float w0 = e[0]*rs;
#pragma unroll
    for (int ci=0;ci<32;ci++) acc[ci] = w0*tgb[(size_t)(cb+ci)*PP + p];
#pragma unroll
    for (int k=0;k<4;k++){
        float wk = e[k+1]*rs;
        const short* Xim = Xft + (size_t)(bt*4+k)*PP*64;
#pragma unroll
        for (int c8=0;c8<4;c8++){
            bf16x8 v = *(const bf16x8*)&Xim[((size_t)(chunk0+c8)*PP + p)*8];
#pragma unroll
            for (int j=0;j<8;j++)
                acc[c8*8+j] = fmaf(wk, bf2f(v[j]), acc[c8*8+j]);
        }
    }
#pragma unroll
    for (int ci=0;ci<32;ci++)
        out[((size_t)bt*64 + cb+ci)*PP + p] = acc[ci];
}

// ---------------------------------------------------------------------------
// FALLBACK path (fused kernels) if ws too small
// ---------------------------------------------------------------------------
__global__ __launch_bounds__(256) void k_pwf(const float* __restrict__ bevs,
        const float* __restrict__ w1, const float* __restrict__ b1,
        const float* __restrict__ w2, const float* __restrict__ b2,
        const float* __restrict__ w3, const float* __restrict__ b3,
        const float* __restrict__ w4, const float* __restrict__ b4,
        const float* __restrict__ maskb, const float* __restrict__ denb,
        const unsigned* __restrict__ misc, float* __restrict__ logits)
{
    __shared__ __align__(16) short w1t[128*136];
    __shared__ __align__(16) short w2t[32*136];
    __shared__ __align__(16) short xt[64*136];
    __shared__ __align__(16) float z2[64*33];
    __shared__ float b1l[128], b2l[32], b3l[8], w3l[256], w4l[8], b4l[1];

    int tid = threadIdx.x;
    int img = blockIdx.y, bt = img/5, n = img%5;

    for (int i=tid;i<16384;i+=256) w1t[(i>>7)*136 + (i&127)] = f2bf(w1[i]);
    for (int i=tid;i<4096;i+=256)  w2t[(i>>7)*136 + (i&127)] = f2bf(w2[i]);
    if (tid<128) b1l[tid]=b1[tid];
    if (tid<32)  b2l[tid]=b2[tid];
    if (tid<8)   b3l[tid]=b3[tid];
    if (tid<256) w3l[tid]=w3[tid];
    if (tid<8)   w4l[tid]=w4[tid];
    if (tid==0)  b4l[0]=b4[0];

    int px = tid&63, q = tid>>6;
    int p = blockIdx.x*64 + px;
    const float* tg = bevs + (size_t)bt*5*64*PP;
    if (n == 0){
#pragma unroll
        for (int ci=0;ci<16;ci++){
            int c = q*16+ci;
            short v = f2bf(tg[(size_t)c*PP + p]);
            xt[px*136 + c] = v;
            xt[px*136 + 64 + c] = v;
        }
    } else {
        int im12 = bt*4 + (n-1);
        int off[9]; bool val[9];
        tap_setup(p, off, val);
        const float* mrow = maskb + (size_t)im12*PP;
        float m9[9];
#pragma unroll
        for (int t=0;t<9;t++) m9[t] = val[t] ? mrow[off[t]] : 0.0f;
        float rden = 1.0f/(denb[(size_t)im12*PP + p] + NEPS);
        int iz = ((const int*)misc)[25+im12];
        float mc = m9[4];
        const float* nbb = bevs + (size_t)(bt*5+n)*64*PP;
#pragma unroll
        for (int ci=0;ci<16;ci++){
            int c = q*16+ci;
            xt[px*136 + c] = f2bf(tg[(size_t)c*PP + p]);
            const float* sc = nbb + (size_t)c*PP;
            float num = 0.0f, center = 0.0f;
#pragma unroll
            for (int t=0;t<9;t++){
                if (val[t]){
                    float v = sc[off[t]];
                    num = fmaf(m9[t], v, num);
                    if (t==4) center = v;
                }
            }
            float xc = iz ? center : fmaf(mc, center, (1.0f-mc)*(num*rden));
            xt[px*136 + 64 + c] = f2bf(xc);
        }
    }
    __syncthreads();

    int w = tid>>6, l = tid&63;
    int ln = l&15, kg = l>>4;
    bf16x8 af[4];
#pragma unroll
    for (int ks=0;ks<4;ks++)
        af[ks] = *(const bf16x8*)&xt[(w*16+ln)*136 + ks*32 + kg*8];
#pragma unroll
    for (int nt=0;nt<8;nt++){
        float bias = b1l[nt*16 + ln];
        f32x4 acc = {bias, bias, bias, bias};
#pragma unroll
        for (int ks=0;ks<4;ks++){
            bf16x8 bf = *(const bf16x8*)&w1t[(nt*16+ln)*136 + ks*32 + kg*8];
            acc = __builtin_amdgcn_mfma_f32_16x16x32_bf16(af[ks], bf, acc, 0, 0, 0);
        }
#pragma unroll
        for (int r=0;r<4;r++){
            int pr = w*16 + kg*4 + r;
            xt[pr*136 + nt*16 + ln] = f2bf(fmaxf(acc[r], 0.0f));
        }
    }
    bf16x8 a2[4];
#pragma unroll
    for (int ks=0;ks<4;ks++)
        a2[ks] = *(const bf16x8*)&xt[(w*16+ln)*136 + ks*32 + kg*8];
#pragma unroll
    for (int nt2=0;nt2<2;nt2++){
        float bias = b2l[nt2*16 + ln];
        f32x4 acc = {bias, bias, bias, bias};
#pragma unroll
        for (int ks=0;ks<4;ks++){
            bf16x8 bf = *(const bf16x8*)&w2t[(nt2*16+ln)*136 + ks*32 + kg*8];
            acc = __builtin_amdgcn_mfma_f32_16x16x32_bf16(a2[ks], bf, acc, 0, 0, 0);
        }
#pragma unroll
        for (int r=0;r<4;r++){
            int pr = w*16 + kg*4 + r;
            z2[pr*33 + nt2*16 + ln] = fmaxf(acc[r], 0.0f);
        }
    }
    __syncthreads();
    if (tid < 64){
        float y3[8];
#pragma unroll
        for (int k=0;k<8;k++) y3[k] = b3l[k];
        for (int j=0;j<32;j++){
            float v = z2[tid*33 + j];
#pragma unroll
            for (int k=0;k<8;k++) y3[k] = fmaf(w3l[k*32+j], v, y3[k]);
        }
        float sres = b4l[0];
#pragma unroll
        for (int k=0;k<8;k++) sres = fmaf(w4l[k], fmaxf(y3[k], 0.0f), sres);
        logits[(size_t)img*PP + blockIdx.x*64 + tid] = fmaxf(sres, 0.0f);
    }
}

__global__ __launch_bounds__(256) void k_fuse_old(const float* __restrict__ bevs,
        const float* __restrict__ logits, const float* __restrict__ maskb,
        const float* __restrict__ denb, const unsigned* __restrict__ misc,
        float* __restrict__ out)
{
    int bt = blockIdx.y;
    int p = blockIdx.x*256 + threadIdx.x;
    if (p >= PP) return;
    int off[9]; bool val[9];
    tap_setup(p, off, val);
    float e[5], ssum = 0.0f;
#pragma unroll
    for (int nn=0;nn<5;nn++){ e[nn] = expf(logits[(size_t)(bt*5+nn)*PP + p]); ssum += e[nn]; }
    float wts[5];
#pragma unroll
    for (int nn=0;nn<5;nn++) wts[nn] = e[nn] / ssum;
    float m9[4][9]; float rden[4]; int iz[4];
#pragma unroll
    for (int k=0;k<4;k++){
        int im12 = bt*4 + k;
        const float* mrow = maskb + (size_t)im12*PP;
#pragma unroll
        for (int t=0;t<9;t++) m9[k][t] = val[t] ? mrow[off[t]] : 0.0f;
        rden[k] = 1.0f/(denb[(size_t)im12*PP + p] + NEPS);
        iz[k] = ((const int*)misc)[25+im12];
    }
    const float* base = bevs + (size_t)bt*5*64*PP;
    for (int c=0;c<64;c++){
        float tgc = base[(size_t)c*PP + p];
        float fused = wts[0]*tgc;
#pragma unroll
        for (int k=0;k<4;k++){
            const float* sc = base + (size_t)(k+1)*64*PP + (size_t)c*PP;
            float num = 0.0f, center = 0.0f;
#pragma unroll
            for (int t=0;t<9;t++){
                if (val[t]){
                    float v = sc[off[t]];
                    num = fmaf(m9[k][t], v, num);
                    if (t==4) center = v;
                }
            }
            float mc = m9[k][4];
            float xc = iz[k] ? center : fmaf(mc, center, (1.0f-mc)*(num*rden[k]));
            fused = fmaf(wts[k+1], xc, fused);
        }
        out[((size_t)bt*64 + c)*PP + p] = fused;
    }
}

extern "C" void kernel_launch(void* const* d_in, const int* in_sizes, int n_in,
                              void* d_out, int out_size, void* d_ws, size_t ws_size,
                              hipStream_t stream)
{
    const float* bevs = (const float*)d_in[0];
    const float* cw  = (const float*)d_in[1];
    const float* cb  = (const float*)d_in[2];
    const float* w1  = (const float*)d_in[3];
    const float* b1  = (const float*)d_in[4];
    const float* w2  = (const float*)d_in[5];
    const float* b2  = (const float*)d_in[6];
    const float* w3  = (const float*)d_in[7];
    const float* b3  = (const float*)d_in[8];
    const float* w4  = (const float*)d_in[9];
    const float* b4  = (const float*)d_in[10];
    float* out = (float*)d_out;
    float* ws = (float*)d_ws;

    float* com    = ws + OFF_COM;
    float* ent    = ws + OFF_ENT;
    float* maskb  = ws + OFF_MASK;
    float* denb   = ws + OFF_DEN;
    float* logits = ws + OFF_LOGITS;
    unsigned* misc = (unsigned*)(ws + OFF_MISC);
    short* Xtg    = (short*)(ws + OFF_XTG_F);
    short* Xft    = (short*)(ws + OFF_XFT_F);
    float* z      = (float*)(ws + OFF_XFT_F);   // overlaps Xft; dead before Xft written

    dim3 blk(256,1,1);
    int gx = (PP + 255)/256;
    bool big = ws_size >= WS_NEED;

    k_init<<<dim3(1),dim3(64),0,stream>>>(misc);
    if (big){
        k_csum<<<dim3((PP/4+255)/256,15),blk,0,stream>>>(bevs,cw,misc,z);
        k_cfin<<<dim3(gx,15),blk,0,stream>>>(z,cb,com);
        k_xtg <<<dim3(PP/64,3),blk,0,stream>>>(bevs,Xtg);
    } else {
        k_conv<<<dim3(gx,15),blk,0,stream>>>(bevs,cw,cb,com,misc);
    }
    k_ent <<<dim3(gx,15),blk,0,stream>>>(com,ent);
    k_mask<<<dim3(gx,12),blk,0,stream>>>(ent,maskb,misc);
    k_den <<<dim3(gx,12),blk,0,stream>>>(maskb,denb);
    k_fin <<<dim3(1),dim3(64),0,stream>>>(misc, out + (size_t)3*64*PP);

    if (big){
        k_xft  <<<dim3((PP/4+255)/256,12,8),blk,0,stream>>>(bevs,maskb,denb,misc,Xft);
        k_mlp  <<<dim3(gx,15),blk,0,stream>>>(Xtg,Xft,w1,b1,w2,b2,w3,b3,w4,b4,logits);
        k_fuse2<<<dim3(gx,3,2),blk,0,stream>>>(bevs,logits,Xft,out);
    } else {
        k_pwf  <<<dim3(PP/64,15),blk,0,stream>>>(bevs,w1,b1,w2,b2,w3,b3,w4,b4,maskb,denb,misc,logits);
        k_fuse_old<<<dim3(gx,3),blk,0,stream>>>(bevs,logits,maskb,denb,misc,out);
    }
}